// Round 1
// baseline (2531.879 us; speedup 1.0000x reference)
//
#include <hip/hip_runtime.h>
#include <math.h>

#define PI_F      3.14159265358979323846f
#define TWOPI_F   6.28318530717958647692f
#define HALFPI_F  1.57079632679489661923f
#define ANG_F     0.8944271909999159f

// ---- staging layout (doubles) ----
#define SG_PIX   0      // sum, d2, d3, d4
#define SG_MAG   4      // 18 magnitude sums
#define SG_HISQ  22     // sum hi^2
#define SG_PMAG  23     // 12 parent-mag sums (s=0..2, b=0..3)
#define SG_IMM   35     // 5 x (sum im^2, im^3, im^4)
#define SG_ACE   50     // [4][4][81]
#define SG_ACR   1346   // [5][81]
#define SG_C0    1751   // [4][16]
#define SG_CR    1815   // [4][16]
#define SG_CX    1879   // [3][16]
#define SG_CRX   1927   // [4][4*8]
#define SG_CR5   2055   // [25]
#define NSTG     2080

__device__ __forceinline__ int sfreq(int k, int H) { return (k < (H >> 1)) ? k : k - H; }

__device__ __forceinline__ float d_lograd(int fy, int fx, int H) {
  float cy = (float)fy * (2.0f / (float)H);
  float cx = (float)fx * (2.0f / (float)H);
  float rad = sqrtf(cx * cx + cy * cy);
  if (fy == 0 && fx == 0) rad = 2.0f / (float)H;   // reference DC hack
  return log2f(rad);
}
__device__ __forceinline__ float d_angle(int fy, int fx, int H) {
  return atan2f((float)fy * (2.0f / (float)H), (float)fx * (2.0f / (float)H));
}
__device__ __forceinline__ float d_rc(float x) {   // raised cosine
  float c = fminf(fmaxf(-x, 0.0f), 1.0f);
  float t = cosf(0.5f * PI_F * c);
  return t * t;
}
__device__ __forceinline__ float d_alfa(float ang, int b) {
  float bc = (b == 0) ? 0.0f : (b == 1) ? 0.78539816339744830962f
           : (b == 2) ? 1.57079632679489661923f : 2.35619449019234492885f;
  float t = (PI_F + ang) - bc;
  float m = fmodf(t, TWOPI_F);         // mimic jnp.mod (fmod + sign fix)
  if (m < 0.0f) m += TWOPI_F;
  return m - PI_F;
}
__device__ __forceinline__ float d_cos3(float a) { float c = cosf(a); return ANG_F * c * c * c; }
__device__ __forceinline__ float d_amaskC(float ang, int b) {   // complex angle mask 2*A*I
  float alfa = d_alfa(ang, b);
  float A = d_cos3(alfa);
  return (fabsf(alfa) < HALFPI_F) ? 2.0f * A : 0.0f;
}
__device__ __forceinline__ unsigned fkey(float f) {
  unsigned u = __float_as_uint(f);
  return (u & 0x80000000u) ? ~u : (u | 0x80000000u);
}
__device__ __forceinline__ float funkey(unsigned k) {
  return (k & 0x80000000u) ? __uint_as_float(k & 0x7FFFFFFFu) : __uint_as_float(~k);
}

// block (256 threads = 4 waves) reduction of K floats; result in red[0..K)
template<int K>
__device__ __forceinline__ void blk_reduce(float* v, float* red) {
  int tid = threadIdx.x, wave = tid >> 6, lane = tid & 63;
  #pragma unroll
  for (int k = 0; k < K; k++) {
    float x = v[k];
    #pragma unroll
    for (int o = 32; o; o >>= 1) x += __shfl_down(x, o, 64);
    if (lane == 0) red[wave * K + k] = x;
  }
  __syncthreads();
  if (tid < K) red[tid] = red[tid] + red[K + tid] + red[2 * K + tid] + red[3 * K + tid];
}

// ================= FFT (Stockham radix-2, one row per block, LDS) =================
template<int N, bool INV, bool REALIN>
__global__ __launch_bounds__(256) void k_fft_rows(const void* vin, float2* vout) {
  __shared__ float2 bufA[N];
  __shared__ float2 bufB[N];
  const int row = blockIdx.x;
  const int tid = threadIdx.x;
  if constexpr (REALIN) {
    const float* in = (const float*)vin + (size_t)row * N;
    for (int i = tid; i < N; i += 256) bufA[i] = make_float2(in[i], 0.0f);
  } else {
    const float2* in = (const float2*)vin + (size_t)row * N;
    for (int i = tid; i < N; i += 256) bufA[i] = in[i];
  }
  __syncthreads();
  float2* src = bufA; float2* dst = bufB;
  int n = N, st = 0;
  while (n > 1) {
    int m = n >> 1;
    float th0 = (INV ? TWOPI_F : -TWOPI_F) / (float)n;
    for (int t = tid; t < (N >> 1); t += 256) {
      int p = t >> st;
      int q = t & ((1 << st) - 1);
      int i0 = q + (p << st);
      float2 a = src[i0];
      float2 b = src[i0 + (m << st)];
      float sv, cv; sincosf(th0 * (float)p, &sv, &cv);
      float dx = a.x - b.x, dy = a.y - b.y;
      int o0 = q + (p << (st + 1));
      dst[o0] = make_float2(a.x + b.x, a.y + b.y);
      dst[o0 + (1 << st)] = make_float2(dx * cv - dy * sv, dx * sv + dy * cv);
    }
    __syncthreads();
    float2* tmp = src; src = dst; dst = tmp;
    n = m; st++;
  }
  float2* o = vout + (size_t)row * N;
  if (INV) {
    const float sc = 1.0f / (float)N;
    for (int i = tid; i < N; i += 256) { float2 v = src[i]; o[i] = make_float2(v.x * sc, v.y * sc); }
  } else {
    for (int i = tid; i < N; i += 256) o[i] = src[i];
  }
}

__global__ __launch_bounds__(256) void k_transpose(const float2* __restrict__ in, float2* __restrict__ out, int N) {
  __shared__ float2 tile[32][33];
  int bx = blockIdx.x << 5, by = blockIdx.y << 5;
  int tx = threadIdx.x & 31, ty = threadIdx.x >> 5;
  for (int r = ty; r < 32; r += 8) tile[r][tx] = in[(size_t)(by + r) * N + bx + tx];
  __syncthreads();
  for (int r = ty; r < 32; r += 8) out[(size_t)(bx + r) * N + by + tx] = tile[tx][r];
}

// ================= pointwise spectrum generators =================
__global__ __launch_bounds__(256) void k_gen_hi(const float2* __restrict__ F, float2* __restrict__ T, int H) {
  int i = blockIdx.x * 256 + threadIdx.x;
  if (i >= H * H) return;
  int fy = sfreq(i / H, H), fx = sfreq(i % H, H);
  float hi = sqrtf(d_rc(d_lograd(fy, fx, H)));
  float2 v = F[i];
  T[i] = make_float2(v.x * hi, v.y * hi);
}
__global__ __launch_bounds__(256) void k_gen_L0(const float2* __restrict__ F, float2* __restrict__ L, int H) {
  int i = blockIdx.x * 256 + threadIdx.x;
  if (i >= H * H) return;
  int fy = sfreq(i / H, H), fx = sfreq(i % H, H);
  float lo = sqrtf(fmaxf(1.0f - d_rc(d_lograd(fy, fx, H)), 0.0f));
  float2 v = F[i];
  L[i] = make_float2(v.x * lo, v.y * lo);
}
// crop freq domain [-Hn/2, Hn/2) from big (2*Hn) grid, multiply native lo mask
__global__ __launch_bounds__(256) void k_gen_Ldown(const float2* __restrict__ Lb, float2* __restrict__ Ls, int Hn, int zdc) {
  int i = blockIdx.x * 256 + threadIdx.x;
  if (i >= Hn * Hn) return;
  int fy = sfreq(i / Hn, Hn), fx = sfreq(i % Hn, Hn);
  int Hb = Hn << 1;
  int by = fy >= 0 ? fy : fy + Hb;
  int bx = fx >= 0 ? fx : fx + Hb;
  float lo = sqrtf(fmaxf(1.0f - d_rc(d_lograd(fy, fx, Hn)), 0.0f));
  float2 v = Lb[(size_t)by * Hb + bx];
  if (zdc && i == 0) { Ls[0] = make_float2(0.f, 0.f); return; }
  Ls[i] = make_float2(v.x * lo, v.y * lo);
}
// band spectrum B = j * 2*A*I * hm * L
__global__ __launch_bounds__(256) void k_gen_band(const float2* __restrict__ L, float2* __restrict__ out, int H, int b) {
  int i = blockIdx.x * 256 + threadIdx.x;
  if (i >= H * H) return;
  int fy = sfreq(i / H, H), fx = sfreq(i % H, H);
  float hm = sqrtf(d_rc(d_lograd(fy, fx, H) + 1.0f));
  float am = d_amaskC(d_angle(fy, fx, H), b);
  float m = hm * am;
  float2 l = L[i];
  out[i] = make_float2(-l.y * m, l.x * m);
}
// embed band spectrum of scale s+1 (size H/2) into size-H grid (parents)
__global__ __launch_bounds__(256) void k_gen_embed_band(const float2* __restrict__ Lsm, float2* __restrict__ P, int H, int b) {
  int i = blockIdx.x * 256 + threadIdx.x;
  if (i >= H * H) return;
  int fy = sfreq(i / H, H), fx = sfreq(i % H, H);
  int q = H >> 2;
  float2 r = make_float2(0.f, 0.f);
  if (fy >= -q && fy < q && fx >= -q && fx < q) {
    int h2 = H >> 1;
    int sy = fy >= 0 ? fy : fy + h2;
    int sx = fx >= 0 ? fx : fx + h2;
    float hm = sqrtf(d_rc(d_lograd(fy, fx, h2) + 1.0f));
    float am = d_amaskC(d_angle(fy, fx, h2), b);
    float m = hm * am;
    float2 l = Lsm[(size_t)sy * h2 + sx];
    r = make_float2(-l.y * m, l.x * m);
  }
  P[i] = r;
}
// embed L4' (64) into 128 (last-scale rparents)
__global__ __launch_bounds__(256) void k_gen_embed_lo(const float2* __restrict__ L4, float2* __restrict__ P, int H) {
  int i = blockIdx.x * 256 + threadIdx.x;
  if (i >= H * H) return;
  int fy = sfreq(i / H, H), fx = sfreq(i % H, H);
  int q = H >> 2;
  float2 r = make_float2(0.f, 0.f);
  if (fy >= -q && fy < q && fx >= -q && fx < q) {
    int h2 = H >> 1;
    int sy = fy >= 0 ? fy : fy + h2;
    int sx = fx >= 0 ? fx : fx + h2;
    r = L4[(size_t)sy * h2 + sx];
  }
  P[i] = r;
}
// imF_4 = L4' * lo0(64)
__global__ __launch_bounds__(256) void k_gen_imF4(const float2* __restrict__ L4, float2* __restrict__ out, int H) {
  int i = blockIdx.x * 256 + threadIdx.x;
  if (i >= H * H) return;
  int fy = sfreq(i / H, H), fx = sfreq(i % H, H);
  float lo = sqrtf(fmaxf(1.0f - d_rc(d_lograd(fy, fx, H)), 0.0f));
  float2 v = L4[i];
  out[i] = make_float2(v.x * lo, v.y * lo);
}
// imF_s = embed(sym(imF_{s+1})) + lo0*hm^2*L_s*sum_b A1*(A1*I1 - A2*I2)
__global__ __launch_bounds__(256) void k_gen_imF_step(const float2* __restrict__ imSm, const float2* __restrict__ Ls,
                                                      float2* __restrict__ out, int H) {
  int i = blockIdx.x * 256 + threadIdx.x;
  if (i >= H * H) return;
  int fy = sfreq(i / H, H), fx = sfreq(i % H, H);
  int q = H >> 2, h2 = H >> 1;
  float2 v = make_float2(0.f, 0.f);
  if (fy >= -q && fy < q && fx >= -q && fx < q) {
    int sy = fy >= 0 ? fy : fy + h2;
    int sx = fx >= 0 ? fx : fx + h2;
    int nfy = (fy == -q) ? fy : -fy;
    int nfx = (fx == -q) ? fx : -fx;
    int ny = nfy >= 0 ? nfy : nfy + h2;
    int nx = nfx >= 0 ? nfx : nfx + h2;
    float2 a = imSm[(size_t)sy * h2 + sx];
    float2 bb = imSm[(size_t)ny * h2 + nx];
    v = make_float2(0.5f * (a.x + bb.x), 0.5f * (a.y - bb.y));   // symmetrize
  }
  float lr = d_lograd(fy, fx, H);
  float hm2 = d_rc(lr + 1.0f);
  float lo0 = sqrtf(fmaxf(1.0f - d_rc(lr), 0.0f));
  float ang1 = d_angle(fy, fx, H);
  int gfy = (fy == -(H >> 1)) ? fy : -fy;
  int gfx = (fx == -(H >> 1)) ? fx : -fx;
  float ang2 = d_angle(gfy, gfx, H);
  float msum = 0.0f;
  #pragma unroll
  for (int b = 0; b < 4; b++) {
    float a1 = d_alfa(ang1, b), a2 = d_alfa(ang2, b);
    float A1 = d_cos3(a1), A2 = d_cos3(a2);
    float T1 = (fabsf(a1) < HALFPI_F) ? A1 : 0.0f;
    float T2 = (fabsf(a2) < HALFPI_F) ? A2 : 0.0f;
    msum += A1 * (T1 - T2);
  }
  float mm = lo0 * hm2 * msum;
  float2 l = Ls[i];
  out[i] = make_float2(v.x + l.x * mm, v.y + l.y * mm);
}

// ================= reductions =================
__global__ __launch_bounds__(256) void k_init(double* stg, unsigned* stgu) {
  int i = blockIdx.x * 256 + threadIdx.x;
  if (i < NSTG) stg[i] = 0.0;
  if (i == 0) { stgu[0] = 0u; stgu[1] = 0xFFFFFFFFu; }
}
__global__ __launch_bounds__(256) void k_pix1(const float* __restrict__ x, int n, double* stg, unsigned* stgu) {
  __shared__ float red[4];
  float s = 0.f, mn = 3.402823466e38f, mx = -3.402823466e38f;
  for (int i = blockIdx.x * 256 + threadIdx.x; i < n; i += gridDim.x * 256) {
    float v = x[i]; s += v; mn = fminf(mn, v); mx = fmaxf(mx, v);
  }
  float acc[1] = {s};
  blk_reduce<1>(acc, red);
  if (threadIdx.x == 0) atomicAdd(&stg[SG_PIX], (double)red[0]);
  #pragma unroll
  for (int o = 32; o; o >>= 1) { mn = fminf(mn, __shfl_down(mn, o, 64)); mx = fmaxf(mx, __shfl_down(mx, o, 64)); }
  if ((threadIdx.x & 63) == 0) { atomicMin(&stgu[1], fkey(mn)); atomicMax(&stgu[0], fkey(mx)); }
}
__global__ __launch_bounds__(256) void k_pix2(const float* __restrict__ x, int n, double* stg) {
  __shared__ float red[12];
  float mu = (float)(stg[SG_PIX] / (double)n);
  float a2 = 0.f, a3 = 0.f, a4 = 0.f;
  for (int i = blockIdx.x * 256 + threadIdx.x; i < n; i += gridDim.x * 256) {
    float d = x[i] - mu; float d2 = d * d; a2 += d2; a3 += d2 * d; a4 += d2 * d2;
  }
  float acc[3] = {a2, a3, a4};
  blk_reduce<3>(acc, red);
  if (threadIdx.x < 3) atomicAdd(&stg[SG_PIX + 1 + threadIdx.x], (double)red[threadIdx.x]);
}
__global__ __launch_bounds__(256) void k_reduce_hi(const float2* __restrict__ t, int n, double* m0, double* hs) {
  __shared__ float red[8];
  float a = 0.f, b = 0.f;
  for (int i = blockIdx.x * 256 + threadIdx.x; i < n; i += gridDim.x * 256) {
    float v = t[i].x; a += fabsf(v); b += v * v;
  }
  float acc[2] = {a, b};
  blk_reduce<2>(acc, red);
  if (threadIdx.x == 0) atomicAdd(m0, (double)red[0]);
  if (threadIdx.x == 1) atomicAdd(hs, (double)red[1]);
}
__global__ __launch_bounds__(256) void k_reduce_absre(const float2* __restrict__ t, int n, double* out) {
  __shared__ float red[4];
  float a = 0.f;
  for (int i = blockIdx.x * 256 + threadIdx.x; i < n; i += gridDim.x * 256) a += fabsf(t[i].x);
  float acc[1] = {a};
  blk_reduce<1>(acc, red);
  if (threadIdx.x == 0) atomicAdd(out, (double)red[0]);
}
__global__ __launch_bounds__(256) void k_reduce_magc(const float2* __restrict__ t, int n, double* out) {
  __shared__ float red[4];
  float a = 0.f;
  for (int i = blockIdx.x * 256 + threadIdx.x; i < n; i += gridDim.x * 256) {
    float2 v = t[i]; a += sqrtf(v.x * v.x + v.y * v.y);
  }
  float acc[1] = {a};
  blk_reduce<1>(acc, red);
  if (threadIdx.x == 0) atomicAdd(out, (double)red[0]);
}
__global__ __launch_bounds__(256) void k_reduce_mag4(const float2* __restrict__ b0, const float2* __restrict__ b1,
                                                     const float2* __restrict__ b2, const float2* __restrict__ b3,
                                                     int n, double* out) {
  __shared__ float red[16];
  float a0 = 0.f, a1 = 0.f, a2 = 0.f, a3 = 0.f;
  for (int i = blockIdx.x * 256 + threadIdx.x; i < n; i += gridDim.x * 256) {
    float2 v0 = b0[i], v1 = b1[i], v2 = b2[i], v3 = b3[i];
    a0 += sqrtf(v0.x * v0.x + v0.y * v0.y);
    a1 += sqrtf(v1.x * v1.x + v1.y * v1.y);
    a2 += sqrtf(v2.x * v2.x + v2.y * v2.y);
    a3 += sqrtf(v3.x * v3.x + v3.y * v3.y);
  }
  float acc[4] = {a0, a1, a2, a3};
  blk_reduce<4>(acc, red);
  if (threadIdx.x < 4) atomicAdd(&out[threadIdx.x], (double)red[threadIdx.x]);
}
__global__ __launch_bounds__(256) void k_reduce_im(const float2* __restrict__ t, int n, double* out) {
  __shared__ float red[12];
  float a2 = 0.f, a3 = 0.f, a4 = 0.f;
  for (int i = blockIdx.x * 256 + threadIdx.x; i < n; i += gridDim.x * 256) {
    float v = t[i].x; float v2 = v * v; a2 += v2; a3 += v2 * v; a4 += v2 * v2;
  }
  float acc[3] = {a2, a3, a4};
  blk_reduce<3>(acc, red);
  if (threadIdx.x < 3) atomicAdd(&out[threadIdx.x], (double)red[threadIdx.x]);
}

// central 9x9 circular autocorrelation (raw sums)
template<int MODE>   // 0: real part; 1: |complex| - mean
__global__ __launch_bounds__(256) void k_autocorr(const float2* __restrict__ in, int H,
                                                  const double* msum, float invCsz, double* gacc) {
  __shared__ float tile[40][40];
  __shared__ float accL[81];
  float mean = 0.f;
  if constexpr (MODE == 1) mean = (float)(msum[0] * (double)invCsz);
  if (threadIdx.x < 81) accL[threadIdx.x] = 0.f;
  int nT = (H >> 5) * (H >> 5);
  for (int ti = blockIdx.x; ti < nT; ti += gridDim.x) {
    __syncthreads();
    int by = (ti / (H >> 5)) << 5, bx = (ti % (H >> 5)) << 5;
    for (int ii = threadIdx.x; ii < 1600; ii += 256) {
      int r = ii / 40, c = ii - r * 40;
      int gy = (by + r - 4) & (H - 1), gx = (bx + c - 4) & (H - 1);
      float2 v = in[(size_t)gy * H + gx];
      float val;
      if constexpr (MODE == 1) val = sqrtf(v.x * v.x + v.y * v.y) - mean;
      else val = v.x;
      tile[r][c] = val;
    }
    __syncthreads();
    int tx = threadIdx.x & 31, ty = threadIdx.x >> 5;
    float cen[4];
    #pragma unroll
    for (int r = 0; r < 4; r++) cen[r] = tile[ty + 8 * r + 4][tx + 4];
    for (int o = 0; o < 81; o++) {
      int dy = o / 9 - 4, dx = o - (o / 9) * 9 - 4;
      float ss = 0.f;
      #pragma unroll
      for (int r = 0; r < 4; r++) ss += cen[r] * tile[ty + 8 * r + 4 + dy][tx + 4 + dx];
      #pragma unroll
      for (int ofs = 32; ofs; ofs >>= 1) ss += __shfl_down(ss, ofs, 64);
      if ((threadIdx.x & 63) == 0) atomicAdd(&accL[o], ss);
    }
  }
  __syncthreads();
  if (threadIdx.x < 81) atomicAdd(&gacc[threadIdx.x], (double)accL[threadIdx.x]);
}

// C0 (centered |c|) and Cr0 (real parts) Grams of 4 bands
__global__ __launch_bounds__(256) void k_gram4(const float2* __restrict__ b0, const float2* __restrict__ b1,
                                               const float2* __restrict__ b2, const float2* __restrict__ b3,
                                               const double* msum, int n, float invCsz,
                                               double* c0out, double* crout) {
  __shared__ float red[128];
  float mm[4];
  #pragma unroll
  for (int k = 0; k < 4; k++) mm[k] = (float)(msum[k] * (double)invCsz);
  float acc[32];
  #pragma unroll
  for (int k = 0; k < 32; k++) acc[k] = 0.f;
  for (int i = blockIdx.x * 256 + threadIdx.x; i < n; i += gridDim.x * 256) {
    float2 v0 = b0[i], v1 = b1[i], v2 = b2[i], v3 = b3[i];
    float a[4] = { sqrtf(v0.x * v0.x + v0.y * v0.y) - mm[0], sqrtf(v1.x * v1.x + v1.y * v1.y) - mm[1],
                   sqrtf(v2.x * v2.x + v2.y * v2.y) - mm[2], sqrtf(v3.x * v3.x + v3.y * v3.y) - mm[3] };
    float r[4] = { v0.x, v1.x, v2.x, v3.x };
    #pragma unroll
    for (int ii = 0; ii < 4; ii++)
      #pragma unroll
      for (int jj = 0; jj < 4; jj++) { acc[ii * 4 + jj] += a[ii] * a[jj]; acc[16 + ii * 4 + jj] += r[ii] * r[jj]; }
  }
  blk_reduce<32>(acc, red);
  int tid = threadIdx.x;
  if (tid < 16) atomicAdd(&c0out[tid], (double)red[tid]);
  else if (tid < 32) atomicAdd(&crout[tid - 16], (double)red[tid]);
}
// parent dot products (one orientation b): Cx column + Crx real/imag columns
__global__ __launch_bounds__(256) void k_dots_parent(const float2* __restrict__ P, const double* pms,
                                                     const float2* __restrict__ b0, const float2* __restrict__ b1,
                                                     const float2* __restrict__ b2, const float2* __restrict__ b3,
                                                     const double* msum, int n, float invCsz,
                                                     double* cxB, double* crxB, int b) {
  __shared__ float red[48];
  float pm = (float)(pms[0] * (double)invCsz);
  float mm[4];
  #pragma unroll
  for (int k = 0; k < 4; k++) mm[k] = (float)(msum[k] * (double)invCsz);
  float acc[12];
  #pragma unroll
  for (int k = 0; k < 12; k++) acc[k] = 0.f;
  for (int i = blockIdx.x * 256 + threadIdx.x; i < n; i += gridDim.x * 256) {
    float2 p = P[i];
    float mag = sqrtf(p.x * p.x + p.y * p.y);
    float pc = mag - pm;
    float rr = 0.f, ri = 0.f;
    if (mag > 0.f) { rr = (p.y * p.y - p.x * p.x) / mag; ri = 2.f * p.x * p.y / mag; }
    float2 v[4] = { b0[i], b1[i], b2[i], b3[i] };
    #pragma unroll
    for (int ii = 0; ii < 4; ii++) {
      float a = sqrtf(v[ii].x * v[ii].x + v[ii].y * v[ii].y) - mm[ii];
      acc[ii] += a * pc;
      acc[4 + ii] += v[ii].x * rr;
      acc[8 + ii] += v[ii].x * ri;
    }
  }
  blk_reduce<12>(acc, red);
  int tid = threadIdx.x;
  if (tid < 4) atomicAdd(&cxB[tid * 4], (double)red[tid]);
  else if (tid < 8) atomicAdd(&crxB[(tid - 4) * 8 + b], (double)red[tid]);
  else if (tid < 12) atomicAdd(&crxB[(tid - 8) * 8 + 4 + b], (double)red[tid]);
}
// last scale: rcousins^T rparents(5 shifted copies of expanded lo)  (H=128)
__global__ __launch_bounds__(256) void k_dots_rpar5(const float2* __restrict__ P,
                                                    const float2* __restrict__ b0, const float2* __restrict__ b1,
                                                    const float2* __restrict__ b2, const float2* __restrict__ b3,
                                                    double* crxB) {
  __shared__ float red[80];
  float acc[20];
  #pragma unroll
  for (int k = 0; k < 20; k++) acc[k] = 0.f;
  for (int i = blockIdx.x * 256 + threadIdx.x; i < 16384; i += gridDim.x * 256) {
    int y = i >> 7, x = i & 127;
    float tt[5];
    tt[0] = P[i].x;
    tt[1] = P[(y << 7) | ((x - 1) & 127)].x;
    tt[2] = P[(y << 7) | ((x + 1) & 127)].x;
    tt[3] = P[(((y - 1) & 127) << 7) | x].x;
    tt[4] = P[(((y + 1) & 127) << 7) | x].x;
    float r[4] = { b0[i].x, b1[i].x, b2[i].x, b3[i].x };
    #pragma unroll
    for (int a = 0; a < 4; a++)
      #pragma unroll
      for (int c = 0; c < 5; c++) acc[a * 5 + c] += r[a] * tt[c];
  }
  blk_reduce<20>(acc, red);
  int tid = threadIdx.x;
  if (tid < 20) atomicAdd(&crxB[(tid / 5) * 8 + (tid % 5)], (double)red[tid]);
}
__global__ __launch_bounds__(256) void k_gram5(const float2* __restrict__ P, double* cr5) {
  __shared__ float red[100];
  float acc[25];
  #pragma unroll
  for (int k = 0; k < 25; k++) acc[k] = 0.f;
  for (int i = blockIdx.x * 256 + threadIdx.x; i < 16384; i += gridDim.x * 256) {
    int y = i >> 7, x = i & 127;
    float tt[5];
    tt[0] = P[i].x;
    tt[1] = P[(y << 7) | ((x - 1) & 127)].x;
    tt[2] = P[(y << 7) | ((x + 1) & 127)].x;
    tt[3] = P[(((y - 1) & 127) << 7) | x].x;
    tt[4] = P[(((y + 1) & 127) << 7) | x].x;
    #pragma unroll
    for (int a = 0; a < 5; a++)
      #pragma unroll
      for (int c = 0; c < 5; c++) acc[a * 5 + c] += tt[a] * tt[c];
  }
  blk_reduce<25>(acc, red);
  int tid = threadIdx.x;
  if (tid < 25) atomicAdd(&cr5[tid], (double)red[tid]);
}

// ================= finalize: write all 2456 outputs =================
__global__ __launch_bounds__(256) void k_finalize(const double* __restrict__ stg, const unsigned* __restrict__ stgu,
                                                  float* __restrict__ out) {
  int t = blockIdx.x * 256 + threadIdx.x;
  if (t >= 2456) return;
  const double N = 1048576.0;
  if (t < 6) {
    double mu = stg[SG_PIX] / N;
    double vp = stg[SG_PIX + 1] / N;
    double r;
    if (t == 0) r = mu;
    else if (t == 1) r = vp * (N / (N - 1.0));
    else if (t == 2) r = (stg[SG_PIX + 2] / N) / (vp * sqrt(vp));
    else if (t == 3) r = (stg[SG_PIX + 3] / N) / (vp * vp);
    else if (t == 4) r = (double)funkey(stgu[1]);
    else r = (double)funkey(stgu[0]);
    out[t] = (float)r;
  } else if (t < 24) {
    int i = t - 6;
    double csz;
    if (i == 0) csz = 1048576.0;
    else if (i < 17) { int s = (i - 1) >> 2; double h = (double)(1024 >> s); csz = h * h; }
    else csz = 4096.0;
    out[t] = (float)(stg[SG_MAG + i] / csz);
  } else if (t < 1320) {
    int e = t - 24;
    int b = e & 3, s = (e >> 2) & 3, o = e >> 4;
    double h = (double)(1024 >> s);
    out[t] = (float)(stg[SG_ACE + (s * 4 + b) * 81 + o] / (h * h));
  } else if (t < 1330) {
    int kurt = (t >= 1325);
    int s = t - (kurt ? 1325 : 1320);
    double h = (double)(1024 >> s); double csz = h * h;
    double vari = stg[SG_IMM + s * 3] / csz;
    double var0 = (stg[SG_PIX + 1] / N) * (N / (N - 1.0));
    double v = vari > 1e-12 ? vari : 1e-12;
    double r;
    if (vari / var0 > 1e-6)
      r = kurt ? (stg[SG_IMM + s * 3 + 2] / csz) / (v * v) : (stg[SG_IMM + s * 3 + 1] / csz) / (v * sqrt(v));
    else
      r = kurt ? 3.0 : 0.0;
    out[t] = (float)r;
  } else if (t < 1735) {
    int e = t - 1330;
    int s = e % 5, o = e / 5;
    double h = (double)(1024 >> s);
    out[t] = (float)(stg[SG_ACR + s * 81 + o] / (h * h));
  } else if (t < 1815) {
    int e = t - 1735;
    int s = e % 5, o = e / 5;
    if (s < 4) { double h = (double)(1024 >> s); out[t] = (float)(stg[SG_C0 + s * 16 + o] / (h * h)); }
    else out[t] = 0.0f;
  } else if (t < 1879) {
    int e = t - 1815;
    int s = e & 3, o = e >> 2;
    if (s < 3) { double h = (double)(1024 >> s); out[t] = (float)(stg[SG_CX + s * 16 + o] / (h * h)); }
    else out[t] = 0.0f;
  } else if (t < 2199) {
    int e = t - 1879;
    int s = e % 5, o = e / 5;
    int i = o >> 3, j = o & 7;
    float r = 0.0f;
    if (s < 4) { if (i < 4 && j < 4) { double h = (double)(1024 >> s); r = (float)(stg[SG_CR + s * 16 + i * 4 + j] / (h * h)); } }
    else { if (i < 5 && j < 5) r = (float)(stg[SG_CR5 + i * 5 + j] / 4096.0); }
    out[t] = r;
  } else if (t < 2455) {
    int e = t - 2199;
    int s = e & 3, o = e >> 2;
    int i = o >> 3, j = o & 7;
    float r = 0.0f;
    if (i < 4) {
      if (s < 3) { double h = (double)(1024 >> s); r = (float)(stg[SG_CRX + s * 32 + i * 8 + j] / (h * h)); }
      else if (j < 5) r = (float)(stg[SG_CRX + 96 + i * 8 + j] / 16384.0);
    }
    out[t] = r;
  } else {
    out[t] = (float)(stg[SG_HISQ] / N);
  }
}

// ================= host orchestration =================
static void ifft2_ip(float2* X, float2* S, int N, hipStream_t st) {
  dim3 tg(N / 32, N / 32);
  switch (N) {
#define CASE_N(NN) \
    case NN: \
      k_fft_rows<NN, true, false><<<NN, 256, 0, st>>>(X, X); \
      k_transpose<<<tg, 256, 0, st>>>(X, S, NN); \
      k_fft_rows<NN, true, false><<<NN, 256, 0, st>>>(S, S); \
      k_transpose<<<tg, 256, 0, st>>>(S, X, NN); \
      break;
    CASE_N(64) CASE_N(128) CASE_N(256) CASE_N(512) CASE_N(1024)
#undef CASE_N
    default: break;
  }
}
static inline int rb(int n) { int b = (n + 255) / 256; return b > 256 ? 256 : b; }
static inline int gb(int n) { return (n + 255) / 256; }

extern "C" void kernel_launch(void* const* d_in, const int* in_sizes, int n_in,
                              void* d_out, int out_size, void* d_ws, size_t ws_size,
                              hipStream_t stream) {
  (void)in_sizes; (void)n_in; (void)out_size;
  if (ws_size < 95076616ull) return;
  const float* img = (const float*)d_in[0];
  float* out = (float*)d_out;
  char* w = (char*)d_ws;
  float2* F  = (float2*)(w + 0ull);
  float2* L0 = (float2*)(w + 8388608ull);
  float2* L1 = (float2*)(w + 16777216ull);
  float2* L2 = (float2*)(w + 18874368ull);
  float2* L3 = (float2*)(w + 19398656ull);
  float2* L4 = (float2*)(w + 19529728ull);
  float2* S  = (float2*)(w + 19562496ull);
  float2* T  = (float2*)(w + 27951104ull);
  float2* P  = (float2*)(w + 36339712ull);
  float2* B0 = (float2*)(w + 44728320ull);
  float2* B1 = (float2*)(w + 53116928ull);
  float2* B2 = (float2*)(w + 61505536ull);
  float2* B3 = (float2*)(w + 69894144ull);
  float2* IA = (float2*)(w + 78282752ull);
  float2* IB = (float2*)(w + 86671360ull);
  double* stg = (double*)(w + 95059968ull);
  unsigned* stgu = (unsigned*)(stg + NSTG);
  float2* Lp[5] = {L0, L1, L2, L3, L4};
  float2* Bp[4] = {B0, B1, B2, B3};

  k_init<<<9, 256, 0, stream>>>(stg, stgu);
  k_pix1<<<256, 256, 0, stream>>>(img, 1048576, stg, stgu);
  k_pix2<<<256, 256, 0, stream>>>(img, 1048576, stg);

  // F = fft2(img)
  k_fft_rows<1024, false, true><<<1024, 256, 0, stream>>>(img, F);
  k_transpose<<<dim3(32, 32), 256, 0, stream>>>(F, S, 1024);
  k_fft_rows<1024, false, false><<<1024, 256, 0, stream>>>(S, S);
  k_transpose<<<dim3(32, 32), 256, 0, stream>>>(S, F, 1024);

  // hi residual: magMeans[0], vHPR0
  k_gen_hi<<<4096, 256, 0, stream>>>(F, T, 1024);
  ifft2_ip(T, S, 1024, stream);
  k_reduce_hi<<<256, 256, 0, stream>>>(T, 1048576, stg + SG_MAG, stg + SG_HISQ);

  // lowpass chain
  k_gen_L0<<<4096, 256, 0, stream>>>(F, L0, 1024);
  k_gen_Ldown<<<1024, 256, 0, stream>>>(L0, L1, 512, 0);
  k_gen_Ldown<<<256, 256, 0, stream>>>(L1, L2, 256, 0);
  k_gen_Ldown<<<64, 256, 0, stream>>>(L2, L3, 128, 0);
  k_gen_Ldown<<<16, 256, 0, stream>>>(L3, L4, 64, 1);   // DC zeroed = mean-subtracted lo resid

  // lo residual spatial -> magMeans[17]
  hipMemcpyAsync(T, L4, 64 * 64 * sizeof(float2), hipMemcpyDeviceToDevice, stream);
  ifft2_ip(T, S, 64, stream);
  k_reduce_absre<<<16, 256, 0, stream>>>(T, 4096, stg + SG_MAG + 17);

  // im chain, base scale (index 4)
  k_gen_imF4<<<16, 256, 0, stream>>>(L4, IA, 64);
  hipMemcpyAsync(T, IA, 64 * 64 * sizeof(float2), hipMemcpyDeviceToDevice, stream);
  ifft2_ip(T, S, 64, stream);
  k_reduce_im<<<16, 256, 0, stream>>>(T, 4096, stg + SG_IMM + 4 * 3);
  k_autocorr<0><<<4, 256, 0, stream>>>(T, 64, nullptr, 0.0f, stg + SG_ACR + 4 * 81);

  float2* cur = IA; float2* oth = IB;
  for (int s = 3; s >= 0; s--) {
    int H = 1024 >> s; int n = H * H;
    k_gen_imF_step<<<gb(n), 256, 0, stream>>>(cur, Lp[s], oth, H);
    hipMemcpyAsync(T, oth, (size_t)n * sizeof(float2), hipMemcpyDeviceToDevice, stream);
    ifft2_ip(T, S, H, stream);
    k_reduce_im<<<rb(n), 256, 0, stream>>>(T, n, stg + SG_IMM + s * 3);
    int nT = (H / 32) * (H / 32);
    k_autocorr<0><<<(nT > 256 ? 256 : nT), 256, 0, stream>>>(T, H, nullptr, 0.0f, stg + SG_ACR + s * 81);
    float2* tsw = cur; cur = oth; oth = tsw;
  }

  // per-scale bands + stats
  for (int s = 0; s < 4; s++) {
    int H = 1024 >> s; int n = H * H; float inv = 1.0f / (float)n;
    for (int b = 0; b < 4; b++) {
      k_gen_band<<<gb(n), 256, 0, stream>>>(Lp[s], Bp[b], H, b);
      ifft2_ip(Bp[b], S, H, stream);
    }
    k_reduce_mag4<<<rb(n), 256, 0, stream>>>(B0, B1, B2, B3, n, stg + SG_MAG + 1 + 4 * s);
    int nT = (H / 32) * (H / 32);
    for (int b = 0; b < 4; b++)
      k_autocorr<1><<<(nT > 256 ? 256 : nT), 256, 0, stream>>>(Bp[b], H, stg + SG_MAG + 1 + 4 * s + b, inv,
                                                               stg + SG_ACE + (s * 4 + b) * 81);
    k_gram4<<<rb(n), 256, 0, stream>>>(B0, B1, B2, B3, stg + SG_MAG + 1 + 4 * s, n, inv,
                                       stg + SG_C0 + s * 16, stg + SG_CR + s * 16);
    if (s < 3) {
      for (int b = 0; b < 4; b++) {
        k_gen_embed_band<<<gb(n), 256, 0, stream>>>(Lp[s + 1], P, H, b);
        ifft2_ip(P, S, H, stream);
        k_reduce_magc<<<rb(n), 256, 0, stream>>>(P, n, stg + SG_PMAG + s * 4 + b);
        k_dots_parent<<<rb(n), 256, 0, stream>>>(P, stg + SG_PMAG + s * 4 + b, B0, B1, B2, B3,
                                                 stg + SG_MAG + 1 + 4 * s, n, inv,
                                                 stg + SG_CX + s * 16 + b, stg + SG_CRX + s * 32, b);
      }
    } else {
      k_gen_embed_lo<<<64, 256, 0, stream>>>(L4, P, 128);
      ifft2_ip(P, S, 128, stream);
      k_dots_rpar5<<<64, 256, 0, stream>>>(P, B0, B1, B2, B3, stg + SG_CRX + 3 * 32);
      k_gram5<<<64, 256, 0, stream>>>(P, stg + SG_CR5);
    }
  }

  k_finalize<<<10, 256, 0, stream>>>(stg, stgu, out);
}

// Round 2
// 1248.068 us; speedup vs baseline: 2.0286x; 2.0286x over previous
//
#include <hip/hip_runtime.h>
#include <math.h>

#define PI_F      3.14159265358979323846f
#define TWOPI_F   6.28318530717958647692f
#define HALFPI_F  1.57079632679489661923f
#define ANG_F     0.8944271909999159f

// ---- staging layout (doubles) ----
#define SG_PIX   0      // sum, d2, d3, d4
#define SG_MAG   4      // 18 magnitude sums
#define SG_HISQ  22     // sum hi^2
#define SG_PMAG  23     // 12 parent-mag sums (s=0..2, b=0..3)
#define SG_IMM   35     // 5 x (sum im^2, im^3, im^4)
#define SG_ACE   50     // [4][4][81]
#define SG_ACR   1346   // [5][81]
#define SG_C0    1751   // [4][16]
#define SG_CR    1815   // [4][16]
#define SG_CX    1879   // [3][16]
#define SG_CRX   1927   // [4][4*8]
#define SG_CR5   2055   // [25]
#define NSTG     2080

enum { MA_C2 = 0, MA_REAL, MA_BAND, MA_EMBED_BAND, MA_EMBED_LO, MA_IMF4, MA_IMSTEP };
enum { WB_WRITE = 0, WB_WRITE_MAG, WB_WRITE_IM, WB_RED_HI, WB_RED_ABSRE, WB_FWD_MASK };

__device__ __forceinline__ int sfreq(int k, int H) { return (k < (H >> 1)) ? k : k - H; }
__device__ __forceinline__ int skx(int i) { return i + (i >> 4); }   // LDS bank skew

__device__ __forceinline__ float d_lograd(int fy, int fx, int H) {
  float cy = (float)fy * (2.0f / (float)H);
  float cx = (float)fx * (2.0f / (float)H);
  float rad = sqrtf(cx * cx + cy * cy);
  if (fy == 0 && fx == 0) rad = 2.0f / (float)H;   // reference DC hack
  return log2f(rad);
}
__device__ __forceinline__ float d_angle(int fy, int fx, int H) {
  return atan2f((float)fy * (2.0f / (float)H), (float)fx * (2.0f / (float)H));
}
__device__ __forceinline__ float d_rc(float x) {
  float c = fminf(fmaxf(-x, 0.0f), 1.0f);
  float t = cosf(0.5f * PI_F * c);
  return t * t;
}
__device__ __forceinline__ float d_alfa(float ang, int b) {
  float bc = (b == 0) ? 0.0f : (b == 1) ? 0.78539816339744830962f
           : (b == 2) ? 1.57079632679489661923f : 2.35619449019234492885f;
  float t = (PI_F + ang) - bc;
  float m = fmodf(t, TWOPI_F);
  if (m < 0.0f) m += TWOPI_F;
  return m - PI_F;
}
__device__ __forceinline__ float d_cos3(float a) { float c = cosf(a); return ANG_F * c * c * c; }
__device__ __forceinline__ float d_amaskC(float ang, int b) {
  float alfa = d_alfa(ang, b);
  float A = d_cos3(alfa);
  return (fabsf(alfa) < HALFPI_F) ? 2.0f * A : 0.0f;
}
__device__ __forceinline__ unsigned fkey(float f) {
  unsigned u = __float_as_uint(f);
  return (u & 0x80000000u) ? ~u : (u | 0x80000000u);
}
__device__ __forceinline__ float funkey(unsigned k) {
  return (k & 0x80000000u) ? __uint_as_float(k & 0x7FFFFFFFu) : __uint_as_float(~k);
}

template<int K>
__device__ __forceinline__ void blk_reduce(float* v, float* red) {
  int tid = threadIdx.x, wave = tid >> 6, lane = tid & 63;
  #pragma unroll
  for (int k = 0; k < K; k++) {
    float x = v[k];
    #pragma unroll
    for (int o = 32; o; o >>= 1) x += __shfl_down(x, o, 64);
    if (lane == 0) red[wave * K + k] = x;
  }
  __syncthreads();
  if (tid < K) red[tid] = red[tid] + red[K + tid] + red[2 * K + tid] + red[3 * K + tid];
}

// ================= FFT core (Stockham radix-2 in LDS, twiddle table) =================
template<int N> struct FftConst {
  static constexpr int L2N = (N == 64) ? 6 : (N == 128) ? 7 : (N == 256) ? 8 : (N == 512) ? 9 : 10;
  static constexpr int RPB = (N >= 512) ? 1 : (512 / N);
  static constexpr int TPR = (N >= 512) ? 256 : (N / 2);
  static constexpr int BUF = N + (N >> 4);
};

template<int N, bool INV>
__device__ __forceinline__ float2* fft_core(float2* A, float2* B, const float2* tw, int tr) {
  constexpr int TPR = FftConst<N>::TPR;
  constexpr int L2N = FftConst<N>::L2N;
  float2* src = A; float2* dst = B;
  #pragma unroll
  for (int st = 0; st < L2N; ++st) {
    for (int t = tr; t < (N >> 1); t += TPR) {
      int p = t >> st;
      int q = t & ((1 << st) - 1);
      float2 w = tw[p << st];
      float cv = w.x, sv = INV ? w.y : -w.y;
      float2 a = src[skx(t)];
      float2 b = src[skx(t + (N >> 1))];
      float dx = a.x - b.x, dy = a.y - b.y;
      int o0 = q + (p << (st + 1));
      dst[skx(o0)] = make_float2(a.x + b.x, a.y + b.y);
      dst[skx(o0 + (1 << st))] = make_float2(dx * cv - dy * sv, dx * sv + dy * cv);
    }
    __syncthreads();
    float2* tmp = src; src = dst; dst = tmp;
  }
  return src;
}

struct KAp {
  const float2* in;
  const float2* in2;
  float2* spec;
  float2* out[4];
  const float2* twg;
};
struct KBp {
  const float2* in[4];
  float2* out[4];
  float2* out2;
  double* red;
  double* red2;
  const float2* twg;
};
struct TPp { const float2* src[4]; float2* dst[4]; };

template<int N, int MODE>
__device__ __forceinline__ float2 loadA(const KAp& p, int row, int i, int b) {
  if constexpr (MODE == MA_C2) {
    return p.in[(size_t)row * N + i];
  } else if constexpr (MODE == MA_REAL) {
    const float* f = (const float*)p.in;
    return make_float2(f[(size_t)row * N + i], 0.0f);
  } else if constexpr (MODE == MA_BAND) {
    int fy = sfreq(i, N), fx = sfreq(row, N);
    float m = sqrtf(d_rc(d_lograd(fy, fx, N) + 1.0f)) * d_amaskC(d_angle(fy, fx, N), b);
    float2 l = p.in[(size_t)row * N + i];
    return make_float2(-l.y * m, l.x * m);
  } else if constexpr (MODE == MA_EMBED_BAND) {
    int fy = sfreq(i, N), fx = sfreq(row, N);
    int q = N >> 2, h2 = N >> 1;
    if (fy < -q || fy >= q || fx < -q || fx >= q) return make_float2(0.f, 0.f);
    int U = fx >= 0 ? fx : fx + h2, V = fy >= 0 ? fy : fy + h2;
    float m = sqrtf(d_rc(d_lograd(fy, fx, h2) + 1.0f)) * d_amaskC(d_angle(fy, fx, h2), b);
    float2 l = p.in[(size_t)U * h2 + V];
    return make_float2(-l.y * m, l.x * m);
  } else if constexpr (MODE == MA_EMBED_LO) {
    int fy = sfreq(i, N), fx = sfreq(row, N);
    int q = N >> 2, h2 = N >> 1;
    if (fy < -q || fy >= q || fx < -q || fx >= q) return make_float2(0.f, 0.f);
    int U = fx >= 0 ? fx : fx + h2, V = fy >= 0 ? fy : fy + h2;
    return p.in[(size_t)U * h2 + V];
  } else if constexpr (MODE == MA_IMF4) {
    int fy = sfreq(i, N), fx = sfreq(row, N);
    float lo = sqrtf(fmaxf(1.0f - d_rc(d_lograd(fy, fx, N)), 0.0f));
    float2 v = p.in[(size_t)row * N + i];
    return make_float2(v.x * lo, v.y * lo);
  } else {  // MA_IMSTEP
    int fy = sfreq(i, N), fx = sfreq(row, N);
    int q = N >> 2, h2 = N >> 1;
    float2 v = make_float2(0.f, 0.f);
    if (fy >= -q && fy < q && fx >= -q && fx < q) {
      int U = fx >= 0 ? fx : fx + h2, V = fy >= 0 ? fy : fy + h2;
      int nfy = (fy == -q) ? fy : -fy, nfx = (fx == -q) ? fx : -fx;
      int NU = nfx >= 0 ? nfx : nfx + h2, NV = nfy >= 0 ? nfy : nfy + h2;
      float2 a = p.in[(size_t)U * h2 + V];
      float2 bb = p.in[(size_t)NU * h2 + NV];
      v = make_float2(0.5f * (a.x + bb.x), 0.5f * (a.y - bb.y));
    }
    float lr = d_lograd(fy, fx, N);
    float hm2 = d_rc(lr + 1.0f);
    float lo0 = sqrtf(fmaxf(1.0f - d_rc(lr), 0.0f));
    float ang1 = d_angle(fy, fx, N);
    int gfy = (fy == -(N >> 1)) ? fy : -fy;
    int gfx = (fx == -(N >> 1)) ? fx : -fx;
    float ang2 = d_angle(gfy, gfx, N);
    float msum = 0.0f;
    #pragma unroll
    for (int b4 = 0; b4 < 4; b4++) {
      float a1 = d_alfa(ang1, b4), a2 = d_alfa(ang2, b4);
      float A1 = d_cos3(a1), A2 = d_cos3(a2);
      float T1 = (fabsf(a1) < HALFPI_F) ? A1 : 0.0f;
      float T2 = (fabsf(a2) < HALFPI_F) ? A2 : 0.0f;
      msum += A1 * (T1 - T2);
    }
    float mm = lo0 * hm2 * msum;
    float2 l = p.in2[(size_t)row * N + i];
    return make_float2(v.x + l.x * mm, v.y + l.y * mm);
  }
}

// pass A: fused load op -> FFT -> write natural
template<int N, bool INV, int MODE, bool SPEC>
__global__ __launch_bounds__(256) void k_ffta(KAp p) {
  using FC = FftConst<N>;
  __shared__ float2 shA[FC::RPB][FC::BUF];
  __shared__ float2 shB[FC::RPB][FC::BUF];
  __shared__ float2 tw[N / 2];
  int tid = threadIdx.x;
  for (int k = tid; k < N / 2; k += 256) tw[k] = p.twg[k << (10 - FC::L2N)];
  int rl = tid / FC::TPR;
  int tr = tid % FC::TPR;
  int row = blockIdx.x * FC::RPB + rl;
  int b = blockIdx.y;
  float2* A = shA[rl];
  for (int i = tr; i < N; i += FC::TPR) {
    float2 v = loadA<N, MODE>(p, row, i, b);
    if constexpr (SPEC) p.spec[(size_t)row * N + i] = v;
    A[skx(i)] = v;
  }
  __syncthreads();
  float2* res = fft_core<N, INV>(A, shB[rl], tw, tr);
  constexpr float sc = INV ? 1.0f / (float)N : 1.0f;
  float2* o = p.out[b] + (size_t)row * N;
  for (int i = tr; i < N; i += FC::TPR) {
    float2 v = res[skx(i)];
    o[i] = make_float2(v.x * sc, v.y * sc);
  }
}

// pass B: plain load -> FFT -> write/reduce
template<int N, bool INV, int WMODE>
__global__ __launch_bounds__(256) void k_fftb(KBp p) {
  using FC = FftConst<N>;
  __shared__ float2 shA[FC::RPB][FC::BUF];
  __shared__ float2 shB[FC::RPB][FC::BUF];
  __shared__ float2 tw[N / 2];
  __shared__ float red[12];
  int tid = threadIdx.x;
  for (int k = tid; k < N / 2; k += 256) tw[k] = p.twg[k << (10 - FC::L2N)];
  int rl = tid / FC::TPR;
  int tr = tid % FC::TPR;
  int row = blockIdx.x * FC::RPB + rl;
  int plane = blockIdx.y;
  const float2* in = p.in[plane] + (size_t)row * N;
  float2* A = shA[rl];
  for (int i = tr; i < N; i += FC::TPR) A[skx(i)] = in[i];
  __syncthreads();
  float2* res = fft_core<N, INV>(A, shB[rl], tw, tr);
  constexpr float sc = INV ? 1.0f / (float)N : 1.0f;
  if constexpr (WMODE == WB_WRITE || WMODE == WB_WRITE_MAG || WMODE == WB_WRITE_IM) {
    float2* o = p.out[plane] + (size_t)row * N;
    float a0 = 0.f, a1 = 0.f, a2 = 0.f;
    for (int i = tr; i < N; i += FC::TPR) {
      float2 v = res[skx(i)];
      v.x *= sc; v.y *= sc;
      o[i] = v;
      if constexpr (WMODE == WB_WRITE_MAG) a0 += sqrtf(v.x * v.x + v.y * v.y);
      if constexpr (WMODE == WB_WRITE_IM) { float v2 = v.x * v.x; a0 += v2; a1 += v2 * v.x; a2 += v2 * v2; }
    }
    if constexpr (WMODE == WB_WRITE_MAG) {
      float acc[1] = {a0}; blk_reduce<1>(acc, red);
      if (tid == 0) atomicAdd(&p.red[plane], (double)red[0]);
    }
    if constexpr (WMODE == WB_WRITE_IM) {
      float acc[3] = {a0, a1, a2}; blk_reduce<3>(acc, red);
      if (tid < 3) atomicAdd(&p.red[tid], (double)red[tid]);
    }
  } else if constexpr (WMODE == WB_RED_HI) {
    float a0 = 0.f, a1 = 0.f;
    for (int i = tr; i < N; i += FC::TPR) {
      float v = res[skx(i)].x * sc;
      a0 += fabsf(v); a1 += v * v;
    }
    float acc[2] = {a0, a1}; blk_reduce<2>(acc, red);
    if (tid == 0) atomicAdd(p.red, (double)red[0]);
    if (tid == 1) atomicAdd(p.red2, (double)red[1]);
  } else if constexpr (WMODE == WB_RED_ABSRE) {
    float a0 = 0.f;
    for (int i = tr; i < N; i += FC::TPR) a0 += fabsf(res[skx(i)].x * sc);
    float acc[1] = {a0}; blk_reduce<1>(acc, red);
    if (tid == 0) atomicAdd(p.red, (double)red[0]);
  } else {  // WB_FWD_MASK
    float2* o1 = p.out[0] + (size_t)row * N;
    float2* o2 = p.out2 + (size_t)row * N;
    int fx = sfreq(row, N);
    for (int i = tr; i < N; i += FC::TPR) {
      float2 v = res[skx(i)];
      int fy = sfreq(i, N);
      float rcv = d_rc(d_lograd(fy, fx, N));
      float hi = sqrtf(rcv), lo = sqrtf(fmaxf(1.0f - rcv, 0.0f));
      o1[i] = make_float2(v.x * hi, v.y * hi);
      o2[i] = make_float2(v.x * lo, v.y * lo);
    }
  }
}

__global__ __launch_bounds__(256) void k_transpose(TPp p, int N) {
  __shared__ float2 tile[32][33];
  int z = blockIdx.z;
  const float2* in = p.src[z];
  float2* out = p.dst[z];
  int bx = blockIdx.x << 5, by = blockIdx.y << 5;
  int tx = threadIdx.x & 31, ty = threadIdx.x >> 5;
  for (int r = ty; r < 32; r += 8) tile[r][tx] = in[(size_t)(by + r) * N + bx + tx];
  __syncthreads();
  for (int r = ty; r < 32; r += 8) out[(size_t)(bx + r) * N + by + tx] = tile[tx][r];
}

// crop freq domain [-Hn/2, Hn/2) from big (2*Hn) grid, multiply native lo mask
__global__ __launch_bounds__(256) void k_gen_Ldown(const float2* __restrict__ Lb, float2* __restrict__ Ls, int Hn, int zdc) {
  int i = blockIdx.x * 256 + threadIdx.x;
  if (i >= Hn * Hn) return;
  int fy = sfreq(i / Hn, Hn), fx = sfreq(i % Hn, Hn);
  int Hb = Hn << 1;
  int by = fy >= 0 ? fy : fy + Hb;
  int bx = fx >= 0 ? fx : fx + Hb;
  float lo = sqrtf(fmaxf(1.0f - d_rc(d_lograd(fy, fx, Hn)), 0.0f));
  float2 v = Lb[(size_t)by * Hb + bx];
  if (zdc && i == 0) { Ls[0] = make_float2(0.f, 0.f); return; }
  Ls[i] = make_float2(v.x * lo, v.y * lo);
}

// ================= reductions / stats =================
__global__ __launch_bounds__(256) void k_init(double* stg, unsigned* stgu, float2* Wg) {
  int i = blockIdx.x * 256 + threadIdx.x;
  if (i < NSTG) stg[i] = 0.0;
  if (i == 0) { stgu[0] = 0u; stgu[1] = 0xFFFFFFFFu; }
  if (i < 512) {
    float a = TWOPI_F * (float)i * (1.0f / 1024.0f);
    float sv, cv; sincosf(a, &sv, &cv);
    Wg[i] = make_float2(cv, sv);
  }
}
__global__ __launch_bounds__(256) void k_pix1(const float* __restrict__ x, int n, double* stg, unsigned* stgu) {
  __shared__ float red[4];
  float s = 0.f, mn = 3.402823466e38f, mx = -3.402823466e38f;
  for (int i = blockIdx.x * 256 + threadIdx.x; i < n; i += gridDim.x * 256) {
    float v = x[i]; s += v; mn = fminf(mn, v); mx = fmaxf(mx, v);
  }
  float acc[1] = {s};
  blk_reduce<1>(acc, red);
  if (threadIdx.x == 0) atomicAdd(&stg[SG_PIX], (double)red[0]);
  #pragma unroll
  for (int o = 32; o; o >>= 1) { mn = fminf(mn, __shfl_down(mn, o, 64)); mx = fmaxf(mx, __shfl_down(mx, o, 64)); }
  if ((threadIdx.x & 63) == 0) { atomicMin(&stgu[1], fkey(mn)); atomicMax(&stgu[0], fkey(mx)); }
}
__global__ __launch_bounds__(256) void k_pix2(const float* __restrict__ x, int n, double* stg) {
  __shared__ float red[12];
  float mu = (float)(stg[SG_PIX] / (double)n);
  float a2 = 0.f, a3 = 0.f, a4 = 0.f;
  for (int i = blockIdx.x * 256 + threadIdx.x; i < n; i += gridDim.x * 256) {
    float d = x[i] - mu; float d2 = d * d; a2 += d2; a3 += d2 * d; a4 += d2 * d2;
  }
  float acc[3] = {a2, a3, a4};
  blk_reduce<3>(acc, red);
  if (threadIdx.x < 3) atomicAdd(&stg[SG_PIX + 1 + threadIdx.x], (double)red[threadIdx.x]);
}

struct ACp { const float2* in[4]; };
template<int MODE>   // 0: real part; 1: |complex| - mean
__global__ __launch_bounds__(256) void k_autocorr(ACp p, int H, const double* msum, float invCsz, double* gacc) {
  __shared__ float tile[40][40];
  __shared__ float accL[81];
  int plane = blockIdx.y;
  const float2* in = p.in[plane];
  double* g = gacc + plane * 81;
  float mean = 0.f;
  if constexpr (MODE == 1) mean = (float)(msum[plane] * (double)invCsz);
  if (threadIdx.x < 81) accL[threadIdx.x] = 0.f;
  int nT = (H >> 5) * (H >> 5);
  for (int ti = blockIdx.x; ti < nT; ti += gridDim.x) {
    __syncthreads();
    int by = (ti / (H >> 5)) << 5, bx = (ti % (H >> 5)) << 5;
    for (int ii = threadIdx.x; ii < 1600; ii += 256) {
      int r = ii / 40, c = ii - r * 40;
      int gy = (by + r - 4) & (H - 1), gx = (bx + c - 4) & (H - 1);
      float2 v = in[(size_t)gy * H + gx];
      float val;
      if constexpr (MODE == 1) val = sqrtf(v.x * v.x + v.y * v.y) - mean;
      else val = v.x;
      tile[r][c] = val;
    }
    __syncthreads();
    int tx = threadIdx.x & 31, ty = threadIdx.x >> 5;
    float cen[4];
    #pragma unroll
    for (int r = 0; r < 4; r++) cen[r] = tile[ty + 8 * r + 4][tx + 4];
    for (int o = 0; o < 81; o++) {
      int dy = o / 9 - 4, dx = o - (o / 9) * 9 - 4;
      float ss = 0.f;
      #pragma unroll
      for (int r = 0; r < 4; r++) ss += cen[r] * tile[ty + 8 * r + 4 + dy][tx + 4 + dx];
      #pragma unroll
      for (int ofs = 32; ofs; ofs >>= 1) ss += __shfl_down(ss, ofs, 64);
      if ((threadIdx.x & 63) == 0) atomicAdd(&accL[o], ss);
    }
  }
  __syncthreads();
  if (threadIdx.x < 81) atomicAdd(&g[threadIdx.x], (double)accL[threadIdx.x]);
}

__global__ __launch_bounds__(256) void k_gram4(const float2* __restrict__ b0, const float2* __restrict__ b1,
                                               const float2* __restrict__ b2, const float2* __restrict__ b3,
                                               const double* msum, int n, float invCsz,
                                               double* c0out, double* crout) {
  __shared__ float red[128];
  float mm[4];
  #pragma unroll
  for (int k = 0; k < 4; k++) mm[k] = (float)(msum[k] * (double)invCsz);
  float acc[32];
  #pragma unroll
  for (int k = 0; k < 32; k++) acc[k] = 0.f;
  for (int i = blockIdx.x * 256 + threadIdx.x; i < n; i += gridDim.x * 256) {
    float2 v0 = b0[i], v1 = b1[i], v2 = b2[i], v3 = b3[i];
    float a[4] = { sqrtf(v0.x * v0.x + v0.y * v0.y) - mm[0], sqrtf(v1.x * v1.x + v1.y * v1.y) - mm[1],
                   sqrtf(v2.x * v2.x + v2.y * v2.y) - mm[2], sqrtf(v3.x * v3.x + v3.y * v3.y) - mm[3] };
    float r[4] = { v0.x, v1.x, v2.x, v3.x };
    #pragma unroll
    for (int ii = 0; ii < 4; ii++)
      #pragma unroll
      for (int jj = 0; jj < 4; jj++) { acc[ii * 4 + jj] += a[ii] * a[jj]; acc[16 + ii * 4 + jj] += r[ii] * r[jj]; }
  }
  blk_reduce<32>(acc, red);
  int tid = threadIdx.x;
  if (tid < 16) atomicAdd(&c0out[tid], (double)red[tid]);
  else if (tid < 32) atomicAdd(&crout[tid - 16], (double)red[tid]);
}

struct DTp { const float2* P[4]; const float2* B[4]; };
__global__ __launch_bounds__(256) void k_dots_all(DTp p, const double* pms, const double* bms,
                                                  int n, float inv, double* cx, double* crx) {
  __shared__ float red[192];
  float pm[4], mm[4];
  #pragma unroll
  for (int k = 0; k < 4; k++) { pm[k] = (float)(pms[k] * (double)inv); mm[k] = (float)(bms[k] * (double)inv); }
  float acc[48];
  #pragma unroll
  for (int k = 0; k < 48; k++) acc[k] = 0.f;
  for (int i = blockIdx.x * 256 + threadIdx.x; i < n; i += gridDim.x * 256) {
    float a[4], re[4];
    #pragma unroll
    for (int c = 0; c < 4; c++) { float2 v = p.B[c][i]; a[c] = sqrtf(v.x * v.x + v.y * v.y) - mm[c]; re[c] = v.x; }
    #pragma unroll
    for (int b = 0; b < 4; b++) {
      float2 q = p.P[b][i];
      float mag = sqrtf(q.x * q.x + q.y * q.y);
      float pc = mag - pm[b];
      float rr = 0.f, ri = 0.f;
      if (mag > 0.f) { rr = (q.y * q.y - q.x * q.x) / mag; ri = 2.f * q.x * q.y / mag; }
      #pragma unroll
      for (int c = 0; c < 4; c++) {
        acc[b * 4 + c] += a[c] * pc;
        acc[16 + b * 4 + c] += re[c] * rr;
        acc[32 + b * 4 + c] += re[c] * ri;
      }
    }
  }
  blk_reduce<48>(acc, red);
  int tid = threadIdx.x;
  if (tid < 48) {
    int grp = tid >> 4, t = tid & 15, b = t >> 2, c = t & 3;
    double v = (double)red[tid];
    if (grp == 0) atomicAdd(&cx[c * 4 + b], v);
    else if (grp == 1) atomicAdd(&crx[c * 8 + b], v);
    else atomicAdd(&crx[c * 8 + 4 + b], v);
  }
}

__global__ __launch_bounds__(256) void k_dots_rpar5(const float2* __restrict__ P,
                                                    const float2* __restrict__ b0, const float2* __restrict__ b1,
                                                    const float2* __restrict__ b2, const float2* __restrict__ b3,
                                                    double* crxB) {
  __shared__ float red[80];
  float acc[20];
  #pragma unroll
  for (int k = 0; k < 20; k++) acc[k] = 0.f;
  for (int i = blockIdx.x * 256 + threadIdx.x; i < 16384; i += gridDim.x * 256) {
    int y = i >> 7, x = i & 127;
    float tt[5];
    tt[0] = P[i].x;
    tt[1] = P[(y << 7) | ((x - 1) & 127)].x;
    tt[2] = P[(y << 7) | ((x + 1) & 127)].x;
    tt[3] = P[(((y - 1) & 127) << 7) | x].x;
    tt[4] = P[(((y + 1) & 127) << 7) | x].x;
    float r[4] = { b0[i].x, b1[i].x, b2[i].x, b3[i].x };
    #pragma unroll
    for (int a = 0; a < 4; a++)
      #pragma unroll
      for (int c = 0; c < 5; c++) acc[a * 5 + c] += r[a] * tt[c];
  }
  blk_reduce<20>(acc, red);
  int tid = threadIdx.x;
  if (tid < 20) atomicAdd(&crxB[(tid / 5) * 8 + (tid % 5)], (double)red[tid]);
}
__global__ __launch_bounds__(256) void k_gram5(const float2* __restrict__ P, double* cr5) {
  __shared__ float red[100];
  float acc[25];
  #pragma unroll
  for (int k = 0; k < 25; k++) acc[k] = 0.f;
  for (int i = blockIdx.x * 256 + threadIdx.x; i < 16384; i += gridDim.x * 256) {
    int y = i >> 7, x = i & 127;
    float tt[5];
    tt[0] = P[i].x;
    tt[1] = P[(y << 7) | ((x - 1) & 127)].x;
    tt[2] = P[(y << 7) | ((x + 1) & 127)].x;
    tt[3] = P[(((y - 1) & 127) << 7) | x].x;
    tt[4] = P[(((y + 1) & 127) << 7) | x].x;
    #pragma unroll
    for (int a = 0; a < 5; a++)
      #pragma unroll
      for (int c = 0; c < 5; c++) acc[a * 5 + c] += tt[a] * tt[c];
  }
  blk_reduce<25>(acc, red);
  int tid = threadIdx.x;
  if (tid < 25) atomicAdd(&cr5[tid], (double)red[tid]);
}

// ================= finalize: write all 2456 outputs =================
__global__ __launch_bounds__(256) void k_finalize(const double* __restrict__ stg, const unsigned* __restrict__ stgu,
                                                  float* __restrict__ out) {
  int t = blockIdx.x * 256 + threadIdx.x;
  if (t >= 2456) return;
  const double N = 1048576.0;
  if (t < 6) {
    double mu = stg[SG_PIX] / N;
    double vp = stg[SG_PIX + 1] / N;
    double r;
    if (t == 0) r = mu;
    else if (t == 1) r = vp * (N / (N - 1.0));
    else if (t == 2) r = (stg[SG_PIX + 2] / N) / (vp * sqrt(vp));
    else if (t == 3) r = (stg[SG_PIX + 3] / N) / (vp * vp);
    else if (t == 4) r = (double)funkey(stgu[1]);
    else r = (double)funkey(stgu[0]);
    out[t] = (float)r;
  } else if (t < 24) {
    int i = t - 6;
    double csz;
    if (i == 0) csz = 1048576.0;
    else if (i < 17) { int s = (i - 1) >> 2; double h = (double)(1024 >> s); csz = h * h; }
    else csz = 4096.0;
    out[t] = (float)(stg[SG_MAG + i] / csz);
  } else if (t < 1320) {
    int e = t - 24;
    int b = e & 3, s = (e >> 2) & 3, o = e >> 4;
    double h = (double)(1024 >> s);
    out[t] = (float)(stg[SG_ACE + (s * 4 + b) * 81 + o] / (h * h));
  } else if (t < 1330) {
    int kurt = (t >= 1325);
    int s = t - (kurt ? 1325 : 1320);
    double h = (double)(1024 >> s); double csz = h * h;
    double vari = stg[SG_IMM + s * 3] / csz;
    double var0 = (stg[SG_PIX + 1] / N) * (N / (N - 1.0));
    double v = vari > 1e-12 ? vari : 1e-12;
    double r;
    if (vari / var0 > 1e-6)
      r = kurt ? (stg[SG_IMM + s * 3 + 2] / csz) / (v * v) : (stg[SG_IMM + s * 3 + 1] / csz) / (v * sqrt(v));
    else
      r = kurt ? 3.0 : 0.0;
    out[t] = (float)r;
  } else if (t < 1735) {
    int e = t - 1330;
    int s = e % 5, o = e / 5;
    double h = (double)(1024 >> s);
    out[t] = (float)(stg[SG_ACR + s * 81 + o] / (h * h));
  } else if (t < 1815) {
    int e = t - 1735;
    int s = e % 5, o = e / 5;
    if (s < 4) { double h = (double)(1024 >> s); out[t] = (float)(stg[SG_C0 + s * 16 + o] / (h * h)); }
    else out[t] = 0.0f;
  } else if (t < 1879) {
    int e = t - 1815;
    int s = e & 3, o = e >> 2;
    if (s < 3) { double h = (double)(1024 >> s); out[t] = (float)(stg[SG_CX + s * 16 + o] / (h * h)); }
    else out[t] = 0.0f;
  } else if (t < 2199) {
    int e = t - 1879;
    int s = e % 5, o = e / 5;
    int i = o >> 3, j = o & 7;
    float r = 0.0f;
    if (s < 4) { if (i < 4 && j < 4) { double h = (double)(1024 >> s); r = (float)(stg[SG_CR + s * 16 + i * 4 + j] / (h * h)); } }
    else { if (i < 5 && j < 5) r = (float)(stg[SG_CR5 + i * 5 + j] / 4096.0); }
    out[t] = r;
  } else if (t < 2455) {
    int e = t - 2199;
    int s = e & 3, o = e >> 2;
    int i = o >> 3, j = o & 7;
    float r = 0.0f;
    if (i < 4) {
      if (s < 3) { double h = (double)(1024 >> s); r = (float)(stg[SG_CRX + s * 32 + i * 8 + j] / (h * h)); }
      else if (j < 5) r = (float)(stg[SG_CRX + 96 + i * 8 + j] / 16384.0);
    }
    out[t] = r;
  } else {
    out[t] = (float)(stg[SG_HISQ] / N);
  }
}

// ================= host orchestration =================
static inline int rb(int n) { int b = (n + 255) / 256; return b > 256 ? 256 : b; }

struct Bufs {
  const float* img;
  float2 *L[5], *X[4], *Xh[4], *Y[4], *Wg;
  double* stg; unsigned* stgu;
  float* out;
};

template<int N>
static void im_step_t(const Bufs& B, int s, const float2* IA, float2* IB, hipStream_t st) {
  constexpr int RPB = FftConst<N>::RPB;
  { KAp a{}; a.in = IA; a.in2 = B.L[s]; a.spec = IB; a.out[0] = B.X[0]; a.twg = B.Wg;
    k_ffta<N, true, MA_IMSTEP, true><<<dim3(N / RPB, 1), 256, 0, st>>>(a); }
  { TPp t{}; t.src[0] = B.X[0]; t.dst[0] = B.X[1];
    k_transpose<<<dim3(N / 32, N / 32, 1), 256, 0, st>>>(t, N); }
  { KBp b{}; b.in[0] = B.X[1]; b.out[0] = B.X[0]; b.red = B.stg + SG_IMM + s * 3; b.twg = B.Wg;
    k_fftb<N, true, WB_WRITE_IM><<<dim3(N / RPB, 1), 256, 0, st>>>(b); }
  int nT = (N / 32) * (N / 32);
  { ACp c{}; c.in[0] = B.X[0];
    k_autocorr<0><<<dim3(nT > 256 ? 256 : nT, 1), 256, 0, st>>>(c, N, nullptr, 0.f, B.stg + SG_ACR + s * 81); }
}

template<int N>
static void band_phase_t(const Bufs& B, int s, hipStream_t st) {
  constexpr int RPB = FftConst<N>::RPB;
  int n = N * N; float inv = 1.f / (float)n;
  int nT = (N / 32) * (N / 32); int acb = nT > 256 ? 256 : nT;
  { KAp a{}; a.in = B.L[s]; a.twg = B.Wg;
    for (int k = 0; k < 4; k++) a.out[k] = B.X[k];
    k_ffta<N, true, MA_BAND, false><<<dim3(N / RPB, 4), 256, 0, st>>>(a); }
  { TPp t{}; for (int k = 0; k < 4; k++) { t.src[k] = B.X[k]; t.dst[k] = B.Y[k]; }
    k_transpose<<<dim3(N / 32, N / 32, 4), 256, 0, st>>>(t, N); }
  { KBp b{}; for (int k = 0; k < 4; k++) { b.in[k] = B.Y[k]; b.out[k] = B.Y[k]; }
    b.red = B.stg + SG_MAG + 1 + 4 * s; b.twg = B.Wg;
    k_fftb<N, true, WB_WRITE_MAG><<<dim3(N / RPB, 4), 256, 0, st>>>(b); }
  { ACp c{}; for (int k = 0; k < 4; k++) c.in[k] = B.Y[k];
    k_autocorr<1><<<dim3(acb, 4), 256, 0, st>>>(c, N, B.stg + SG_MAG + 1 + 4 * s, inv, B.stg + SG_ACE + s * 4 * 81); }
  k_gram4<<<rb(n), 256, 0, st>>>(B.Y[0], B.Y[1], B.Y[2], B.Y[3], B.stg + SG_MAG + 1 + 4 * s, n, inv,
                                 B.stg + SG_C0 + s * 16, B.stg + SG_CR + s * 16);
  if constexpr (N > 128) {
    { KAp a{}; a.in = B.L[s + 1]; a.twg = B.Wg;
      for (int k = 0; k < 4; k++) a.out[k] = B.X[k];
      k_ffta<N, true, MA_EMBED_BAND, false><<<dim3(N / RPB, 4), 256, 0, st>>>(a); }
    float2* P[4];
    if (s == 0) {
      const float2* srcs[4] = {B.X[0], B.X[1], B.X[2], B.X[3]};
      float2* dsts[4] = {B.L[0], B.X[0], B.X[1], B.X[2]};
      for (int k = 0; k < 4; k++) {
        TPp t{}; t.src[0] = srcs[k]; t.dst[0] = dsts[k];
        k_transpose<<<dim3(N / 32, N / 32, 1), 256, 0, st>>>(t, N);
      }
      P[0] = B.L[0]; P[1] = B.X[0]; P[2] = B.X[1]; P[3] = B.X[2];
    } else {
      TPp t{}; for (int k = 0; k < 4; k++) { t.src[k] = B.X[k]; t.dst[k] = B.Xh[k]; }
      k_transpose<<<dim3(N / 32, N / 32, 4), 256, 0, st>>>(t, N);
      for (int k = 0; k < 4; k++) P[k] = B.Xh[k];
    }
    { KBp b{}; for (int k = 0; k < 4; k++) { b.in[k] = P[k]; b.out[k] = P[k]; }
      b.red = B.stg + SG_PMAG + 4 * s; b.twg = B.Wg;
      k_fftb<N, true, WB_WRITE_MAG><<<dim3(N / RPB, 4), 256, 0, st>>>(b); }
    { DTp d{}; for (int k = 0; k < 4; k++) { d.P[k] = P[k]; d.B[k] = B.Y[k]; }
      k_dots_all<<<rb(n), 256, 0, st>>>(d, B.stg + SG_PMAG + 4 * s, B.stg + SG_MAG + 1 + 4 * s, n, inv,
                                        B.stg + SG_CX + s * 16, B.stg + SG_CRX + s * 32); }
  } else {
    { KAp a{}; a.in = B.L[4]; a.twg = B.Wg; a.out[0] = B.X[0];
      k_ffta<128, true, MA_EMBED_LO, false><<<dim3(128 / FftConst<128>::RPB, 1), 256, 0, st>>>(a); }
    { TPp t{}; t.src[0] = B.X[0]; t.dst[0] = B.X[1];
      k_transpose<<<dim3(4, 4, 1), 256, 0, st>>>(t, 128); }
    { KBp b{}; b.in[0] = B.X[1]; b.out[0] = B.X[0]; b.twg = B.Wg;
      k_fftb<128, true, WB_WRITE><<<dim3(128 / FftConst<128>::RPB, 1), 256, 0, st>>>(b); }
    k_dots_rpar5<<<64, 256, 0, st>>>(B.X[0], B.Y[0], B.Y[1], B.Y[2], B.Y[3], B.stg + SG_CRX + 96);
    k_gram5<<<64, 256, 0, st>>>(B.X[0], B.stg + SG_CR5);
  }
}

extern "C" void kernel_launch(void* const* d_in, const int* in_sizes, int n_in,
                              void* d_out, int out_size, void* d_ws, size_t ws_size,
                              hipStream_t stream) {
  (void)in_sizes; (void)n_in; (void)out_size;
  if (ws_size < 78643200ull) return;
  char* w = (char*)d_ws;
  Bufs B;
  B.img = (const float*)d_in[0];
  B.out = (float*)d_out;
  B.L[0] = (float2*)(w + 0ull);
  B.L[1] = (float2*)(w + 8388608ull);
  B.L[2] = (float2*)(w + 10485760ull);
  B.L[3] = (float2*)(w + 11010048ull);
  B.L[4] = (float2*)(w + 11141120ull);
  B.Wg   = (float2*)(w + 11173888ull);
  B.stg  = (double*)(w + 11177984ull);
  B.stgu = (unsigned*)(B.stg + NSTG);
  B.X[0] = (float2*)(w + 11534336ull);
  B.X[1] = (float2*)(w + 19922944ull);
  B.X[2] = (float2*)(w + 28311552ull);
  B.X[3] = (float2*)(w + 36700160ull);
  for (int k = 0; k < 4; k++) B.Xh[k] = (float2*)((char*)B.X[k] + 4194304ull);
  B.Y[0] = (float2*)(w + 45088768ull);
  B.Y[1] = (float2*)(w + 53477376ull);
  B.Y[2] = (float2*)(w + 61865984ull);
  B.Y[3] = (float2*)(w + 70254592ull);
  hipStream_t st = stream;
  double* stg = B.stg;

  k_init<<<9, 256, 0, st>>>(stg, B.stgu, B.Wg);
  k_pix1<<<256, 256, 0, st>>>(B.img, 1048576, stg, B.stgu);
  k_pix2<<<256, 256, 0, st>>>(B.img, 1048576, stg);

  // forward fft2: img -> transposed spectrum; fused write of Thi (X2) and L0
  { KAp a{}; a.in = (const float2*)B.img; a.out[0] = B.X[0]; a.twg = B.Wg;
    k_ffta<1024, false, MA_REAL, false><<<dim3(1024, 1), 256, 0, st>>>(a); }
  { TPp t{}; t.src[0] = B.X[0]; t.dst[0] = B.X[1];
    k_transpose<<<dim3(32, 32, 1), 256, 0, st>>>(t, 1024); }
  { KBp b{}; b.in[0] = B.X[1]; b.out[0] = B.X[2]; b.out2 = B.L[0]; b.twg = B.Wg;
    k_fftb<1024, false, WB_FWD_MASK><<<dim3(1024, 1), 256, 0, st>>>(b); }

  // hi residual: ifft2 of Thi, reduce-only final pass (sum |re|, re^2)
  { KAp a{}; a.in = B.X[2]; a.out[0] = B.X[0]; a.twg = B.Wg;
    k_ffta<1024, true, MA_C2, false><<<dim3(1024, 1), 256, 0, st>>>(a); }
  { TPp t{}; t.src[0] = B.X[0]; t.dst[0] = B.X[1];
    k_transpose<<<dim3(32, 32, 1), 256, 0, st>>>(t, 1024); }
  { KBp b{}; b.in[0] = B.X[1]; b.red = stg + SG_MAG; b.red2 = stg + SG_HISQ; b.twg = B.Wg;
    k_fftb<1024, true, WB_RED_HI><<<dim3(1024, 1), 256, 0, st>>>(b); }

  // lowpass chain
  k_gen_Ldown<<<1024, 256, 0, st>>>(B.L[0], B.L[1], 512, 0);
  k_gen_Ldown<<<256, 256, 0, st>>>(B.L[1], B.L[2], 256, 0);
  k_gen_Ldown<<<64, 256, 0, st>>>(B.L[2], B.L[3], 128, 0);
  k_gen_Ldown<<<16, 256, 0, st>>>(B.L[3], B.L[4], 64, 1);   // DC zeroed = mean-subtracted lo resid

  // lo residual spatial -> magMeans[17] (reduce-only)
  { KAp a{}; a.in = B.L[4]; a.out[0] = B.X[0]; a.twg = B.Wg;
    k_ffta<64, true, MA_C2, false><<<dim3(8, 1), 256, 0, st>>>(a); }
  { TPp t{}; t.src[0] = B.X[0]; t.dst[0] = B.X[1];
    k_transpose<<<dim3(2, 2, 1), 256, 0, st>>>(t, 64); }
  { KBp b{}; b.in[0] = B.X[1]; b.red = stg + SG_MAG + 17; b.twg = B.Wg;
    k_fftb<64, true, WB_RED_ABSRE><<<dim3(8, 1), 256, 0, st>>>(b); }

  // im chain base: imF4 = L4 * lo0, spectrum echoed to X2 (=IA)
  { KAp a{}; a.in = B.L[4]; a.spec = B.X[2]; a.out[0] = B.X[0]; a.twg = B.Wg;
    k_ffta<64, true, MA_IMF4, true><<<dim3(8, 1), 256, 0, st>>>(a); }
  { TPp t{}; t.src[0] = B.X[0]; t.dst[0] = B.X[1];
    k_transpose<<<dim3(2, 2, 1), 256, 0, st>>>(t, 64); }
  { KBp b{}; b.in[0] = B.X[1]; b.out[0] = B.X[0]; b.red = stg + SG_IMM + 12; b.twg = B.Wg;
    k_fftb<64, true, WB_WRITE_IM><<<dim3(8, 1), 256, 0, st>>>(b); }
  { ACp c{}; c.in[0] = B.X[0];
    k_autocorr<0><<<dim3(4, 1), 256, 0, st>>>(c, 64, nullptr, 0.f, stg + SG_ACR + 4 * 81); }

  // im steps s=3..0 (IA/IB alternate X2/X3)
  im_step_t<128>(B, 3, B.X[2], B.X[3], st);
  im_step_t<256>(B, 2, B.X[3], B.X[2], st);
  im_step_t<512>(B, 1, B.X[2], B.X[3], st);
  im_step_t<1024>(B, 0, B.X[3], B.X[2], st);

  // band phases
  band_phase_t<1024>(B, 0, st);
  band_phase_t<512>(B, 1, st);
  band_phase_t<256>(B, 2, st);
  band_phase_t<128>(B, 3, st);

  k_finalize<<<10, 256, 0, st>>>(stg, B.stgu, B.out);
}

// Round 3
// 1049.084 us; speedup vs baseline: 2.4134x; 1.1897x over previous
//
#include <hip/hip_runtime.h>
#include <math.h>

#define PI_F      3.14159265358979323846f
#define TWOPI_F   6.28318530717958647692f
#define HALFPI_F  1.57079632679489661923f
#define ANG_F     0.8944271909999159f

// ---- staging layout (doubles) ----
#define SG_PIX   0      // sum, d2, d3, d4
#define SG_MAG   4      // 18 magnitude sums
#define SG_HISQ  22     // sum hi^2
#define SG_PMAG  23     // 12 parent-mag sums (s=0..2, b=0..3)
#define SG_IMM   35     // 5 x (sum im^2, im^3, im^4)
#define SG_ACE   50     // [4][4][81]
#define SG_ACR   1346   // [5][81]
#define SG_C0    1751   // [4][16]
#define SG_CR    1815   // [4][16]
#define SG_CX    1879   // [3][16]
#define SG_CRX   1927   // [4][4*8]
#define SG_CR5   2055   // [25]
#define NSTG     2080

enum { MA_C2 = 0, MA_REAL, MA_BAND, MA_EMBED_BAND, MA_EMBED_LO, MA_IMF4, MA_IMSTEP };
enum { WB_WRITE = 0, WB_WRITE_MAG, WB_WRITE_IM, WB_RED_HI, WB_RED_ABSRE, WB_FWD_MASK };

__device__ __forceinline__ int sfreq(int k, int H) { return (k < (H >> 1)) ? k : k - H; }
__device__ __forceinline__ int skx(int i) { return i + (i >> 4); }   // LDS bank skew

__device__ __forceinline__ float d_lograd(int fy, int fx, int H) {
  float cy = (float)fy * (2.0f / (float)H);
  float cx = (float)fx * (2.0f / (float)H);
  float rad = sqrtf(cx * cx + cy * cy);
  if (fy == 0 && fx == 0) rad = 2.0f / (float)H;   // reference DC hack
  return log2f(rad);
}
__device__ __forceinline__ float d_angle(int fy, int fx, int H) {
  return atan2f((float)fy * (2.0f / (float)H), (float)fx * (2.0f / (float)H));
}
__device__ __forceinline__ float d_rc(float x) {
  float c = fminf(fmaxf(-x, 0.0f), 1.0f);
  float t = cosf(0.5f * PI_F * c);
  return t * t;
}
__device__ __forceinline__ float d_alfa(float ang, int b) {
  float bc = (b == 0) ? 0.0f : (b == 1) ? 0.78539816339744830962f
           : (b == 2) ? 1.57079632679489661923f : 2.35619449019234492885f;
  float t = (PI_F + ang) - bc;
  float m = fmodf(t, TWOPI_F);
  if (m < 0.0f) m += TWOPI_F;
  return m - PI_F;
}
__device__ __forceinline__ float d_cos3(float a) { float c = cosf(a); return ANG_F * c * c * c; }
__device__ __forceinline__ float d_amaskC(float ang, int b) {
  float alfa = d_alfa(ang, b);
  float A = d_cos3(alfa);
  return (fabsf(alfa) < HALFPI_F) ? 2.0f * A : 0.0f;
}
__device__ __forceinline__ unsigned fkey(float f) {
  unsigned u = __float_as_uint(f);
  return (u & 0x80000000u) ? ~u : (u | 0x80000000u);
}
__device__ __forceinline__ float funkey(unsigned k) {
  return (k & 0x80000000u) ? __uint_as_float(k & 0x7FFFFFFFu) : __uint_as_float(~k);
}

template<int K>
__device__ __forceinline__ void blk_reduce(float* v, float* red) {
  int tid = threadIdx.x, wave = tid >> 6, lane = tid & 63;
  #pragma unroll
  for (int k = 0; k < K; k++) {
    float x = v[k];
    #pragma unroll
    for (int o = 32; o; o >>= 1) x += __shfl_down(x, o, 64);
    if (lane == 0) red[wave * K + k] = x;
  }
  __syncthreads();
  if (tid < K) red[tid] = red[tid] + red[K + tid] + red[2 * K + tid] + red[3 * K + tid];
}

// ================= FFT core (Stockham radix-2 in LDS, twiddle table) =================
template<int N> struct FftConst {
  static constexpr int L2N = (N == 64) ? 6 : (N == 128) ? 7 : (N == 256) ? 8 : (N == 512) ? 9 : 10;
  static constexpr int RPB = (N >= 512) ? 1 : (512 / N);
  static constexpr int TPR = (N >= 512) ? 256 : (N / 2);
  static constexpr int BUF = N + (N >> 4);
};

template<int N, bool INV>
__device__ __forceinline__ float2* fft_core(float2* A, float2* B, const float2* tw, int tr) {
  constexpr int TPR = FftConst<N>::TPR;
  constexpr int L2N = FftConst<N>::L2N;
  float2* src = A; float2* dst = B;
  #pragma unroll
  for (int st = 0; st < L2N; ++st) {
    for (int t = tr; t < (N >> 1); t += TPR) {
      int p = t >> st;
      int q = t & ((1 << st) - 1);
      float2 w = tw[p << st];
      float cv = w.x, sv = INV ? w.y : -w.y;
      float2 a = src[skx(t)];
      float2 b = src[skx(t + (N >> 1))];
      float dx = a.x - b.x, dy = a.y - b.y;
      int o0 = q + (p << (st + 1));
      dst[skx(o0)] = make_float2(a.x + b.x, a.y + b.y);
      dst[skx(o0 + (1 << st))] = make_float2(dx * cv - dy * sv, dx * sv + dy * cv);
    }
    __syncthreads();
    float2* tmp = src; src = dst; dst = tmp;
  }
  return src;
}

struct KAp {
  const float2* in;
  const float2* in2;
  float2* spec;
  float2* out[4];
  const float2* twg;
};
struct KBp {
  const float2* in[4];
  float2* out[4];
  float2* out2;
  double* red;
  double* red2;
  const float2* twg;
};
struct TPp { const float2* src[4]; float2* dst[4]; };

template<int N, int MODE>
__device__ __forceinline__ float2 loadA(const KAp& p, int row, int i, int b) {
  if constexpr (MODE == MA_C2) {
    return p.in[(size_t)row * N + i];
  } else if constexpr (MODE == MA_REAL) {
    const float* f = (const float*)p.in;
    return make_float2(f[(size_t)row * N + i], 0.0f);
  } else if constexpr (MODE == MA_BAND) {
    int fy = sfreq(i, N), fx = sfreq(row, N);
    float m = sqrtf(d_rc(d_lograd(fy, fx, N) + 1.0f)) * d_amaskC(d_angle(fy, fx, N), b);
    float2 l = p.in[(size_t)row * N + i];
    return make_float2(-l.y * m, l.x * m);
  } else if constexpr (MODE == MA_EMBED_BAND) {
    int fy = sfreq(i, N), fx = sfreq(row, N);
    int q = N >> 2, h2 = N >> 1;
    if (fy < -q || fy >= q || fx < -q || fx >= q) return make_float2(0.f, 0.f);
    int U = fx >= 0 ? fx : fx + h2, V = fy >= 0 ? fy : fy + h2;
    float m = sqrtf(d_rc(d_lograd(fy, fx, h2) + 1.0f)) * d_amaskC(d_angle(fy, fx, h2), b);
    float2 l = p.in[(size_t)U * h2 + V];
    return make_float2(-l.y * m, l.x * m);
  } else if constexpr (MODE == MA_EMBED_LO) {
    int fy = sfreq(i, N), fx = sfreq(row, N);
    int q = N >> 2, h2 = N >> 1;
    if (fy < -q || fy >= q || fx < -q || fx >= q) return make_float2(0.f, 0.f);
    int U = fx >= 0 ? fx : fx + h2, V = fy >= 0 ? fy : fy + h2;
    return p.in[(size_t)U * h2 + V];
  } else if constexpr (MODE == MA_IMF4) {
    int fy = sfreq(i, N), fx = sfreq(row, N);
    float lo = sqrtf(fmaxf(1.0f - d_rc(d_lograd(fy, fx, N)), 0.0f));
    float2 v = p.in[(size_t)row * N + i];
    return make_float2(v.x * lo, v.y * lo);
  } else {  // MA_IMSTEP
    int fy = sfreq(i, N), fx = sfreq(row, N);
    int q = N >> 2, h2 = N >> 1;
    float2 v = make_float2(0.f, 0.f);
    if (fy >= -q && fy < q && fx >= -q && fx < q) {
      int U = fx >= 0 ? fx : fx + h2, V = fy >= 0 ? fy : fy + h2;
      int nfy = (fy == -q) ? fy : -fy, nfx = (fx == -q) ? fx : -fx;
      int NU = nfx >= 0 ? nfx : nfx + h2, NV = nfy >= 0 ? nfy : nfy + h2;
      float2 a = p.in[(size_t)U * h2 + V];
      float2 bb = p.in[(size_t)NU * h2 + NV];
      v = make_float2(0.5f * (a.x + bb.x), 0.5f * (a.y - bb.y));
    }
    float lr = d_lograd(fy, fx, N);
    float hm2 = d_rc(lr + 1.0f);
    float lo0 = sqrtf(fmaxf(1.0f - d_rc(lr), 0.0f));
    float ang1 = d_angle(fy, fx, N);
    int gfy = (fy == -(N >> 1)) ? fy : -fy;
    int gfx = (fx == -(N >> 1)) ? fx : -fx;
    float ang2 = d_angle(gfy, gfx, N);
    float msum = 0.0f;
    #pragma unroll
    for (int b4 = 0; b4 < 4; b4++) {
      float a1 = d_alfa(ang1, b4), a2 = d_alfa(ang2, b4);
      float A1 = d_cos3(a1), A2 = d_cos3(a2);
      float T1 = (fabsf(a1) < HALFPI_F) ? A1 : 0.0f;
      float T2 = (fabsf(a2) < HALFPI_F) ? A2 : 0.0f;
      msum += A1 * (T1 - T2);
    }
    float mm = lo0 * hm2 * msum;
    float2 l = p.in2[(size_t)row * N + i];
    return make_float2(v.x + l.x * mm, v.y + l.y * mm);
  }
}

// pass A: fused load op -> FFT -> write natural
template<int N, bool INV, int MODE, bool SPEC>
__global__ __launch_bounds__(256) void k_ffta(KAp p) {
  using FC = FftConst<N>;
  __shared__ float2 shA[FC::RPB][FC::BUF];
  __shared__ float2 shB[FC::RPB][FC::BUF];
  __shared__ float2 tw[N / 2];
  int tid = threadIdx.x;
  for (int k = tid; k < N / 2; k += 256) tw[k] = p.twg[k << (10 - FC::L2N)];
  int rl = tid / FC::TPR;
  int tr = tid % FC::TPR;
  int row = blockIdx.x * FC::RPB + rl;
  int b = blockIdx.y;
  float2* A = shA[rl];
  for (int i = tr; i < N; i += FC::TPR) {
    float2 v = loadA<N, MODE>(p, row, i, b);
    if constexpr (SPEC) p.spec[(size_t)row * N + i] = v;
    A[skx(i)] = v;
  }
  __syncthreads();
  float2* res = fft_core<N, INV>(A, shB[rl], tw, tr);
  constexpr float sc = INV ? 1.0f / (float)N : 1.0f;
  float2* o = p.out[b] + (size_t)row * N;
  for (int i = tr; i < N; i += FC::TPR) {
    float2 v = res[skx(i)];
    o[i] = make_float2(v.x * sc, v.y * sc);
  }
}

// pass B: plain load -> FFT -> write/reduce
template<int N, bool INV, int WMODE>
__global__ __launch_bounds__(256) void k_fftb(KBp p) {
  using FC = FftConst<N>;
  __shared__ float2 shA[FC::RPB][FC::BUF];
  __shared__ float2 shB[FC::RPB][FC::BUF];
  __shared__ float2 tw[N / 2];
  __shared__ float red[12];
  int tid = threadIdx.x;
  for (int k = tid; k < N / 2; k += 256) tw[k] = p.twg[k << (10 - FC::L2N)];
  int rl = tid / FC::TPR;
  int tr = tid % FC::TPR;
  int row = blockIdx.x * FC::RPB + rl;
  int plane = blockIdx.y;
  const float2* in = p.in[plane] + (size_t)row * N;
  float2* A = shA[rl];
  for (int i = tr; i < N; i += FC::TPR) A[skx(i)] = in[i];
  __syncthreads();
  float2* res = fft_core<N, INV>(A, shB[rl], tw, tr);
  constexpr float sc = INV ? 1.0f / (float)N : 1.0f;
  if constexpr (WMODE == WB_WRITE || WMODE == WB_WRITE_MAG || WMODE == WB_WRITE_IM) {
    float2* o = p.out[plane] + (size_t)row * N;
    float a0 = 0.f, a1 = 0.f, a2 = 0.f;
    for (int i = tr; i < N; i += FC::TPR) {
      float2 v = res[skx(i)];
      v.x *= sc; v.y *= sc;
      o[i] = v;
      if constexpr (WMODE == WB_WRITE_MAG) a0 += sqrtf(v.x * v.x + v.y * v.y);
      if constexpr (WMODE == WB_WRITE_IM) { float v2 = v.x * v.x; a0 += v2; a1 += v2 * v.x; a2 += v2 * v2; }
    }
    if constexpr (WMODE == WB_WRITE_MAG) {
      float acc[1] = {a0}; blk_reduce<1>(acc, red);
      if (tid == 0) atomicAdd(&p.red[plane], (double)red[0]);
    }
    if constexpr (WMODE == WB_WRITE_IM) {
      float acc[3] = {a0, a1, a2}; blk_reduce<3>(acc, red);
      if (tid < 3) atomicAdd(&p.red[tid], (double)red[tid]);
    }
  } else if constexpr (WMODE == WB_RED_HI) {
    float a0 = 0.f, a1 = 0.f;
    for (int i = tr; i < N; i += FC::TPR) {
      float v = res[skx(i)].x * sc;
      a0 += fabsf(v); a1 += v * v;
    }
    float acc[2] = {a0, a1}; blk_reduce<2>(acc, red);
    if (tid == 0) atomicAdd(p.red, (double)red[0]);
    if (tid == 1) atomicAdd(p.red2, (double)red[1]);
  } else if constexpr (WMODE == WB_RED_ABSRE) {
    float a0 = 0.f;
    for (int i = tr; i < N; i += FC::TPR) a0 += fabsf(res[skx(i)].x * sc);
    float acc[1] = {a0}; blk_reduce<1>(acc, red);
    if (tid == 0) atomicAdd(p.red, (double)red[0]);
  } else {  // WB_FWD_MASK
    float2* o1 = p.out[0] + (size_t)row * N;
    float2* o2 = p.out2 + (size_t)row * N;
    int fx = sfreq(row, N);
    for (int i = tr; i < N; i += FC::TPR) {
      float2 v = res[skx(i)];
      int fy = sfreq(i, N);
      float rcv = d_rc(d_lograd(fy, fx, N));
      float hi = sqrtf(rcv), lo = sqrtf(fmaxf(1.0f - rcv, 0.0f));
      o1[i] = make_float2(v.x * hi, v.y * hi);
      o2[i] = make_float2(v.x * lo, v.y * lo);
    }
  }
}

__global__ __launch_bounds__(256) void k_transpose(TPp p, int N) {
  __shared__ float2 tile[32][33];
  int z = blockIdx.z;
  const float2* in = p.src[z];
  float2* out = p.dst[z];
  int bx = blockIdx.x << 5, by = blockIdx.y << 5;
  int tx = threadIdx.x & 31, ty = threadIdx.x >> 5;
  for (int r = ty; r < 32; r += 8) tile[r][tx] = in[(size_t)(by + r) * N + bx + tx];
  __syncthreads();
  for (int r = ty; r < 32; r += 8) out[(size_t)(bx + r) * N + by + tx] = tile[tx][r];
}

// crop freq domain [-Hn/2, Hn/2) from big (2*Hn) grid, multiply native lo mask
__global__ __launch_bounds__(256) void k_gen_Ldown(const float2* __restrict__ Lb, float2* __restrict__ Ls, int Hn, int zdc) {
  int i = blockIdx.x * 256 + threadIdx.x;
  if (i >= Hn * Hn) return;
  int fy = sfreq(i / Hn, Hn), fx = sfreq(i % Hn, Hn);
  int Hb = Hn << 1;
  int by = fy >= 0 ? fy : fy + Hb;
  int bx = fx >= 0 ? fx : fx + Hb;
  float lo = sqrtf(fmaxf(1.0f - d_rc(d_lograd(fy, fx, Hn)), 0.0f));
  float2 v = Lb[(size_t)by * Hb + bx];
  if (zdc && i == 0) { Ls[0] = make_float2(0.f, 0.f); return; }
  Ls[i] = make_float2(v.x * lo, v.y * lo);
}

// ================= reductions / stats =================
__global__ __launch_bounds__(256) void k_init(double* stg, unsigned* stgu, float2* Wg) {
  int i = blockIdx.x * 256 + threadIdx.x;
  if (i < NSTG) stg[i] = 0.0;
  if (i == 0) { stgu[0] = 0u; stgu[1] = 0xFFFFFFFFu; }
  if (i < 512) {
    float a = TWOPI_F * (float)i * (1.0f / 1024.0f);
    float sv, cv; sincosf(a, &sv, &cv);
    Wg[i] = make_float2(cv, sv);
  }
}
__global__ __launch_bounds__(256) void k_pix1(const float* __restrict__ x, int n, double* stg, unsigned* stgu) {
  __shared__ float red[4];
  float s = 0.f, mn = 3.402823466e38f, mx = -3.402823466e38f;
  for (int i = blockIdx.x * 256 + threadIdx.x; i < n; i += gridDim.x * 256) {
    float v = x[i]; s += v; mn = fminf(mn, v); mx = fmaxf(mx, v);
  }
  float acc[1] = {s};
  blk_reduce<1>(acc, red);
  if (threadIdx.x == 0) atomicAdd(&stg[SG_PIX], (double)red[0]);
  #pragma unroll
  for (int o = 32; o; o >>= 1) { mn = fminf(mn, __shfl_down(mn, o, 64)); mx = fmaxf(mx, __shfl_down(mx, o, 64)); }
  if ((threadIdx.x & 63) == 0) { atomicMin(&stgu[1], fkey(mn)); atomicMax(&stgu[0], fkey(mx)); }
}
__global__ __launch_bounds__(256) void k_pix2(const float* __restrict__ x, int n, double* stg) {
  __shared__ float red[12];
  float mu = (float)(stg[SG_PIX] / (double)n);
  float a2 = 0.f, a3 = 0.f, a4 = 0.f;
  for (int i = blockIdx.x * 256 + threadIdx.x; i < n; i += gridDim.x * 256) {
    float d = x[i] - mu; float d2 = d * d; a2 += d2; a3 += d2 * d; a4 += d2 * d2;
  }
  float acc[3] = {a2, a3, a4};
  blk_reduce<3>(acc, red);
  if (threadIdx.x < 3) atomicAdd(&stg[SG_PIX + 1 + threadIdx.x], (double)red[threadIdx.x]);
}

// central 9x9 circular autocorrelation (raw sums), register accumulators
struct ACp { const float2* in[4]; };
template<int MODE>   // 0: real part; 1: |complex| - mean
__global__ __launch_bounds__(256) void k_autocorr(ACp p, int H, const double* msum, float invCsz, double* gacc) {
  __shared__ float tile[40][40];
  __shared__ float fred[4 * 81];
  int plane = blockIdx.y;
  const float2* in = p.in[plane];
  double* g = gacc + plane * 81;
  float mean = 0.f;
  if constexpr (MODE == 1) mean = (float)(msum[plane] * (double)invCsz);
  float acc[81];
  #pragma unroll
  for (int k = 0; k < 81; k++) acc[k] = 0.f;
  int nT = (H >> 5) * (H >> 5);
  int tx = threadIdx.x & 31, ty = threadIdx.x >> 5;
  for (int ti = blockIdx.x; ti < nT; ti += gridDim.x) {
    __syncthreads();
    int by = (ti / (H >> 5)) << 5, bx = (ti % (H >> 5)) << 5;
    for (int ii = threadIdx.x; ii < 1600; ii += 256) {
      int r = ii / 40, c = ii - r * 40;
      int gy = (by + r - 4) & (H - 1), gx = (bx + c - 4) & (H - 1);
      float2 v = in[(size_t)gy * H + gx];
      float val;
      if constexpr (MODE == 1) val = sqrtf(v.x * v.x + v.y * v.y) - mean;
      else val = v.x;
      tile[r][c] = val;
    }
    __syncthreads();
    float cen[4];
    #pragma unroll
    for (int r = 0; r < 4; r++) cen[r] = tile[ty + 8 * r + 4][tx + 4];
    #pragma unroll
    for (int dy = -4; dy <= 4; dy++) {
      #pragma unroll
      for (int dx = -4; dx <= 4; dx++) {
        int o = (dy + 4) * 9 + (dx + 4);
        float s = 0.f;
        #pragma unroll
        for (int r = 0; r < 4; r++) s += cen[r] * tile[ty + 8 * r + 4 + dy][tx + 4 + dx];
        acc[o] += s;
      }
    }
  }
  // single block-level reduction of the 81 register accumulators
  int wave = threadIdx.x >> 6, lane = threadIdx.x & 63;
  #pragma unroll
  for (int k = 0; k < 81; k++) {
    float x = acc[k];
    #pragma unroll
    for (int o = 32; o; o >>= 1) x += __shfl_down(x, o, 64);
    if (lane == 0) fred[wave * 81 + k] = x;
  }
  __syncthreads();
  for (int k = threadIdx.x; k < 81; k += 256)
    atomicAdd(&g[k], (double)(fred[k] + fred[81 + k] + fred[162 + k] + fred[243 + k]));
}

__global__ __launch_bounds__(256) void k_gram4(const float2* __restrict__ b0, const float2* __restrict__ b1,
                                               const float2* __restrict__ b2, const float2* __restrict__ b3,
                                               const double* msum, int n, float invCsz,
                                               double* c0out, double* crout) {
  __shared__ float red[128];
  float mm[4];
  #pragma unroll
  for (int k = 0; k < 4; k++) mm[k] = (float)(msum[k] * (double)invCsz);
  float acc[32];
  #pragma unroll
  for (int k = 0; k < 32; k++) acc[k] = 0.f;
  for (int i = blockIdx.x * 256 + threadIdx.x; i < n; i += gridDim.x * 256) {
    float2 v0 = b0[i], v1 = b1[i], v2 = b2[i], v3 = b3[i];
    float a[4] = { sqrtf(v0.x * v0.x + v0.y * v0.y) - mm[0], sqrtf(v1.x * v1.x + v1.y * v1.y) - mm[1],
                   sqrtf(v2.x * v2.x + v2.y * v2.y) - mm[2], sqrtf(v3.x * v3.x + v3.y * v3.y) - mm[3] };
    float r[4] = { v0.x, v1.x, v2.x, v3.x };
    #pragma unroll
    for (int ii = 0; ii < 4; ii++)
      #pragma unroll
      for (int jj = 0; jj < 4; jj++) { acc[ii * 4 + jj] += a[ii] * a[jj]; acc[16 + ii * 4 + jj] += r[ii] * r[jj]; }
  }
  blk_reduce<32>(acc, red);
  int tid = threadIdx.x;
  if (tid < 16) atomicAdd(&c0out[tid], (double)red[tid]);
  else if (tid < 32) atomicAdd(&crout[tid - 16], (double)red[tid]);
}

struct DTp { const float2* P[4]; const float2* B[4]; };
__global__ __launch_bounds__(256) void k_dots_all(DTp p, const double* pms, const double* bms,
                                                  int n, float inv, double* cx, double* crx) {
  __shared__ float red[192];
  float pm[4], mm[4];
  #pragma unroll
  for (int k = 0; k < 4; k++) { pm[k] = (float)(pms[k] * (double)inv); mm[k] = (float)(bms[k] * (double)inv); }
  float acc[48];
  #pragma unroll
  for (int k = 0; k < 48; k++) acc[k] = 0.f;
  for (int i = blockIdx.x * 256 + threadIdx.x; i < n; i += gridDim.x * 256) {
    float a[4], re[4];
    #pragma unroll
    for (int c = 0; c < 4; c++) { float2 v = p.B[c][i]; a[c] = sqrtf(v.x * v.x + v.y * v.y) - mm[c]; re[c] = v.x; }
    #pragma unroll
    for (int b = 0; b < 4; b++) {
      float2 q = p.P[b][i];
      float mag = sqrtf(q.x * q.x + q.y * q.y);
      float pc = mag - pm[b];
      float rr = 0.f, ri = 0.f;
      if (mag > 0.f) { rr = (q.y * q.y - q.x * q.x) / mag; ri = 2.f * q.x * q.y / mag; }
      #pragma unroll
      for (int c = 0; c < 4; c++) {
        acc[b * 4 + c] += a[c] * pc;
        acc[16 + b * 4 + c] += re[c] * rr;
        acc[32 + b * 4 + c] += re[c] * ri;
      }
    }
  }
  blk_reduce<48>(acc, red);
  int tid = threadIdx.x;
  if (tid < 48) {
    int grp = tid >> 4, t = tid & 15, b = t >> 2, c = t & 3;
    double v = (double)red[tid];
    if (grp == 0) atomicAdd(&cx[c * 4 + b], v);
    else if (grp == 1) atomicAdd(&crx[c * 8 + b], v);
    else atomicAdd(&crx[c * 8 + 4 + b], v);
  }
}

__global__ __launch_bounds__(256) void k_dots_rpar5(const float2* __restrict__ P,
                                                    const float2* __restrict__ b0, const float2* __restrict__ b1,
                                                    const float2* __restrict__ b2, const float2* __restrict__ b3,
                                                    double* crxB) {
  __shared__ float red[80];
  float acc[20];
  #pragma unroll
  for (int k = 0; k < 20; k++) acc[k] = 0.f;
  for (int i = blockIdx.x * 256 + threadIdx.x; i < 16384; i += gridDim.x * 256) {
    int y = i >> 7, x = i & 127;
    float tt[5];
    tt[0] = P[i].x;
    tt[1] = P[(y << 7) | ((x - 1) & 127)].x;
    tt[2] = P[(y << 7) | ((x + 1) & 127)].x;
    tt[3] = P[(((y - 1) & 127) << 7) | x].x;
    tt[4] = P[(((y + 1) & 127) << 7) | x].x;
    float r[4] = { b0[i].x, b1[i].x, b2[i].x, b3[i].x };
    #pragma unroll
    for (int a = 0; a < 4; a++)
      #pragma unroll
      for (int c = 0; c < 5; c++) acc[a * 5 + c] += r[a] * tt[c];
  }
  blk_reduce<20>(acc, red);
  int tid = threadIdx.x;
  if (tid < 20) atomicAdd(&crxB[(tid / 5) * 8 + (tid % 5)], (double)red[tid]);
}
__global__ __launch_bounds__(256) void k_gram5(const float2* __restrict__ P, double* cr5) {
  __shared__ float red[100];
  float acc[25];
  #pragma unroll
  for (int k = 0; k < 25; k++) acc[k] = 0.f;
  for (int i = blockIdx.x * 256 + threadIdx.x; i < 16384; i += gridDim.x * 256) {
    int y = i >> 7, x = i & 127;
    float tt[5];
    tt[0] = P[i].x;
    tt[1] = P[(y << 7) | ((x - 1) & 127)].x;
    tt[2] = P[(y << 7) | ((x + 1) & 127)].x;
    tt[3] = P[(((y - 1) & 127) << 7) | x].x;
    tt[4] = P[(((y + 1) & 127) << 7) | x].x;
    #pragma unroll
    for (int a = 0; a < 5; a++)
      #pragma unroll
      for (int c = 0; c < 5; c++) acc[a * 5 + c] += tt[a] * tt[c];
  }
  blk_reduce<25>(acc, red);
  int tid = threadIdx.x;
  if (tid < 25) atomicAdd(&cr5[tid], (double)red[tid]);
}

// ================= finalize: write all 2456 outputs =================
__global__ __launch_bounds__(256) void k_finalize(const double* __restrict__ stg, const unsigned* __restrict__ stgu,
                                                  float* __restrict__ out) {
  int t = blockIdx.x * 256 + threadIdx.x;
  if (t >= 2456) return;
  const double N = 1048576.0;
  if (t < 6) {
    double mu = stg[SG_PIX] / N;
    double vp = stg[SG_PIX + 1] / N;
    double r;
    if (t == 0) r = mu;
    else if (t == 1) r = vp * (N / (N - 1.0));
    else if (t == 2) r = (stg[SG_PIX + 2] / N) / (vp * sqrt(vp));
    else if (t == 3) r = (stg[SG_PIX + 3] / N) / (vp * vp);
    else if (t == 4) r = (double)funkey(stgu[1]);
    else r = (double)funkey(stgu[0]);
    out[t] = (float)r;
  } else if (t < 24) {
    int i = t - 6;
    double csz;
    if (i == 0) csz = 1048576.0;
    else if (i < 17) { int s = (i - 1) >> 2; double h = (double)(1024 >> s); csz = h * h; }
    else csz = 4096.0;
    out[t] = (float)(stg[SG_MAG + i] / csz);
  } else if (t < 1320) {
    int e = t - 24;
    int b = e & 3, s = (e >> 2) & 3, o = e >> 4;
    double h = (double)(1024 >> s);
    out[t] = (float)(stg[SG_ACE + (s * 4 + b) * 81 + o] / (h * h));
  } else if (t < 1330) {
    int kurt = (t >= 1325);
    int s = t - (kurt ? 1325 : 1320);
    double h = (double)(1024 >> s); double csz = h * h;
    double vari = stg[SG_IMM + s * 3] / csz;
    double var0 = (stg[SG_PIX + 1] / N) * (N / (N - 1.0));
    double v = vari > 1e-12 ? vari : 1e-12;
    double r;
    if (vari / var0 > 1e-6)
      r = kurt ? (stg[SG_IMM + s * 3 + 2] / csz) / (v * v) : (stg[SG_IMM + s * 3 + 1] / csz) / (v * sqrt(v));
    else
      r = kurt ? 3.0 : 0.0;
    out[t] = (float)r;
  } else if (t < 1735) {
    int e = t - 1330;
    int s = e % 5, o = e / 5;
    double h = (double)(1024 >> s);
    out[t] = (float)(stg[SG_ACR + s * 81 + o] / (h * h));
  } else if (t < 1815) {
    int e = t - 1735;
    int s = e % 5, o = e / 5;
    if (s < 4) { double h = (double)(1024 >> s); out[t] = (float)(stg[SG_C0 + s * 16 + o] / (h * h)); }
    else out[t] = 0.0f;
  } else if (t < 1879) {
    int e = t - 1815;
    int s = e & 3, o = e >> 2;
    if (s < 3) { double h = (double)(1024 >> s); out[t] = (float)(stg[SG_CX + s * 16 + o] / (h * h)); }
    else out[t] = 0.0f;
  } else if (t < 2199) {
    int e = t - 1879;
    int s = e % 5, o = e / 5;
    int i = o >> 3, j = o & 7;
    float r = 0.0f;
    if (s < 4) { if (i < 4 && j < 4) { double h = (double)(1024 >> s); r = (float)(stg[SG_CR + s * 16 + i * 4 + j] / (h * h)); } }
    else { if (i < 5 && j < 5) r = (float)(stg[SG_CR5 + i * 5 + j] / 4096.0); }
    out[t] = r;
  } else if (t < 2455) {
    int e = t - 2199;
    int s = e & 3, o = e >> 2;
    int i = o >> 3, j = o & 7;
    float r = 0.0f;
    if (i < 4) {
      if (s < 3) { double h = (double)(1024 >> s); r = (float)(stg[SG_CRX + s * 32 + i * 8 + j] / (h * h)); }
      else if (j < 5) r = (float)(stg[SG_CRX + 96 + i * 8 + j] / 16384.0);
    }
    out[t] = r;
  } else {
    out[t] = (float)(stg[SG_HISQ] / N);
  }
}

// ================= host orchestration =================
static inline int rb(int n) { int b = (n + 255) / 256; return b > 256 ? 256 : b; }
static inline int acg(int nT) { return nT > 128 ? 128 : nT; }

struct Bufs {
  const float* img;
  float2 *L[5], *X[4], *Xh[4], *Y[4], *Wg;
  double* stg; unsigned* stgu;
  float* out;
};

template<int N>
static void im_step_t(const Bufs& B, int s, const float2* IA, float2* IB, hipStream_t st) {
  constexpr int RPB = FftConst<N>::RPB;
  { KAp a{}; a.in = IA; a.in2 = B.L[s]; a.spec = IB; a.out[0] = B.X[0]; a.twg = B.Wg;
    k_ffta<N, true, MA_IMSTEP, true><<<dim3(N / RPB, 1), 256, 0, st>>>(a); }
  { TPp t{}; t.src[0] = B.X[0]; t.dst[0] = B.X[1];
    k_transpose<<<dim3(N / 32, N / 32, 1), 256, 0, st>>>(t, N); }
  { KBp b{}; b.in[0] = B.X[1]; b.out[0] = B.X[0]; b.red = B.stg + SG_IMM + s * 3; b.twg = B.Wg;
    k_fftb<N, true, WB_WRITE_IM><<<dim3(N / RPB, 1), 256, 0, st>>>(b); }
  int nT = (N / 32) * (N / 32);
  { ACp c{}; c.in[0] = B.X[0];
    k_autocorr<0><<<dim3(acg(nT), 1), 256, 0, st>>>(c, N, nullptr, 0.f, B.stg + SG_ACR + s * 81); }
}

template<int N>
static void band_phase_t(const Bufs& B, int s, hipStream_t st) {
  constexpr int RPB = FftConst<N>::RPB;
  int n = N * N; float inv = 1.f / (float)n;
  int nT = (N / 32) * (N / 32);
  { KAp a{}; a.in = B.L[s]; a.twg = B.Wg;
    for (int k = 0; k < 4; k++) a.out[k] = B.X[k];
    k_ffta<N, true, MA_BAND, false><<<dim3(N / RPB, 4), 256, 0, st>>>(a); }
  { TPp t{}; for (int k = 0; k < 4; k++) { t.src[k] = B.X[k]; t.dst[k] = B.Y[k]; }
    k_transpose<<<dim3(N / 32, N / 32, 4), 256, 0, st>>>(t, N); }
  { KBp b{}; for (int k = 0; k < 4; k++) { b.in[k] = B.Y[k]; b.out[k] = B.Y[k]; }
    b.red = B.stg + SG_MAG + 1 + 4 * s; b.twg = B.Wg;
    k_fftb<N, true, WB_WRITE_MAG><<<dim3(N / RPB, 4), 256, 0, st>>>(b); }
  { ACp c{}; for (int k = 0; k < 4; k++) c.in[k] = B.Y[k];
    k_autocorr<1><<<dim3(acg(nT), 4), 256, 0, st>>>(c, N, B.stg + SG_MAG + 1 + 4 * s, inv, B.stg + SG_ACE + s * 4 * 81); }
  k_gram4<<<rb(n), 256, 0, st>>>(B.Y[0], B.Y[1], B.Y[2], B.Y[3], B.stg + SG_MAG + 1 + 4 * s, n, inv,
                                 B.stg + SG_C0 + s * 16, B.stg + SG_CR + s * 16);
  if constexpr (N > 128) {
    { KAp a{}; a.in = B.L[s + 1]; a.twg = B.Wg;
      for (int k = 0; k < 4; k++) a.out[k] = B.X[k];
      k_ffta<N, true, MA_EMBED_BAND, false><<<dim3(N / RPB, 4), 256, 0, st>>>(a); }
    float2* P[4];
    if (s == 0) {
      const float2* srcs[4] = {B.X[0], B.X[1], B.X[2], B.X[3]};
      float2* dsts[4] = {B.L[0], B.X[0], B.X[1], B.X[2]};
      for (int k = 0; k < 4; k++) {
        TPp t{}; t.src[0] = srcs[k]; t.dst[0] = dsts[k];
        k_transpose<<<dim3(N / 32, N / 32, 1), 256, 0, st>>>(t, N);
      }
      P[0] = B.L[0]; P[1] = B.X[0]; P[2] = B.X[1]; P[3] = B.X[2];
    } else {
      TPp t{}; for (int k = 0; k < 4; k++) { t.src[k] = B.X[k]; t.dst[k] = B.Xh[k]; }
      k_transpose<<<dim3(N / 32, N / 32, 4), 256, 0, st>>>(t, N);
      for (int k = 0; k < 4; k++) P[k] = B.Xh[k];
    }
    { KBp b{}; for (int k = 0; k < 4; k++) { b.in[k] = P[k]; b.out[k] = P[k]; }
      b.red = B.stg + SG_PMAG + 4 * s; b.twg = B.Wg;
      k_fftb<N, true, WB_WRITE_MAG><<<dim3(N / RPB, 4), 256, 0, st>>>(b); }
    { DTp d{}; for (int k = 0; k < 4; k++) { d.P[k] = P[k]; d.B[k] = B.Y[k]; }
      k_dots_all<<<rb(n), 256, 0, st>>>(d, B.stg + SG_PMAG + 4 * s, B.stg + SG_MAG + 1 + 4 * s, n, inv,
                                        B.stg + SG_CX + s * 16, B.stg + SG_CRX + s * 32); }
  } else {
    { KAp a{}; a.in = B.L[4]; a.twg = B.Wg; a.out[0] = B.X[0];
      k_ffta<128, true, MA_EMBED_LO, false><<<dim3(128 / FftConst<128>::RPB, 1), 256, 0, st>>>(a); }
    { TPp t{}; t.src[0] = B.X[0]; t.dst[0] = B.X[1];
      k_transpose<<<dim3(4, 4, 1), 256, 0, st>>>(t, 128); }
    { KBp b{}; b.in[0] = B.X[1]; b.out[0] = B.X[0]; b.twg = B.Wg;
      k_fftb<128, true, WB_WRITE><<<dim3(128 / FftConst<128>::RPB, 1), 256, 0, st>>>(b); }
    k_dots_rpar5<<<64, 256, 0, st>>>(B.X[0], B.Y[0], B.Y[1], B.Y[2], B.Y[3], B.stg + SG_CRX + 96);
    k_gram5<<<64, 256, 0, st>>>(B.X[0], B.stg + SG_CR5);
  }
}

extern "C" void kernel_launch(void* const* d_in, const int* in_sizes, int n_in,
                              void* d_out, int out_size, void* d_ws, size_t ws_size,
                              hipStream_t stream) {
  (void)in_sizes; (void)n_in; (void)out_size;
  if (ws_size < 78643200ull) return;
  char* w = (char*)d_ws;
  Bufs B;
  B.img = (const float*)d_in[0];
  B.out = (float*)d_out;
  B.L[0] = (float2*)(w + 0ull);
  B.L[1] = (float2*)(w + 8388608ull);
  B.L[2] = (float2*)(w + 10485760ull);
  B.L[3] = (float2*)(w + 11010048ull);
  B.L[4] = (float2*)(w + 11141120ull);
  B.Wg   = (float2*)(w + 11173888ull);
  B.stg  = (double*)(w + 11177984ull);
  B.stgu = (unsigned*)(B.stg + NSTG);
  B.X[0] = (float2*)(w + 11534336ull);
  B.X[1] = (float2*)(w + 19922944ull);
  B.X[2] = (float2*)(w + 28311552ull);
  B.X[3] = (float2*)(w + 36700160ull);
  for (int k = 0; k < 4; k++) B.Xh[k] = (float2*)((char*)B.X[k] + 4194304ull);
  B.Y[0] = (float2*)(w + 45088768ull);
  B.Y[1] = (float2*)(w + 53477376ull);
  B.Y[2] = (float2*)(w + 61865984ull);
  B.Y[3] = (float2*)(w + 70254592ull);
  hipStream_t st = stream;
  double* stg = B.stg;

  k_init<<<9, 256, 0, st>>>(stg, B.stgu, B.Wg);
  k_pix1<<<256, 256, 0, st>>>(B.img, 1048576, stg, B.stgu);
  k_pix2<<<256, 256, 0, st>>>(B.img, 1048576, stg);

  // forward fft2: img -> transposed spectrum; fused write of Thi (X2) and L0
  { KAp a{}; a.in = (const float2*)B.img; a.out[0] = B.X[0]; a.twg = B.Wg;
    k_ffta<1024, false, MA_REAL, false><<<dim3(1024, 1), 256, 0, st>>>(a); }
  { TPp t{}; t.src[0] = B.X[0]; t.dst[0] = B.X[1];
    k_transpose<<<dim3(32, 32, 1), 256, 0, st>>>(t, 1024); }
  { KBp b{}; b.in[0] = B.X[1]; b.out[0] = B.X[2]; b.out2 = B.L[0]; b.twg = B.Wg;
    k_fftb<1024, false, WB_FWD_MASK><<<dim3(1024, 1), 256, 0, st>>>(b); }

  // hi residual: ifft2 of Thi, reduce-only final pass (sum |re|, re^2)
  { KAp a{}; a.in = B.X[2]; a.out[0] = B.X[0]; a.twg = B.Wg;
    k_ffta<1024, true, MA_C2, false><<<dim3(1024, 1), 256, 0, st>>>(a); }
  { TPp t{}; t.src[0] = B.X[0]; t.dst[0] = B.X[1];
    k_transpose<<<dim3(32, 32, 1), 256, 0, st>>>(t, 1024); }
  { KBp b{}; b.in[0] = B.X[1]; b.red = stg + SG_MAG; b.red2 = stg + SG_HISQ; b.twg = B.Wg;
    k_fftb<1024, true, WB_RED_HI><<<dim3(1024, 1), 256, 0, st>>>(b); }

  // lowpass chain
  k_gen_Ldown<<<1024, 256, 0, st>>>(B.L[0], B.L[1], 512, 0);
  k_gen_Ldown<<<256, 256, 0, st>>>(B.L[1], B.L[2], 256, 0);
  k_gen_Ldown<<<64, 256, 0, st>>>(B.L[2], B.L[3], 128, 0);
  k_gen_Ldown<<<16, 256, 0, st>>>(B.L[3], B.L[4], 64, 1);   // DC zeroed = mean-subtracted lo resid

  // lo residual spatial -> magMeans[17] (reduce-only)
  { KAp a{}; a.in = B.L[4]; a.out[0] = B.X[0]; a.twg = B.Wg;
    k_ffta<64, true, MA_C2, false><<<dim3(8, 1), 256, 0, st>>>(a); }
  { TPp t{}; t.src[0] = B.X[0]; t.dst[0] = B.X[1];
    k_transpose<<<dim3(2, 2, 1), 256, 0, st>>>(t, 64); }
  { KBp b{}; b.in[0] = B.X[1]; b.red = stg + SG_MAG + 17; b.twg = B.Wg;
    k_fftb<64, true, WB_RED_ABSRE><<<dim3(8, 1), 256, 0, st>>>(b); }

  // im chain base: imF4 = L4 * lo0, spectrum echoed to X2 (=IA)
  { KAp a{}; a.in = B.L[4]; a.spec = B.X[2]; a.out[0] = B.X[0]; a.twg = B.Wg;
    k_ffta<64, true, MA_IMF4, true><<<dim3(8, 1), 256, 0, st>>>(a); }
  { TPp t{}; t.src[0] = B.X[0]; t.dst[0] = B.X[1];
    k_transpose<<<dim3(2, 2, 1), 256, 0, st>>>(t, 64); }
  { KBp b{}; b.in[0] = B.X[1]; b.out[0] = B.X[0]; b.red = stg + SG_IMM + 12; b.twg = B.Wg;
    k_fftb<64, true, WB_WRITE_IM><<<dim3(8, 1), 256, 0, st>>>(b); }
  { ACp c{}; c.in[0] = B.X[0];
    k_autocorr<0><<<dim3(4, 1), 256, 0, st>>>(c, 64, nullptr, 0.f, stg + SG_ACR + 4 * 81); }

  // im steps s=3..0 (IA/IB alternate X2/X3)
  im_step_t<128>(B, 3, B.X[2], B.X[3], st);
  im_step_t<256>(B, 2, B.X[3], B.X[2], st);
  im_step_t<512>(B, 1, B.X[2], B.X[3], st);
  im_step_t<1024>(B, 0, B.X[3], B.X[2], st);

  // band phases
  band_phase_t<1024>(B, 0, st);
  band_phase_t<512>(B, 1, st);
  band_phase_t<256>(B, 2, st);
  band_phase_t<128>(B, 3, st);

  k_finalize<<<10, 256, 0, st>>>(stg, B.stgu, B.out);
}

// Round 4
// 1001.502 us; speedup vs baseline: 2.5281x; 1.0475x over previous
//
#include <hip/hip_runtime.h>
#include <math.h>

#define PI_F      3.14159265358979323846f
#define TWOPI_F   6.28318530717958647692f
#define HALFPI_F  1.57079632679489661923f
#define ANG_F     0.8944271909999159f

// ---- staging layout (doubles) ----
#define SG_PIX   0      // sum, d2, d3, d4
#define SG_MAG   4      // 18 magnitude sums
#define SG_HISQ  22     // sum hi^2
#define SG_PMAG  23     // 12 parent-mag sums (s=0..2, b=0..3)
#define SG_IMM   35     // 5 x (sum im^2, im^3, im^4)
#define SG_ACE   50     // [4][4][81]
#define SG_ACR   1346   // [5][81]
#define SG_C0    1751   // [4][16]
#define SG_CR    1815   // [4][16]
#define SG_CX    1879   // [3][16]
#define SG_CRX   1927   // [4][4*8]
#define SG_CR5   2055   // [25]
#define NSTG     2080

enum { MA_C2 = 0, MA_REAL, MA_BAND, MA_EMBED_BAND, MA_EMBED_LO, MA_IMF4, MA_IMSTEP };
enum { WB_WRITE = 0, WB_WRITE_MAG, WB_WRITE_IM, WB_RED_HI, WB_RED_ABSRE, WB_FWD_MASK };

__device__ __forceinline__ int sfreq(int k, int H) { return (k < (H >> 1)) ? k : k - H; }
__device__ __forceinline__ int skx(int i) { return i + (i >> 4); }   // LDS bank skew

__device__ __forceinline__ float d_lograd(int fy, int fx, int H) {
  float cy = (float)fy * (2.0f / (float)H);
  float cx = (float)fx * (2.0f / (float)H);
  float rad = sqrtf(cx * cx + cy * cy);
  if (fy == 0 && fx == 0) rad = 2.0f / (float)H;   // reference DC hack
  return log2f(rad);
}
__device__ __forceinline__ float d_angle(int fy, int fx, int H) {
  return atan2f((float)fy * (2.0f / (float)H), (float)fx * (2.0f / (float)H));
}
__device__ __forceinline__ float d_rc(float x) {
  float c = fminf(fmaxf(-x, 0.0f), 1.0f);
  float t = cosf(0.5f * PI_F * c);
  return t * t;
}
__device__ __forceinline__ float d_alfa(float ang, int b) {
  float bc = (b == 0) ? 0.0f : (b == 1) ? 0.78539816339744830962f
           : (b == 2) ? 1.57079632679489661923f : 2.35619449019234492885f;
  float t = (PI_F + ang) - bc;
  float m = fmodf(t, TWOPI_F);
  if (m < 0.0f) m += TWOPI_F;
  return m - PI_F;
}
__device__ __forceinline__ float d_cos3(float a) { float c = cosf(a); return ANG_F * c * c * c; }
__device__ __forceinline__ float d_amaskC(float ang, int b) {
  float alfa = d_alfa(ang, b);
  float A = d_cos3(alfa);
  return (fabsf(alfa) < HALFPI_F) ? 2.0f * A : 0.0f;
}
__device__ __forceinline__ unsigned fkey(float f) {
  unsigned u = __float_as_uint(f);
  return (u & 0x80000000u) ? ~u : (u | 0x80000000u);
}
__device__ __forceinline__ float funkey(unsigned k) {
  return (k & 0x80000000u) ? __uint_as_float(k & 0x7FFFFFFFu) : __uint_as_float(~k);
}

template<int K>
__device__ __forceinline__ void blk_reduce(float* v, float* red) {
  int tid = threadIdx.x, wave = tid >> 6, lane = tid & 63;
  #pragma unroll
  for (int k = 0; k < K; k++) {
    float x = v[k];
    #pragma unroll
    for (int o = 32; o; o >>= 1) x += __shfl_down(x, o, 64);
    if (lane == 0) red[wave * K + k] = x;
  }
  __syncthreads();
  if (tid < K) red[tid] = red[tid] + red[K + tid] + red[2 * K + tid] + red[3 * K + tid];
}

// ================= FFT core (Stockham, radix-4 with leading radix-2, twiddle table) ======
template<int N> struct FftConst {
  static constexpr int L2N = (N == 64) ? 6 : (N == 128) ? 7 : (N == 256) ? 8 : (N == 512) ? 9 : 10;
  static constexpr int TPR = (N / 4 >= 256) ? 256 : ((N / 4 < 16) ? 16 : N / 4);
  static constexpr int RPB = 256 / TPR;
  static constexpr int BUF = N + (N >> 4);
};

template<int N, bool INV>
__device__ __forceinline__ float2* fft_core(float2* A, float2* B, const float2* tw, int tr) {
  constexpr int TPR = FftConst<N>::TPR;
  constexpr int L2N = FftConst<N>::L2N;
  float2* src = A; float2* dst = B;
  if constexpr (L2N & 1) {
    // one radix-2 stage at st=0
    for (int t = tr; t < (N >> 1); t += TPR) {
      float2 w = tw[t];
      float cv = w.x, sv = INV ? w.y : -w.y;
      float2 a = src[skx(t)];
      float2 b = src[skx(t + (N >> 1))];
      float dx = a.x - b.x, dy = a.y - b.y;
      dst[skx(2 * t)] = make_float2(a.x + b.x, a.y + b.y);
      dst[skx(2 * t + 1)] = make_float2(dx * cv - dy * sv, dx * sv + dy * cv);
    }
    __syncthreads();
    float2* tmp = src; src = dst; dst = tmp;
  }
  // radix-4 stages (fused pairs of the radix-2 recursion; verified vs radix-2 algebra)
  #pragma unroll
  for (int st = (L2N & 1); st < L2N; st += 2) {
    for (int t = tr; t < (N >> 2); t += TPR) {
      int p = t >> st;
      int q = t & ((1 << st) - 1);
      int i0 = q + (p << st);
      float2 x0 = src[skx(i0)];
      float2 x1 = src[skx(i0 + (N >> 2))];
      float2 x2 = src[skx(i0 + (N >> 1))];
      float2 x3 = src[skx(i0 + 3 * (N >> 2))];
      float2 w = tw[p << st];
      float c1 = w.x, s1 = INV ? w.y : -w.y;
      float c2 = c1 * c1 - s1 * s1, s2 = 2.f * c1 * s1;
      float c3 = c2 * c1 - s2 * s1, s3 = c2 * s1 + s2 * c1;
      float e0x = x0.x + x2.x, e0y = x0.y + x2.y;
      float e1x = x0.x - x2.x, e1y = x0.y - x2.y;
      float o0x = x1.x + x3.x, o0y = x1.y + x3.y;
      float d1x = x1.x - x3.x, d1y = x1.y - x3.y;
      float o1x, o1y;                       // sigma*i*(x1-x3), sigma=+1 inv, -1 fwd
      if constexpr (INV) { o1x = -d1y; o1y = d1x; }
      else               { o1x = d1y;  o1y = -d1x; }
      float t1x = e1x + o1x, t1y = e1y + o1y;
      float t2x = e0x - o0x, t2y = e0y - o0y;
      float t3x = e1x - o1x, t3y = e1y - o1y;
      int o = q + (p << (st + 2));
      int s = 1 << st;
      dst[skx(o)]         = make_float2(e0x + o0x, e0y + o0y);
      dst[skx(o + s)]     = make_float2(t1x * c1 - t1y * s1, t1x * s1 + t1y * c1);
      dst[skx(o + 2 * s)] = make_float2(t2x * c2 - t2y * s2, t2x * s2 + t2y * c2);
      dst[skx(o + 3 * s)] = make_float2(t3x * c3 - t3y * s3, t3x * s3 + t3y * c3);
    }
    __syncthreads();
    float2* tmp = src; src = dst; dst = tmp;
  }
  return src;
}

struct KAp {
  const float2* in;
  const float2* in2;
  float2* spec;
  float2* out[4];
  const float2* twg;
};
struct KBp {
  const float2* in[4];
  float2* out[4];
  float2* out2;
  double* red;
  double* red2;
  const float2* twg;
};
struct TPp { const float2* src[4]; float2* dst[4]; };

template<int N, int MODE>
__device__ __forceinline__ float2 loadA(const KAp& p, int row, int i, int b) {
  if constexpr (MODE == MA_C2) {
    return p.in[(size_t)row * N + i];
  } else if constexpr (MODE == MA_REAL) {
    const float* f = (const float*)p.in;
    return make_float2(f[(size_t)row * N + i], 0.0f);
  } else if constexpr (MODE == MA_BAND) {
    int fy = sfreq(i, N), fx = sfreq(row, N);
    float m = sqrtf(d_rc(d_lograd(fy, fx, N) + 1.0f)) * d_amaskC(d_angle(fy, fx, N), b);
    float2 l = p.in[(size_t)row * N + i];
    return make_float2(-l.y * m, l.x * m);
  } else if constexpr (MODE == MA_EMBED_BAND) {
    int fy = sfreq(i, N), fx = sfreq(row, N);
    int q = N >> 2, h2 = N >> 1;
    if (fy < -q || fy >= q || fx < -q || fx >= q) return make_float2(0.f, 0.f);
    int U = fx >= 0 ? fx : fx + h2, V = fy >= 0 ? fy : fy + h2;
    float m = sqrtf(d_rc(d_lograd(fy, fx, h2) + 1.0f)) * d_amaskC(d_angle(fy, fx, h2), b);
    float2 l = p.in[(size_t)U * h2 + V];
    return make_float2(-l.y * m, l.x * m);
  } else if constexpr (MODE == MA_EMBED_LO) {
    int fy = sfreq(i, N), fx = sfreq(row, N);
    int q = N >> 2, h2 = N >> 1;
    if (fy < -q || fy >= q || fx < -q || fx >= q) return make_float2(0.f, 0.f);
    int U = fx >= 0 ? fx : fx + h2, V = fy >= 0 ? fy : fy + h2;
    return p.in[(size_t)U * h2 + V];
  } else if constexpr (MODE == MA_IMF4) {
    int fy = sfreq(i, N), fx = sfreq(row, N);
    float lo = sqrtf(fmaxf(1.0f - d_rc(d_lograd(fy, fx, N)), 0.0f));
    float2 v = p.in[(size_t)row * N + i];
    return make_float2(v.x * lo, v.y * lo);
  } else {  // MA_IMSTEP
    int fy = sfreq(i, N), fx = sfreq(row, N);
    int q = N >> 2, h2 = N >> 1;
    float2 v = make_float2(0.f, 0.f);
    if (fy >= -q && fy < q && fx >= -q && fx < q) {
      int U = fx >= 0 ? fx : fx + h2, V = fy >= 0 ? fy : fy + h2;
      int nfy = (fy == -q) ? fy : -fy, nfx = (fx == -q) ? fx : -fx;
      int NU = nfx >= 0 ? nfx : nfx + h2, NV = nfy >= 0 ? nfy : nfy + h2;
      float2 a = p.in[(size_t)U * h2 + V];
      float2 bb = p.in[(size_t)NU * h2 + NV];
      v = make_float2(0.5f * (a.x + bb.x), 0.5f * (a.y - bb.y));
    }
    float lr = d_lograd(fy, fx, N);
    float hm2 = d_rc(lr + 1.0f);
    float lo0 = sqrtf(fmaxf(1.0f - d_rc(lr), 0.0f));
    float ang1 = d_angle(fy, fx, N);
    int gfy = (fy == -(N >> 1)) ? fy : -fy;
    int gfx = (fx == -(N >> 1)) ? fx : -fx;
    float ang2 = d_angle(gfy, gfx, N);
    float msum = 0.0f;
    #pragma unroll
    for (int b4 = 0; b4 < 4; b4++) {
      float a1 = d_alfa(ang1, b4), a2 = d_alfa(ang2, b4);
      float A1 = d_cos3(a1), A2 = d_cos3(a2);
      float T1 = (fabsf(a1) < HALFPI_F) ? A1 : 0.0f;
      float T2 = (fabsf(a2) < HALFPI_F) ? A2 : 0.0f;
      msum += A1 * (T1 - T2);
    }
    float mm = lo0 * hm2 * msum;
    float2 l = p.in2[(size_t)row * N + i];
    return make_float2(v.x + l.x * mm, v.y + l.y * mm);
  }
}

// pass A: fused load op -> FFT -> write natural
template<int N, bool INV, int MODE, bool SPEC>
__global__ __launch_bounds__(256) void k_ffta(KAp p) {
  using FC = FftConst<N>;
  __shared__ float2 shA[FC::RPB][FC::BUF];
  __shared__ float2 shB[FC::RPB][FC::BUF];
  __shared__ float2 tw[N / 2];
  int tid = threadIdx.x;
  for (int k = tid; k < N / 2; k += 256) tw[k] = p.twg[k << (10 - FC::L2N)];
  int rl = tid / FC::TPR;
  int tr = tid % FC::TPR;
  int row = blockIdx.x * FC::RPB + rl;
  int b = blockIdx.y;
  float2* A = shA[rl];
  for (int i = tr; i < N; i += FC::TPR) {
    float2 v = loadA<N, MODE>(p, row, i, b);
    if constexpr (SPEC) p.spec[(size_t)row * N + i] = v;
    A[skx(i)] = v;
  }
  __syncthreads();
  float2* res = fft_core<N, INV>(A, shB[rl], tw, tr);
  constexpr float sc = INV ? 1.0f / (float)N : 1.0f;
  float2* o = p.out[b] + (size_t)row * N;
  for (int i = tr; i < N; i += FC::TPR) {
    float2 v = res[skx(i)];
    o[i] = make_float2(v.x * sc, v.y * sc);
  }
}

// pass B: plain load -> FFT -> write/reduce
template<int N, bool INV, int WMODE>
__global__ __launch_bounds__(256) void k_fftb(KBp p) {
  using FC = FftConst<N>;
  __shared__ float2 shA[FC::RPB][FC::BUF];
  __shared__ float2 shB[FC::RPB][FC::BUF];
  __shared__ float2 tw[N / 2];
  __shared__ float red[12];
  int tid = threadIdx.x;
  for (int k = tid; k < N / 2; k += 256) tw[k] = p.twg[k << (10 - FC::L2N)];
  int rl = tid / FC::TPR;
  int tr = tid % FC::TPR;
  int row = blockIdx.x * FC::RPB + rl;
  int plane = blockIdx.y;
  const float2* in = p.in[plane] + (size_t)row * N;
  float2* A = shA[rl];
  for (int i = tr; i < N; i += FC::TPR) A[skx(i)] = in[i];
  __syncthreads();
  float2* res = fft_core<N, INV>(A, shB[rl], tw, tr);
  constexpr float sc = INV ? 1.0f / (float)N : 1.0f;
  if constexpr (WMODE == WB_WRITE || WMODE == WB_WRITE_MAG || WMODE == WB_WRITE_IM) {
    float2* o = p.out[plane] + (size_t)row * N;
    float a0 = 0.f, a1 = 0.f, a2 = 0.f;
    for (int i = tr; i < N; i += FC::TPR) {
      float2 v = res[skx(i)];
      v.x *= sc; v.y *= sc;
      o[i] = v;
      if constexpr (WMODE == WB_WRITE_MAG) a0 += sqrtf(v.x * v.x + v.y * v.y);
      if constexpr (WMODE == WB_WRITE_IM) { float v2 = v.x * v.x; a0 += v2; a1 += v2 * v.x; a2 += v2 * v2; }
    }
    if constexpr (WMODE == WB_WRITE_MAG) {
      float acc[1] = {a0}; blk_reduce<1>(acc, red);
      if (tid == 0) atomicAdd(&p.red[plane], (double)red[0]);
    }
    if constexpr (WMODE == WB_WRITE_IM) {
      float acc[3] = {a0, a1, a2}; blk_reduce<3>(acc, red);
      if (tid < 3) atomicAdd(&p.red[tid], (double)red[tid]);
    }
  } else if constexpr (WMODE == WB_RED_HI) {
    float a0 = 0.f, a1 = 0.f;
    for (int i = tr; i < N; i += FC::TPR) {
      float v = res[skx(i)].x * sc;
      a0 += fabsf(v); a1 += v * v;
    }
    float acc[2] = {a0, a1}; blk_reduce<2>(acc, red);
    if (tid == 0) atomicAdd(p.red, (double)red[0]);
    if (tid == 1) atomicAdd(p.red2, (double)red[1]);
  } else if constexpr (WMODE == WB_RED_ABSRE) {
    float a0 = 0.f;
    for (int i = tr; i < N; i += FC::TPR) a0 += fabsf(res[skx(i)].x * sc);
    float acc[1] = {a0}; blk_reduce<1>(acc, red);
    if (tid == 0) atomicAdd(p.red, (double)red[0]);
  } else {  // WB_FWD_MASK
    float2* o1 = p.out[0] + (size_t)row * N;
    float2* o2 = p.out2 + (size_t)row * N;
    int fx = sfreq(row, N);
    for (int i = tr; i < N; i += FC::TPR) {
      float2 v = res[skx(i)];
      int fy = sfreq(i, N);
      float rcv = d_rc(d_lograd(fy, fx, N));
      float hi = sqrtf(rcv), lo = sqrtf(fmaxf(1.0f - rcv, 0.0f));
      o1[i] = make_float2(v.x * hi, v.y * hi);
      o2[i] = make_float2(v.x * lo, v.y * lo);
    }
  }
}

__global__ __launch_bounds__(256) void k_transpose(TPp p, int N) {
  __shared__ float2 tile[32][33];
  int z = blockIdx.z;
  const float2* in = p.src[z];
  float2* out = p.dst[z];
  int bx = blockIdx.x << 5, by = blockIdx.y << 5;
  int tx = threadIdx.x & 31, ty = threadIdx.x >> 5;
  for (int r = ty; r < 32; r += 8) tile[r][tx] = in[(size_t)(by + r) * N + bx + tx];
  __syncthreads();
  for (int r = ty; r < 32; r += 8) out[(size_t)(bx + r) * N + by + tx] = tile[tx][r];
}

// crop freq domain [-Hn/2, Hn/2) from big (2*Hn) grid, multiply native lo mask
__global__ __launch_bounds__(256) void k_gen_Ldown(const float2* __restrict__ Lb, float2* __restrict__ Ls, int Hn, int zdc) {
  int i = blockIdx.x * 256 + threadIdx.x;
  if (i >= Hn * Hn) return;
  int fy = sfreq(i / Hn, Hn), fx = sfreq(i % Hn, Hn);
  int Hb = Hn << 1;
  int by = fy >= 0 ? fy : fy + Hb;
  int bx = fx >= 0 ? fx : fx + Hb;
  float lo = sqrtf(fmaxf(1.0f - d_rc(d_lograd(fy, fx, Hn)), 0.0f));
  float2 v = Lb[(size_t)by * Hb + bx];
  if (zdc && i == 0) { Ls[0] = make_float2(0.f, 0.f); return; }
  Ls[i] = make_float2(v.x * lo, v.y * lo);
}

// ================= reductions / stats =================
__global__ __launch_bounds__(256) void k_init(double* stg, unsigned* stgu, float2* Wg) {
  int i = blockIdx.x * 256 + threadIdx.x;
  if (i < NSTG) stg[i] = 0.0;
  if (i == 0) { stgu[0] = 0u; stgu[1] = 0xFFFFFFFFu; }
  if (i < 512) {
    float a = TWOPI_F * (float)i * (1.0f / 1024.0f);
    float sv, cv; sincosf(a, &sv, &cv);
    Wg[i] = make_float2(cv, sv);
  }
}
__global__ __launch_bounds__(256) void k_pix1(const float* __restrict__ x, int n, double* stg, unsigned* stgu) {
  __shared__ float red[4];
  float s = 0.f, mn = 3.402823466e38f, mx = -3.402823466e38f;
  for (int i = blockIdx.x * 256 + threadIdx.x; i < n; i += gridDim.x * 256) {
    float v = x[i]; s += v; mn = fminf(mn, v); mx = fmaxf(mx, v);
  }
  float acc[1] = {s};
  blk_reduce<1>(acc, red);
  if (threadIdx.x == 0) atomicAdd(&stg[SG_PIX], (double)red[0]);
  #pragma unroll
  for (int o = 32; o; o >>= 1) { mn = fminf(mn, __shfl_down(mn, o, 64)); mx = fmaxf(mx, __shfl_down(mx, o, 64)); }
  if ((threadIdx.x & 63) == 0) { atomicMin(&stgu[1], fkey(mn)); atomicMax(&stgu[0], fkey(mx)); }
}
__global__ __launch_bounds__(256) void k_pix2(const float* __restrict__ x, int n, double* stg) {
  __shared__ float red[12];
  float mu = (float)(stg[SG_PIX] / (double)n);
  float a2 = 0.f, a3 = 0.f, a4 = 0.f;
  for (int i = blockIdx.x * 256 + threadIdx.x; i < n; i += gridDim.x * 256) {
    float d = x[i] - mu; float d2 = d * d; a2 += d2; a3 += d2 * d; a4 += d2 * d2;
  }
  float acc[3] = {a2, a3, a4};
  blk_reduce<3>(acc, red);
  if (threadIdx.x < 3) atomicAdd(&stg[SG_PIX + 1 + threadIdx.x], (double)red[threadIdx.x]);
}

// central 9x9 circular autocorrelation: register-tiled, float4 LDS reads.
// thread = (row ty 0..31, col-group tx4 0..7), 4 consecutive center cols each.
struct ACp { const float2* in[4]; };
template<int MODE>   // 0: real part; 1: |complex| - mean
__global__ __launch_bounds__(256) void k_autocorr(ACp p, int H, const double* msum, float invCsz, double* gacc) {
  __shared__ float tile[40][44];      // stride 44 floats: 16B-aligned rows, balanced banks
  __shared__ float fred[4 * 81];
  int plane = blockIdx.y;
  const float2* in = p.in[plane];
  double* g = gacc + plane * 81;
  float mean = 0.f;
  if constexpr (MODE == 1) mean = (float)(msum[plane] * (double)invCsz);
  float acc[81];
  #pragma unroll
  for (int k = 0; k < 81; k++) acc[k] = 0.f;
  int nT = (H >> 5) * (H >> 5);
  int tx4 = threadIdx.x & 7, ty = threadIdx.x >> 3;
  for (int ti = blockIdx.x; ti < nT; ti += gridDim.x) {
    __syncthreads();
    int by = (ti / (H >> 5)) << 5, bx = (ti % (H >> 5)) << 5;
    for (int ii = threadIdx.x; ii < 1600; ii += 256) {
      int r = ii / 40, c = ii - r * 40;
      int gy = (by + r - 4) & (H - 1), gx = (bx + c - 4) & (H - 1);
      float2 v = in[(size_t)gy * H + gx];
      float val;
      if constexpr (MODE == 1) val = sqrtf(v.x * v.x + v.y * v.y) - mean;
      else val = v.x;
      tile[r][c] = val;
    }
    __syncthreads();
    float cen[4];
    #pragma unroll
    for (int c = 0; c < 4; c++) cen[c] = tile[ty + 4][4 * tx4 + 4 + c];
    #pragma unroll
    for (int dy = -4; dy <= 4; dy++) {
      const float* rowp = &tile[ty + 4 + dy][4 * tx4];
      float4 f0 = *(const float4*)(rowp);
      float4 f1 = *(const float4*)(rowp + 4);
      float4 f2 = *(const float4*)(rowp + 8);
      float r[12] = { f0.x, f0.y, f0.z, f0.w, f1.x, f1.y, f1.z, f1.w, f2.x, f2.y, f2.z, f2.w };
      #pragma unroll
      for (int dx = -4; dx <= 4; dx++) {
        int o = (dy + 4) * 9 + (dx + 4);
        float s = 0.f;
        #pragma unroll
        for (int c = 0; c < 4; c++) s += cen[c] * r[c + dx + 4];
        acc[o] += s;
      }
    }
  }
  // single block-level reduction of the 81 register accumulators
  int wave = threadIdx.x >> 6, lane = threadIdx.x & 63;
  #pragma unroll
  for (int k = 0; k < 81; k++) {
    float x = acc[k];
    #pragma unroll
    for (int o = 32; o; o >>= 1) x += __shfl_down(x, o, 64);
    if (lane == 0) fred[wave * 81 + k] = x;
  }
  __syncthreads();
  for (int k = threadIdx.x; k < 81; k += 256)
    atomicAdd(&g[k], (double)(fred[k] + fred[81 + k] + fred[162 + k] + fred[243 + k]));
}

__global__ __launch_bounds__(256) void k_gram4(const float2* __restrict__ b0, const float2* __restrict__ b1,
                                               const float2* __restrict__ b2, const float2* __restrict__ b3,
                                               const double* msum, int n, float invCsz,
                                               double* c0out, double* crout) {
  __shared__ float red[128];
  float mm[4];
  #pragma unroll
  for (int k = 0; k < 4; k++) mm[k] = (float)(msum[k] * (double)invCsz);
  float acc[32];
  #pragma unroll
  for (int k = 0; k < 32; k++) acc[k] = 0.f;
  for (int i = blockIdx.x * 256 + threadIdx.x; i < n; i += gridDim.x * 256) {
    float2 v0 = b0[i], v1 = b1[i], v2 = b2[i], v3 = b3[i];
    float a[4] = { sqrtf(v0.x * v0.x + v0.y * v0.y) - mm[0], sqrtf(v1.x * v1.x + v1.y * v1.y) - mm[1],
                   sqrtf(v2.x * v2.x + v2.y * v2.y) - mm[2], sqrtf(v3.x * v3.x + v3.y * v3.y) - mm[3] };
    float r[4] = { v0.x, v1.x, v2.x, v3.x };
    #pragma unroll
    for (int ii = 0; ii < 4; ii++)
      #pragma unroll
      for (int jj = 0; jj < 4; jj++) { acc[ii * 4 + jj] += a[ii] * a[jj]; acc[16 + ii * 4 + jj] += r[ii] * r[jj]; }
  }
  blk_reduce<32>(acc, red);
  int tid = threadIdx.x;
  if (tid < 16) atomicAdd(&c0out[tid], (double)red[tid]);
  else if (tid < 32) atomicAdd(&crout[tid - 16], (double)red[tid]);
}

struct DTp { const float2* P[4]; const float2* B[4]; };
__global__ __launch_bounds__(256) void k_dots_all(DTp p, const double* pms, const double* bms,
                                                  int n, float inv, double* cx, double* crx) {
  __shared__ float red[192];
  float pm[4], mm[4];
  #pragma unroll
  for (int k = 0; k < 4; k++) { pm[k] = (float)(pms[k] * (double)inv); mm[k] = (float)(bms[k] * (double)inv); }
  float acc[48];
  #pragma unroll
  for (int k = 0; k < 48; k++) acc[k] = 0.f;
  for (int i = blockIdx.x * 256 + threadIdx.x; i < n; i += gridDim.x * 256) {
    float a[4], re[4];
    #pragma unroll
    for (int c = 0; c < 4; c++) { float2 v = p.B[c][i]; a[c] = sqrtf(v.x * v.x + v.y * v.y) - mm[c]; re[c] = v.x; }
    #pragma unroll
    for (int b = 0; b < 4; b++) {
      float2 q = p.P[b][i];
      float mag = sqrtf(q.x * q.x + q.y * q.y);
      float pc = mag - pm[b];
      float rr = 0.f, ri = 0.f;
      if (mag > 0.f) { rr = (q.y * q.y - q.x * q.x) / mag; ri = 2.f * q.x * q.y / mag; }
      #pragma unroll
      for (int c = 0; c < 4; c++) {
        acc[b * 4 + c] += a[c] * pc;
        acc[16 + b * 4 + c] += re[c] * rr;
        acc[32 + b * 4 + c] += re[c] * ri;
      }
    }
  }
  blk_reduce<48>(acc, red);
  int tid = threadIdx.x;
  if (tid < 48) {
    int grp = tid >> 4, t = tid & 15, b = t >> 2, c = t & 3;
    double v = (double)red[tid];
    if (grp == 0) atomicAdd(&cx[c * 4 + b], v);
    else if (grp == 1) atomicAdd(&crx[c * 8 + b], v);
    else atomicAdd(&crx[c * 8 + 4 + b], v);
  }
}

__global__ __launch_bounds__(256) void k_dots_rpar5(const float2* __restrict__ P,
                                                    const float2* __restrict__ b0, const float2* __restrict__ b1,
                                                    const float2* __restrict__ b2, const float2* __restrict__ b3,
                                                    double* crxB) {
  __shared__ float red[80];
  float acc[20];
  #pragma unroll
  for (int k = 0; k < 20; k++) acc[k] = 0.f;
  for (int i = blockIdx.x * 256 + threadIdx.x; i < 16384; i += gridDim.x * 256) {
    int y = i >> 7, x = i & 127;
    float tt[5];
    tt[0] = P[i].x;
    tt[1] = P[(y << 7) | ((x - 1) & 127)].x;
    tt[2] = P[(y << 7) | ((x + 1) & 127)].x;
    tt[3] = P[(((y - 1) & 127) << 7) | x].x;
    tt[4] = P[(((y + 1) & 127) << 7) | x].x;
    float r[4] = { b0[i].x, b1[i].x, b2[i].x, b3[i].x };
    #pragma unroll
    for (int a = 0; a < 4; a++)
      #pragma unroll
      for (int c = 0; c < 5; c++) acc[a * 5 + c] += r[a] * tt[c];
  }
  blk_reduce<20>(acc, red);
  int tid = threadIdx.x;
  if (tid < 20) atomicAdd(&crxB[(tid / 5) * 8 + (tid % 5)], (double)red[tid]);
}
__global__ __launch_bounds__(256) void k_gram5(const float2* __restrict__ P, double* cr5) {
  __shared__ float red[100];
  float acc[25];
  #pragma unroll
  for (int k = 0; k < 25; k++) acc[k] = 0.f;
  for (int i = blockIdx.x * 256 + threadIdx.x; i < 16384; i += gridDim.x * 256) {
    int y = i >> 7, x = i & 127;
    float tt[5];
    tt[0] = P[i].x;
    tt[1] = P[(y << 7) | ((x - 1) & 127)].x;
    tt[2] = P[(y << 7) | ((x + 1) & 127)].x;
    tt[3] = P[(((y - 1) & 127) << 7) | x].x;
    tt[4] = P[(((y + 1) & 127) << 7) | x].x;
    #pragma unroll
    for (int a = 0; a < 5; a++)
      #pragma unroll
      for (int c = 0; c < 5; c++) acc[a * 5 + c] += tt[a] * tt[c];
  }
  blk_reduce<25>(acc, red);
  int tid = threadIdx.x;
  if (tid < 25) atomicAdd(&cr5[tid], (double)red[tid]);
}

// ================= finalize: write all 2456 outputs =================
__global__ __launch_bounds__(256) void k_finalize(const double* __restrict__ stg, const unsigned* __restrict__ stgu,
                                                  float* __restrict__ out) {
  int t = blockIdx.x * 256 + threadIdx.x;
  if (t >= 2456) return;
  const double N = 1048576.0;
  if (t < 6) {
    double mu = stg[SG_PIX] / N;
    double vp = stg[SG_PIX + 1] / N;
    double r;
    if (t == 0) r = mu;
    else if (t == 1) r = vp * (N / (N - 1.0));
    else if (t == 2) r = (stg[SG_PIX + 2] / N) / (vp * sqrt(vp));
    else if (t == 3) r = (stg[SG_PIX + 3] / N) / (vp * vp);
    else if (t == 4) r = (double)funkey(stgu[1]);
    else r = (double)funkey(stgu[0]);
    out[t] = (float)r;
  } else if (t < 24) {
    int i = t - 6;
    double csz;
    if (i == 0) csz = 1048576.0;
    else if (i < 17) { int s = (i - 1) >> 2; double h = (double)(1024 >> s); csz = h * h; }
    else csz = 4096.0;
    out[t] = (float)(stg[SG_MAG + i] / csz);
  } else if (t < 1320) {
    int e = t - 24;
    int b = e & 3, s = (e >> 2) & 3, o = e >> 4;
    double h = (double)(1024 >> s);
    out[t] = (float)(stg[SG_ACE + (s * 4 + b) * 81 + o] / (h * h));
  } else if (t < 1330) {
    int kurt = (t >= 1325);
    int s = t - (kurt ? 1325 : 1320);
    double h = (double)(1024 >> s); double csz = h * h;
    double vari = stg[SG_IMM + s * 3] / csz;
    double var0 = (stg[SG_PIX + 1] / N) * (N / (N - 1.0));
    double v = vari > 1e-12 ? vari : 1e-12;
    double r;
    if (vari / var0 > 1e-6)
      r = kurt ? (stg[SG_IMM + s * 3 + 2] / csz) / (v * v) : (stg[SG_IMM + s * 3 + 1] / csz) / (v * sqrt(v));
    else
      r = kurt ? 3.0 : 0.0;
    out[t] = (float)r;
  } else if (t < 1735) {
    int e = t - 1330;
    int s = e % 5, o = e / 5;
    double h = (double)(1024 >> s);
    out[t] = (float)(stg[SG_ACR + s * 81 + o] / (h * h));
  } else if (t < 1815) {
    int e = t - 1735;
    int s = e % 5, o = e / 5;
    if (s < 4) { double h = (double)(1024 >> s); out[t] = (float)(stg[SG_C0 + s * 16 + o] / (h * h)); }
    else out[t] = 0.0f;
  } else if (t < 1879) {
    int e = t - 1815;
    int s = e & 3, o = e >> 2;
    if (s < 3) { double h = (double)(1024 >> s); out[t] = (float)(stg[SG_CX + s * 16 + o] / (h * h)); }
    else out[t] = 0.0f;
  } else if (t < 2199) {
    int e = t - 1879;
    int s = e % 5, o = e / 5;
    int i = o >> 3, j = o & 7;
    float r = 0.0f;
    if (s < 4) { if (i < 4 && j < 4) { double h = (double)(1024 >> s); r = (float)(stg[SG_CR + s * 16 + i * 4 + j] / (h * h)); } }
    else { if (i < 5 && j < 5) r = (float)(stg[SG_CR5 + i * 5 + j] / 4096.0); }
    out[t] = r;
  } else if (t < 2455) {
    int e = t - 2199;
    int s = e & 3, o = e >> 2;
    int i = o >> 3, j = o & 7;
    float r = 0.0f;
    if (i < 4) {
      if (s < 3) { double h = (double)(1024 >> s); r = (float)(stg[SG_CRX + s * 32 + i * 8 + j] / (h * h)); }
      else if (j < 5) r = (float)(stg[SG_CRX + 96 + i * 8 + j] / 16384.0);
    }
    out[t] = r;
  } else {
    out[t] = (float)(stg[SG_HISQ] / N);
  }
}

// ================= host orchestration =================
static inline int rb(int n) { int b = (n + 255) / 256; return b > 256 ? 256 : b; }
static inline int acg(int nT) { return nT > 256 ? 256 : nT; }

struct Bufs {
  const float* img;
  float2 *L[5], *X[4], *Xh[4], *Y[4], *Wg;
  double* stg; unsigned* stgu;
  float* out;
};

template<int N>
static void im_step_t(const Bufs& B, int s, const float2* IA, float2* IB, hipStream_t st) {
  constexpr int RPB = FftConst<N>::RPB;
  { KAp a{}; a.in = IA; a.in2 = B.L[s]; a.spec = IB; a.out[0] = B.X[0]; a.twg = B.Wg;
    k_ffta<N, true, MA_IMSTEP, true><<<dim3(N / RPB, 1), 256, 0, st>>>(a); }
  { TPp t{}; t.src[0] = B.X[0]; t.dst[0] = B.X[1];
    k_transpose<<<dim3(N / 32, N / 32, 1), 256, 0, st>>>(t, N); }
  { KBp b{}; b.in[0] = B.X[1]; b.out[0] = B.X[0]; b.red = B.stg + SG_IMM + s * 3; b.twg = B.Wg;
    k_fftb<N, true, WB_WRITE_IM><<<dim3(N / RPB, 1), 256, 0, st>>>(b); }
  int nT = (N / 32) * (N / 32);
  { ACp c{}; c.in[0] = B.X[0];
    k_autocorr<0><<<dim3(acg(nT), 1), 256, 0, st>>>(c, N, nullptr, 0.f, B.stg + SG_ACR + s * 81); }
}

template<int N>
static void band_phase_t(const Bufs& B, int s, hipStream_t st) {
  constexpr int RPB = FftConst<N>::RPB;
  int n = N * N; float inv = 1.f / (float)n;
  int nT = (N / 32) * (N / 32);
  { KAp a{}; a.in = B.L[s]; a.twg = B.Wg;
    for (int k = 0; k < 4; k++) a.out[k] = B.X[k];
    k_ffta<N, true, MA_BAND, false><<<dim3(N / RPB, 4), 256, 0, st>>>(a); }
  { TPp t{}; for (int k = 0; k < 4; k++) { t.src[k] = B.X[k]; t.dst[k] = B.Y[k]; }
    k_transpose<<<dim3(N / 32, N / 32, 4), 256, 0, st>>>(t, N); }
  { KBp b{}; for (int k = 0; k < 4; k++) { b.in[k] = B.Y[k]; b.out[k] = B.Y[k]; }
    b.red = B.stg + SG_MAG + 1 + 4 * s; b.twg = B.Wg;
    k_fftb<N, true, WB_WRITE_MAG><<<dim3(N / RPB, 4), 256, 0, st>>>(b); }
  { ACp c{}; for (int k = 0; k < 4; k++) c.in[k] = B.Y[k];
    k_autocorr<1><<<dim3(acg(nT), 4), 256, 0, st>>>(c, N, B.stg + SG_MAG + 1 + 4 * s, inv, B.stg + SG_ACE + s * 4 * 81); }
  k_gram4<<<rb(n), 256, 0, st>>>(B.Y[0], B.Y[1], B.Y[2], B.Y[3], B.stg + SG_MAG + 1 + 4 * s, n, inv,
                                 B.stg + SG_C0 + s * 16, B.stg + SG_CR + s * 16);
  if constexpr (N > 128) {
    { KAp a{}; a.in = B.L[s + 1]; a.twg = B.Wg;
      for (int k = 0; k < 4; k++) a.out[k] = B.X[k];
      k_ffta<N, true, MA_EMBED_BAND, false><<<dim3(N / RPB, 4), 256, 0, st>>>(a); }
    float2* P[4];
    if (s == 0) {
      const float2* srcs[4] = {B.X[0], B.X[1], B.X[2], B.X[3]};
      float2* dsts[4] = {B.L[0], B.X[0], B.X[1], B.X[2]};
      for (int k = 0; k < 4; k++) {
        TPp t{}; t.src[0] = srcs[k]; t.dst[0] = dsts[k];
        k_transpose<<<dim3(N / 32, N / 32, 1), 256, 0, st>>>(t, N);
      }
      P[0] = B.L[0]; P[1] = B.X[0]; P[2] = B.X[1]; P[3] = B.X[2];
    } else {
      TPp t{}; for (int k = 0; k < 4; k++) { t.src[k] = B.X[k]; t.dst[k] = B.Xh[k]; }
      k_transpose<<<dim3(N / 32, N / 32, 4), 256, 0, st>>>(t, N);
      for (int k = 0; k < 4; k++) P[k] = B.Xh[k];
    }
    { KBp b{}; for (int k = 0; k < 4; k++) { b.in[k] = P[k]; b.out[k] = P[k]; }
      b.red = B.stg + SG_PMAG + 4 * s; b.twg = B.Wg;
      k_fftb<N, true, WB_WRITE_MAG><<<dim3(N / RPB, 4), 256, 0, st>>>(b); }
    { DTp d{}; for (int k = 0; k < 4; k++) { d.P[k] = P[k]; d.B[k] = B.Y[k]; }
      k_dots_all<<<rb(n), 256, 0, st>>>(d, B.stg + SG_PMAG + 4 * s, B.stg + SG_MAG + 1 + 4 * s, n, inv,
                                        B.stg + SG_CX + s * 16, B.stg + SG_CRX + s * 32); }
  } else {
    { KAp a{}; a.in = B.L[4]; a.twg = B.Wg; a.out[0] = B.X[0];
      k_ffta<128, true, MA_EMBED_LO, false><<<dim3(128 / FftConst<128>::RPB, 1), 256, 0, st>>>(a); }
    { TPp t{}; t.src[0] = B.X[0]; t.dst[0] = B.X[1];
      k_transpose<<<dim3(4, 4, 1), 256, 0, st>>>(t, 128); }
    { KBp b{}; b.in[0] = B.X[1]; b.out[0] = B.X[0]; b.twg = B.Wg;
      k_fftb<128, true, WB_WRITE><<<dim3(128 / FftConst<128>::RPB, 1), 256, 0, st>>>(b); }
    k_dots_rpar5<<<64, 256, 0, st>>>(B.X[0], B.Y[0], B.Y[1], B.Y[2], B.Y[3], B.stg + SG_CRX + 96);
    k_gram5<<<64, 256, 0, st>>>(B.X[0], B.stg + SG_CR5);
  }
}

extern "C" void kernel_launch(void* const* d_in, const int* in_sizes, int n_in,
                              void* d_out, int out_size, void* d_ws, size_t ws_size,
                              hipStream_t stream) {
  (void)in_sizes; (void)n_in; (void)out_size;
  if (ws_size < 78643200ull) return;
  char* w = (char*)d_ws;
  Bufs B;
  B.img = (const float*)d_in[0];
  B.out = (float*)d_out;
  B.L[0] = (float2*)(w + 0ull);
  B.L[1] = (float2*)(w + 8388608ull);
  B.L[2] = (float2*)(w + 10485760ull);
  B.L[3] = (float2*)(w + 11010048ull);
  B.L[4] = (float2*)(w + 11141120ull);
  B.Wg   = (float2*)(w + 11173888ull);
  B.stg  = (double*)(w + 11177984ull);
  B.stgu = (unsigned*)(B.stg + NSTG);
  B.X[0] = (float2*)(w + 11534336ull);
  B.X[1] = (float2*)(w + 19922944ull);
  B.X[2] = (float2*)(w + 28311552ull);
  B.X[3] = (float2*)(w + 36700160ull);
  for (int k = 0; k < 4; k++) B.Xh[k] = (float2*)((char*)B.X[k] + 4194304ull);
  B.Y[0] = (float2*)(w + 45088768ull);
  B.Y[1] = (float2*)(w + 53477376ull);
  B.Y[2] = (float2*)(w + 61865984ull);
  B.Y[3] = (float2*)(w + 70254592ull);
  hipStream_t st = stream;
  double* stg = B.stg;
  constexpr int G64 = 64 / FftConst<64>::RPB;

  k_init<<<9, 256, 0, st>>>(stg, B.stgu, B.Wg);
  k_pix1<<<256, 256, 0, st>>>(B.img, 1048576, stg, B.stgu);
  k_pix2<<<256, 256, 0, st>>>(B.img, 1048576, stg);

  // forward fft2: img -> transposed spectrum; fused write of Thi (X2) and L0
  { KAp a{}; a.in = (const float2*)B.img; a.out[0] = B.X[0]; a.twg = B.Wg;
    k_ffta<1024, false, MA_REAL, false><<<dim3(1024, 1), 256, 0, st>>>(a); }
  { TPp t{}; t.src[0] = B.X[0]; t.dst[0] = B.X[1];
    k_transpose<<<dim3(32, 32, 1), 256, 0, st>>>(t, 1024); }
  { KBp b{}; b.in[0] = B.X[1]; b.out[0] = B.X[2]; b.out2 = B.L[0]; b.twg = B.Wg;
    k_fftb<1024, false, WB_FWD_MASK><<<dim3(1024, 1), 256, 0, st>>>(b); }

  // hi residual: ifft2 of Thi, reduce-only final pass (sum |re|, re^2)
  { KAp a{}; a.in = B.X[2]; a.out[0] = B.X[0]; a.twg = B.Wg;
    k_ffta<1024, true, MA_C2, false><<<dim3(1024, 1), 256, 0, st>>>(a); }
  { TPp t{}; t.src[0] = B.X[0]; t.dst[0] = B.X[1];
    k_transpose<<<dim3(32, 32, 1), 256, 0, st>>>(t, 1024); }
  { KBp b{}; b.in[0] = B.X[1]; b.red = stg + SG_MAG; b.red2 = stg + SG_HISQ; b.twg = B.Wg;
    k_fftb<1024, true, WB_RED_HI><<<dim3(1024, 1), 256, 0, st>>>(b); }

  // lowpass chain
  k_gen_Ldown<<<1024, 256, 0, st>>>(B.L[0], B.L[1], 512, 0);
  k_gen_Ldown<<<256, 256, 0, st>>>(B.L[1], B.L[2], 256, 0);
  k_gen_Ldown<<<64, 256, 0, st>>>(B.L[2], B.L[3], 128, 0);
  k_gen_Ldown<<<16, 256, 0, st>>>(B.L[3], B.L[4], 64, 1);   // DC zeroed = mean-subtracted lo resid

  // lo residual spatial -> magMeans[17] (reduce-only)
  { KAp a{}; a.in = B.L[4]; a.out[0] = B.X[0]; a.twg = B.Wg;
    k_ffta<64, true, MA_C2, false><<<dim3(G64, 1), 256, 0, st>>>(a); }
  { TPp t{}; t.src[0] = B.X[0]; t.dst[0] = B.X[1];
    k_transpose<<<dim3(2, 2, 1), 256, 0, st>>>(t, 64); }
  { KBp b{}; b.in[0] = B.X[1]; b.red = stg + SG_MAG + 17; b.twg = B.Wg;
    k_fftb<64, true, WB_RED_ABSRE><<<dim3(G64, 1), 256, 0, st>>>(b); }

  // im chain base: imF4 = L4 * lo0, spectrum echoed to X2 (=IA)
  { KAp a{}; a.in = B.L[4]; a.spec = B.X[2]; a.out[0] = B.X[0]; a.twg = B.Wg;
    k_ffta<64, true, MA_IMF4, true><<<dim3(G64, 1), 256, 0, st>>>(a); }
  { TPp t{}; t.src[0] = B.X[0]; t.dst[0] = B.X[1];
    k_transpose<<<dim3(2, 2, 1), 256, 0, st>>>(t, 64); }
  { KBp b{}; b.in[0] = B.X[1]; b.out[0] = B.X[0]; b.red = stg + SG_IMM + 12; b.twg = B.Wg;
    k_fftb<64, true, WB_WRITE_IM><<<dim3(G64, 1), 256, 0, st>>>(b); }
  { ACp c{}; c.in[0] = B.X[0];
    k_autocorr<0><<<dim3(4, 1), 256, 0, st>>>(c, 64, nullptr, 0.f, stg + SG_ACR + 4 * 81); }

  // im steps s=3..0 (IA/IB alternate X2/X3)
  im_step_t<128>(B, 3, B.X[2], B.X[3], st);
  im_step_t<256>(B, 2, B.X[3], B.X[2], st);
  im_step_t<512>(B, 1, B.X[2], B.X[3], st);
  im_step_t<1024>(B, 0, B.X[3], B.X[2], st);

  // band phases
  band_phase_t<1024>(B, 0, st);
  band_phase_t<512>(B, 1, st);
  band_phase_t<256>(B, 2, st);
  band_phase_t<128>(B, 3, st);

  k_finalize<<<10, 256, 0, st>>>(stg, B.stgu, B.out);
}

// Round 5
// 890.949 us; speedup vs baseline: 2.8418x; 1.1241x over previous
//
#include <hip/hip_runtime.h>
#include <math.h>

#define PI_F      3.14159265358979323846f
#define TWOPI_F   6.28318530717958647692f
#define HALFPI_F  1.57079632679489661923f
#define ANG_F     0.8944271909999159f

// ---- staging layout (doubles) ----
#define SG_PIX   0      // sum, d2, d3, d4
#define SG_MAG   4      // 18 magnitude sums
#define SG_HISQ  22     // sum hi^2
#define SG_PMAG  23     // 12 parent-mag sums (s=0..2, b=0..3)
#define SG_IMM   35     // 5 x (sum im^2, im^3, im^4)
#define SG_ACE   50     // [4][4][81]  raw (uncentered)
#define SG_ACR   1346   // [5][81]
#define SG_C0    1751   // [4][16]     raw
#define SG_CR    1815   // [4][16]
#define SG_CX    1879   // [3][16]     raw
#define SG_CRX   1927   // [4][4*8]
#define SG_CR5   2055   // [25]
#define NSTG     2080

enum { MA_C2 = 0, MA_REAL, MA_BAND, MA_EMBED_BAND, MA_EMBED_LO, MA_IMF4, MA_IM };
enum { WB_WRITE = 0, WB_WRITE_MAG, WB_WRITE_IM, WB_RED_HI, WB_RED_ABSRE, WB_FWD_MASK, WB_PDOTS };

__device__ __forceinline__ int sfreq(int k, int H) { return (k < (H >> 1)) ? k : k - H; }
__device__ __forceinline__ int skx(int i) { return i + (i >> 4); }   // LDS bank skew

__device__ __forceinline__ float d_lograd(int fy, int fx, int H) {
  float cy = (float)fy * (2.0f / (float)H);
  float cx = (float)fx * (2.0f / (float)H);
  float rad = sqrtf(cx * cx + cy * cy);
  if (fy == 0 && fx == 0) rad = 2.0f / (float)H;   // reference DC hack
  return log2f(rad);
}
__device__ __forceinline__ float d_angle(int fy, int fx, int H) {
  return atan2f((float)fy * (2.0f / (float)H), (float)fx * (2.0f / (float)H));
}
__device__ __forceinline__ float d_rc(float x) {
  float c = fminf(fmaxf(-x, 0.0f), 1.0f);
  float t = cosf(0.5f * PI_F * c);
  return t * t;
}
__device__ __forceinline__ float d_alfa(float ang, int b) {
  float bc = (b == 0) ? 0.0f : (b == 1) ? 0.78539816339744830962f
           : (b == 2) ? 1.57079632679489661923f : 2.35619449019234492885f;
  float t = (PI_F + ang) - bc;
  float m = fmodf(t, TWOPI_F);
  if (m < 0.0f) m += TWOPI_F;
  return m - PI_F;
}
__device__ __forceinline__ float d_cos3(float a) { float c = cosf(a); return ANG_F * c * c * c; }
__device__ __forceinline__ float d_amaskC(float ang, int b) {
  float alfa = d_alfa(ang, b);
  float A = d_cos3(alfa);
  return (fabsf(alfa) < HALFPI_F) ? 2.0f * A : 0.0f;
}
__device__ __forceinline__ float d_lo(int fy, int fx, int H) {
  return sqrtf(fmaxf(1.0f - d_rc(d_lograd(fy, fx, H)), 0.0f));
}
// recon mask at native size H: lo0 * hm^2 * sum_b A1*(A1*I1 - A2*I2)
__device__ __forceinline__ float d_mm(int fy, int fx, int H) {
  float lr = d_lograd(fy, fx, H);
  float hm2 = d_rc(lr + 1.0f);
  float lo0 = sqrtf(fmaxf(1.0f - d_rc(lr), 0.0f));
  float ang1 = d_angle(fy, fx, H);
  int gfy = (fy == -(H >> 1)) ? fy : -fy;
  int gfx = (fx == -(H >> 1)) ? fx : -fx;
  float ang2 = d_angle(gfy, gfx, H);
  float msum = 0.0f;
  #pragma unroll
  for (int b4 = 0; b4 < 4; b4++) {
    float a1 = d_alfa(ang1, b4), a2 = d_alfa(ang2, b4);
    float A1 = d_cos3(a1), A2 = d_cos3(a2);
    float T1 = (fabsf(a1) < HALFPI_F) ? A1 : 0.0f;
    float T2 = (fabsf(a2) < HALFPI_F) ? A2 : 0.0f;
    msum += A1 * (T1 - T2);
  }
  return lo0 * hm2 * msum;
}
// accumulated im-chain mask at scale with native size N (N>=128)
template<int N>
__device__ __forceinline__ float d_G(int fy, int fx) {
  float g = d_mm(fy, fx, N);
  float chain = 1.0f;
  #pragma unroll
  for (int Nj = (N >> 1); Nj >= 64; Nj >>= 1) {
    int h = Nj >> 1;
    if (fy < -h || fy >= h || fx < -h || fx >= h) break;
    chain *= d_lo(fy, fx, Nj);
    if (Nj > 64) g += chain * d_mm(fy, fx, Nj);
    else g += chain * d_lo(fy, fx, 64);   // deepest term: lo@64 * lo0@64
  }
  if (fy == 0 && fx == 0) g = 0.0f;       // L4 DC zeroing (mean-subtracted lo resid)
  return g;
}
__device__ __forceinline__ unsigned fkey(float f) {
  unsigned u = __float_as_uint(f);
  return (u & 0x80000000u) ? ~u : (u | 0x80000000u);
}
__device__ __forceinline__ float funkey(unsigned k) {
  return (k & 0x80000000u) ? __uint_as_float(k & 0x7FFFFFFFu) : __uint_as_float(~k);
}

template<int K>
__device__ __forceinline__ void blk_reduce(float* v, float* red) {
  int tid = threadIdx.x, wave = tid >> 6, lane = tid & 63;
  #pragma unroll
  for (int k = 0; k < K; k++) {
    float x = v[k];
    #pragma unroll
    for (int o = 32; o; o >>= 1) x += __shfl_down(x, o, 64);
    if (lane == 0) red[wave * K + k] = x;
  }
  __syncthreads();
  if (tid < K) red[tid] = red[tid] + red[K + tid] + red[2 * K + tid] + red[3 * K + tid];
}

// ================= FFT core (Stockham, radix-4 with leading radix-2) =================
template<int N> struct FftConst {
  static constexpr int L2N = (N == 64) ? 6 : (N == 128) ? 7 : (N == 256) ? 8 : (N == 512) ? 9 : 10;
  static constexpr int TPR = (N / 4 >= 256) ? 256 : ((N / 4 < 16) ? 16 : N / 4);
  static constexpr int RPB = 256 / TPR;
  static constexpr int BUF = N + (N >> 4);
};

template<int N, bool INV>
__device__ __forceinline__ float2* fft_core(float2* A, float2* B, const float2* tw, int tr) {
  constexpr int TPR = FftConst<N>::TPR;
  constexpr int L2N = FftConst<N>::L2N;
  float2* src = A; float2* dst = B;
  if constexpr (L2N & 1) {
    for (int t = tr; t < (N >> 1); t += TPR) {
      float2 w = tw[t];
      float cv = w.x, sv = INV ? w.y : -w.y;
      float2 a = src[skx(t)];
      float2 b = src[skx(t + (N >> 1))];
      float dx = a.x - b.x, dy = a.y - b.y;
      dst[skx(2 * t)] = make_float2(a.x + b.x, a.y + b.y);
      dst[skx(2 * t + 1)] = make_float2(dx * cv - dy * sv, dx * sv + dy * cv);
    }
    __syncthreads();
    float2* tmp = src; src = dst; dst = tmp;
  }
  #pragma unroll
  for (int st = (L2N & 1); st < L2N; st += 2) {
    for (int t = tr; t < (N >> 2); t += TPR) {
      int p = t >> st;
      int q = t & ((1 << st) - 1);
      int i0 = q + (p << st);
      float2 x0 = src[skx(i0)];
      float2 x1 = src[skx(i0 + (N >> 2))];
      float2 x2 = src[skx(i0 + (N >> 1))];
      float2 x3 = src[skx(i0 + 3 * (N >> 2))];
      float2 w = tw[p << st];
      float c1 = w.x, s1 = INV ? w.y : -w.y;
      float c2 = c1 * c1 - s1 * s1, s2 = 2.f * c1 * s1;
      float c3 = c2 * c1 - s2 * s1, s3 = c2 * s1 + s2 * c1;
      float e0x = x0.x + x2.x, e0y = x0.y + x2.y;
      float e1x = x0.x - x2.x, e1y = x0.y - x2.y;
      float o0x = x1.x + x3.x, o0y = x1.y + x3.y;
      float d1x = x1.x - x3.x, d1y = x1.y - x3.y;
      float o1x, o1y;
      if constexpr (INV) { o1x = -d1y; o1y = d1x; }
      else               { o1x = d1y;  o1y = -d1x; }
      float t1x = e1x + o1x, t1y = e1y + o1y;
      float t2x = e0x - o0x, t2y = e0y - o0y;
      float t3x = e1x - o1x, t3y = e1y - o1y;
      int o = q + (p << (st + 2));
      int s = 1 << st;
      dst[skx(o)]         = make_float2(e0x + o0x, e0y + o0y);
      dst[skx(o + s)]     = make_float2(t1x * c1 - t1y * s1, t1x * s1 + t1y * c1);
      dst[skx(o + 2 * s)] = make_float2(t2x * c2 - t2y * s2, t2x * s2 + t2y * c2);
      dst[skx(o + 3 * s)] = make_float2(t3x * c3 - t3y * s3, t3x * s3 + t3y * c3);
    }
    __syncthreads();
    float2* tmp = src; src = dst; dst = tmp;
  }
  return src;
}

struct PAp {
  const float2* in[6];
  float2* out[6];
  const float2* twg;
  int mode[6];
  int aux[6];
};
struct PBp {
  const float2* in[6];
  float2* out[6];
  float2* out2;
  const float2* Bp[4];
  double* red[6];
  double* red2;
  double* cx;
  double* crx;
  const float2* twg;
  int wmode[6];
  int aux[6];
};
struct TPp { const float2* src[6]; float2* dst[6]; };
struct ACp { const float2* in[5]; double* g[5]; int mode[5]; };

template<int N, int MODE>
__device__ __forceinline__ float2 loadA(const float2* in, int row, int i, int b) {
  if constexpr (MODE == MA_C2) {
    return in[(size_t)row * N + i];
  } else if constexpr (MODE == MA_REAL) {
    const float* f = (const float*)in;
    return make_float2(f[(size_t)row * N + i], 0.0f);
  } else if constexpr (MODE == MA_BAND) {
    int fy = sfreq(i, N), fx = sfreq(row, N);
    float m = sqrtf(d_rc(d_lograd(fy, fx, N) + 1.0f)) * d_amaskC(d_angle(fy, fx, N), b);
    float2 l = in[(size_t)row * N + i];
    return make_float2(-l.y * m, l.x * m);
  } else if constexpr (MODE == MA_EMBED_BAND) {
    int fy = sfreq(i, N), fx = sfreq(row, N);
    int q = N >> 2, h2 = N >> 1;
    if (fy < -q || fy >= q || fx < -q || fx >= q) return make_float2(0.f, 0.f);
    int U = fx >= 0 ? fx : fx + h2, V = fy >= 0 ? fy : fy + h2;
    float m = sqrtf(d_rc(d_lograd(fy, fx, h2) + 1.0f)) * d_amaskC(d_angle(fy, fx, h2), b);
    float2 l = in[(size_t)U * h2 + V];
    return make_float2(-l.y * m, l.x * m);
  } else if constexpr (MODE == MA_EMBED_LO) {
    int fy = sfreq(i, N), fx = sfreq(row, N);
    int q = N >> 2, h2 = N >> 1;
    if (fy < -q || fy >= q || fx < -q || fx >= q) return make_float2(0.f, 0.f);
    int U = fx >= 0 ? fx : fx + h2, V = fy >= 0 ? fy : fy + h2;
    return in[(size_t)U * h2 + V];
  } else if constexpr (MODE == MA_IMF4) {
    int fy = sfreq(i, N), fx = sfreq(row, N);
    float lo = d_lo(fy, fx, N);
    float2 v = in[(size_t)row * N + i];
    return make_float2(v.x * lo, v.y * lo);
  } else {  // MA_IM: L_s * G_s  (closed-form im-chain spectrum)
    int fy = sfreq(i, N), fx = sfreq(row, N);
    float g = d_G<N>(fy, fx);
    float2 l = in[(size_t)row * N + i];
    return make_float2(l.x * g, l.y * g);
  }
}

// pass A: fused load op -> row FFT -> write
template<int N, bool INV>
__global__ __launch_bounds__(256) void k_passA(PAp p) {
  using FC = FftConst<N>;
  __shared__ float2 shA[FC::RPB][FC::BUF];
  __shared__ float2 shB[FC::RPB][FC::BUF];
  __shared__ float2 tw[N / 2];
  int tid = threadIdx.x;
  for (int k = tid; k < N / 2; k += 256) tw[k] = p.twg[k << (10 - FC::L2N)];
  int rl = tid / FC::TPR;
  int tr = tid % FC::TPR;
  int row = blockIdx.x * FC::RPB + rl;
  int plane = blockIdx.y;
  const float2* in = p.in[plane];
  int mode = p.mode[plane];
  int b = p.aux[plane];
  float2* A = shA[rl];
  switch (mode) {
    case MA_C2:         for (int i = tr; i < N; i += FC::TPR) A[skx(i)] = loadA<N, MA_C2>(in, row, i, b); break;
    case MA_REAL:       for (int i = tr; i < N; i += FC::TPR) A[skx(i)] = loadA<N, MA_REAL>(in, row, i, b); break;
    case MA_BAND:       for (int i = tr; i < N; i += FC::TPR) A[skx(i)] = loadA<N, MA_BAND>(in, row, i, b); break;
    case MA_EMBED_BAND: for (int i = tr; i < N; i += FC::TPR) A[skx(i)] = loadA<N, MA_EMBED_BAND>(in, row, i, b); break;
    case MA_EMBED_LO:   for (int i = tr; i < N; i += FC::TPR) A[skx(i)] = loadA<N, MA_EMBED_LO>(in, row, i, b); break;
    case MA_IMF4:       for (int i = tr; i < N; i += FC::TPR) A[skx(i)] = loadA<N, MA_IMF4>(in, row, i, b); break;
    default:            for (int i = tr; i < N; i += FC::TPR) A[skx(i)] = loadA<N, MA_IM>(in, row, i, b); break;
  }
  __syncthreads();
  float2* res = fft_core<N, INV>(A, shB[rl], tw, tr);
  constexpr float sc = INV ? 1.0f / (float)N : 1.0f;
  float2* o = p.out[plane] + (size_t)row * N;
  for (int i = tr; i < N; i += FC::TPR) {
    float2 v = res[skx(i)];
    o[i] = make_float2(v.x * sc, v.y * sc);
  }
}

// pass B: plain load -> row FFT -> write / fused reductions
template<int N, bool INV>
__global__ __launch_bounds__(256) void k_passB(PBp p) {
  using FC = FftConst<N>;
  __shared__ float2 shA[FC::RPB][FC::BUF];
  __shared__ float2 shB[FC::RPB][FC::BUF];
  __shared__ float2 tw[N / 2];
  __shared__ float red[52];
  int tid = threadIdx.x;
  for (int k = tid; k < N / 2; k += 256) tw[k] = p.twg[k << (10 - FC::L2N)];
  int rl = tid / FC::TPR;
  int tr = tid % FC::TPR;
  int row = blockIdx.x * FC::RPB + rl;
  int plane = blockIdx.y;
  const float2* in = p.in[plane] + (size_t)row * N;
  float2* A = shA[rl];
  for (int i = tr; i < N; i += FC::TPR) A[skx(i)] = in[i];
  __syncthreads();
  float2* res = fft_core<N, INV>(A, shB[rl], tw, tr);
  constexpr float sc = INV ? 1.0f / (float)N : 1.0f;
  int wmode = p.wmode[plane];
  if (wmode == WB_WRITE || wmode == WB_WRITE_MAG || wmode == WB_WRITE_IM) {
    float2* o = p.out[plane] + (size_t)row * N;
    float a0 = 0.f, a1 = 0.f, a2 = 0.f;
    for (int i = tr; i < N; i += FC::TPR) {
      float2 v = res[skx(i)];
      v.x *= sc; v.y *= sc;
      o[i] = v;
      if (wmode == WB_WRITE_MAG) a0 += sqrtf(v.x * v.x + v.y * v.y);
      else if (wmode == WB_WRITE_IM) { float v2 = v.x * v.x; a0 += v2; a1 += v2 * v.x; a2 += v2 * v2; }
    }
    if (wmode == WB_WRITE_MAG) {
      float acc[1] = {a0}; blk_reduce<1>(acc, red);
      if (tid == 0) atomicAdd(p.red[plane], (double)red[0]);
    } else if (wmode == WB_WRITE_IM) {
      float acc[3] = {a0, a1, a2}; blk_reduce<3>(acc, red);
      if (tid < 3) atomicAdd(&p.red[plane][tid], (double)red[tid]);
    }
  } else if (wmode == WB_RED_HI) {
    float a0 = 0.f, a1 = 0.f;
    for (int i = tr; i < N; i += FC::TPR) {
      float v = res[skx(i)].x * sc;
      a0 += fabsf(v); a1 += v * v;
    }
    float acc[2] = {a0, a1}; blk_reduce<2>(acc, red);
    if (tid == 0) atomicAdd(p.red[plane], (double)red[0]);
    if (tid == 1) atomicAdd(p.red2, (double)red[1]);
  } else if (wmode == WB_RED_ABSRE) {
    float a0 = 0.f;
    for (int i = tr; i < N; i += FC::TPR) a0 += fabsf(res[skx(i)].x * sc);
    float acc[1] = {a0}; blk_reduce<1>(acc, red);
    if (tid == 0) atomicAdd(p.red[plane], (double)red[0]);
  } else if (wmode == WB_FWD_MASK) {
    float2* o1 = p.out[plane] + (size_t)row * N;
    float2* o2 = p.out2 + (size_t)row * N;
    int fx = sfreq(row, N);
    for (int i = tr; i < N; i += FC::TPR) {
      float2 v = res[skx(i)];
      int fy = sfreq(i, N);
      float rcv = d_rc(d_lograd(fy, fx, N));
      float hi = sqrtf(rcv), lo = sqrtf(fmaxf(1.0f - rcv, 0.0f));
      o1[i] = make_float2(v.x * hi, v.y * hi);
      o2[i] = make_float2(v.x * lo, v.y * lo);
    }
  } else {  // WB_PDOTS: parent spatial -> raw dots vs band planes, no store
    int b = p.aux[plane];
    float acc[13];
    #pragma unroll
    for (int k = 0; k < 13; k++) acc[k] = 0.f;
    for (int i = tr; i < N; i += FC::TPR) {
      float2 v = res[skx(i)];
      v.x *= sc; v.y *= sc;
      float mag = sqrtf(v.x * v.x + v.y * v.y);
      float rr = 0.f, ri = 0.f;
      if (mag > 0.f) { rr = (v.y * v.y - v.x * v.x) / mag; ri = 2.f * v.x * v.y / mag; }
      size_t idx = (size_t)row * N + i;
      #pragma unroll
      for (int c = 0; c < 4; c++) {
        float2 bv = p.Bp[c][idx];
        float am = sqrtf(bv.x * bv.x + bv.y * bv.y);
        acc[c] += am * mag;
        acc[4 + c] += bv.x * rr;
        acc[8 + c] += bv.x * ri;
      }
      acc[12] += mag;
    }
    blk_reduce<13>(acc, red);
    if (tid < 4) atomicAdd(&p.cx[tid * 4 + b], (double)red[tid]);
    else if (tid < 8) atomicAdd(&p.crx[(tid - 4) * 8 + b], (double)red[tid]);
    else if (tid < 12) atomicAdd(&p.crx[(tid - 8) * 8 + 4 + b], (double)red[tid]);
    else if (tid == 12) atomicAdd(p.red[plane], (double)red[12]);
  }
}

__global__ __launch_bounds__(256) void k_transpose(TPp p, int N) {
  __shared__ float2 tile[32][33];
  int z = blockIdx.z;
  const float2* in = p.src[z];
  float2* out = p.dst[z];
  int bx = blockIdx.x << 5, by = blockIdx.y << 5;
  int tx = threadIdx.x & 31, ty = threadIdx.x >> 5;
  for (int r = ty; r < 32; r += 8) tile[r][tx] = in[(size_t)(by + r) * N + bx + tx];
  __syncthreads();
  for (int r = ty; r < 32; r += 8) out[(size_t)(bx + r) * N + by + tx] = tile[tx][r];
}

__global__ __launch_bounds__(256) void k_gen_Ldown(const float2* __restrict__ Lb, float2* __restrict__ Ls, int Hn, int zdc) {
  int i = blockIdx.x * 256 + threadIdx.x;
  if (i >= Hn * Hn) return;
  int fy = sfreq(i / Hn, Hn), fx = sfreq(i % Hn, Hn);
  int Hb = Hn << 1;
  int by = fy >= 0 ? fy : fy + Hb;
  int bx = fx >= 0 ? fx : fx + Hb;
  float lo = d_lo(fy, fx, Hn);
  float2 v = Lb[(size_t)by * Hb + bx];
  if (zdc && i == 0) { Ls[0] = make_float2(0.f, 0.f); return; }
  Ls[i] = make_float2(v.x * lo, v.y * lo);
}

// ================= reductions / stats =================
__global__ __launch_bounds__(256) void k_init(double* stg, unsigned* stgu, float2* Wg) {
  int i = blockIdx.x * 256 + threadIdx.x;
  if (i < NSTG) stg[i] = 0.0;
  if (i == 0) { stgu[0] = 0u; stgu[1] = 0xFFFFFFFFu; }
  if (i < 512) {
    float a = TWOPI_F * (float)i * (1.0f / 1024.0f);
    float sv, cv; sincosf(a, &sv, &cv);
    Wg[i] = make_float2(cv, sv);
  }
}
__global__ __launch_bounds__(256) void k_pix1(const float* __restrict__ x, int n, double* stg, unsigned* stgu) {
  __shared__ float red[4];
  float s = 0.f, mn = 3.402823466e38f, mx = -3.402823466e38f;
  for (int i = blockIdx.x * 256 + threadIdx.x; i < n; i += gridDim.x * 256) {
    float v = x[i]; s += v; mn = fminf(mn, v); mx = fmaxf(mx, v);
  }
  float acc[1] = {s};
  blk_reduce<1>(acc, red);
  if (threadIdx.x == 0) atomicAdd(&stg[SG_PIX], (double)red[0]);
  #pragma unroll
  for (int o = 32; o; o >>= 1) { mn = fminf(mn, __shfl_down(mn, o, 64)); mx = fmaxf(mx, __shfl_down(mx, o, 64)); }
  if ((threadIdx.x & 63) == 0) { atomicMin(&stgu[1], fkey(mn)); atomicMax(&stgu[0], fkey(mx)); }
}
__global__ __launch_bounds__(256) void k_pix2(const float* __restrict__ x, int n, double* stg) {
  __shared__ float red[12];
  float mu = (float)(stg[SG_PIX] / (double)n);
  float a2 = 0.f, a3 = 0.f, a4 = 0.f;
  for (int i = blockIdx.x * 256 + threadIdx.x; i < n; i += gridDim.x * 256) {
    float d = x[i] - mu; float d2 = d * d; a2 += d2; a3 += d2 * d; a4 += d2 * d2;
  }
  float acc[3] = {a2, a3, a4};
  blk_reduce<3>(acc, red);
  if (threadIdx.x < 3) atomicAdd(&stg[SG_PIX + 1 + threadIdx.x], (double)red[threadIdx.x]);
}

// central 9x9 circular autocorrelation, RAW sums (uncentered).
// thread = (center row ty 0..31, col-group tx4 0..7); 12 b32 window reads per dy.
// tile stride 41 (== 1 mod 8): per instruction banks are an exact 2-per-bank map -> conflict-free.
__global__ __launch_bounds__(256) void k_autocorr(ACp p, int H) {
  __shared__ float tile[40][41];
  __shared__ float fred[4 * 81];
  int plane = blockIdx.y;
  const float2* in = p.in[plane];
  double* g = p.g[plane];
  int mode = p.mode[plane];
  float acc[81];
  #pragma unroll
  for (int k = 0; k < 81; k++) acc[k] = 0.f;
  int nT = (H >> 5) * (H >> 5);
  int tx4 = threadIdx.x & 7, ty = threadIdx.x >> 3;
  for (int ti = blockIdx.x; ti < nT; ti += gridDim.x) {
    __syncthreads();
    int by = (ti / (H >> 5)) << 5, bx = (ti % (H >> 5)) << 5;
    for (int ii = threadIdx.x; ii < 1600; ii += 256) {
      int r = ii / 40, c = ii - r * 40;
      int gy = (by + r - 4) & (H - 1), gx = (bx + c - 4) & (H - 1);
      float2 v = in[(size_t)gy * H + gx];
      float val = mode ? sqrtf(v.x * v.x + v.y * v.y) : v.x;
      tile[r][c] = val;
    }
    __syncthreads();
    float cen[4];
    #pragma unroll
    for (int c = 0; c < 4; c++) cen[c] = tile[ty + 4][4 * tx4 + 4 + c];
    #pragma unroll
    for (int dy = -4; dy <= 4; dy++) {
      float r[12];
      #pragma unroll
      for (int j = 0; j < 12; j++) r[j] = tile[ty + 4 + dy][4 * tx4 + j];
      #pragma unroll
      for (int dx = -4; dx <= 4; dx++) {
        int o = (dy + 4) * 9 + (dx + 4);
        float s = 0.f;
        #pragma unroll
        for (int c = 0; c < 4; c++) s += cen[c] * r[c + dx + 4];
        acc[o] += s;
      }
    }
  }
  int wave = threadIdx.x >> 6, lane = threadIdx.x & 63;
  #pragma unroll
  for (int k = 0; k < 81; k++) {
    float x = acc[k];
    #pragma unroll
    for (int o = 32; o; o >>= 1) x += __shfl_down(x, o, 64);
    if (lane == 0) fred[wave * 81 + k] = x;
  }
  __syncthreads();
  for (int k = threadIdx.x; k < 81; k += 256)
    atomicAdd(&g[k], (double)(fred[k] + fred[81 + k] + fred[162 + k] + fred[243 + k]));
}

// raw Grams of 4 band planes: sum |Bi||Bj| and sum re_i re_j
__global__ __launch_bounds__(256) void k_gram4(const float2* __restrict__ b0, const float2* __restrict__ b1,
                                               const float2* __restrict__ b2, const float2* __restrict__ b3,
                                               int n, double* c0out, double* crout) {
  __shared__ float red[128];
  float acc[32];
  #pragma unroll
  for (int k = 0; k < 32; k++) acc[k] = 0.f;
  for (int i = blockIdx.x * 256 + threadIdx.x; i < n; i += gridDim.x * 256) {
    float2 v0 = b0[i], v1 = b1[i], v2 = b2[i], v3 = b3[i];
    float a[4] = { sqrtf(v0.x * v0.x + v0.y * v0.y), sqrtf(v1.x * v1.x + v1.y * v1.y),
                   sqrtf(v2.x * v2.x + v2.y * v2.y), sqrtf(v3.x * v3.x + v3.y * v3.y) };
    float r[4] = { v0.x, v1.x, v2.x, v3.x };
    #pragma unroll
    for (int ii = 0; ii < 4; ii++)
      #pragma unroll
      for (int jj = 0; jj < 4; jj++) { acc[ii * 4 + jj] += a[ii] * a[jj]; acc[16 + ii * 4 + jj] += r[ii] * r[jj]; }
  }
  blk_reduce<32>(acc, red);
  int tid = threadIdx.x;
  if (tid < 16) atomicAdd(&c0out[tid], (double)red[tid]);
  else if (tid < 32) atomicAdd(&crout[tid - 16], (double)red[tid]);
}

__global__ __launch_bounds__(256) void k_dots_rpar5(const float2* __restrict__ P,
                                                    const float2* __restrict__ b0, const float2* __restrict__ b1,
                                                    const float2* __restrict__ b2, const float2* __restrict__ b3,
                                                    double* crxB) {
  __shared__ float red[80];
  float acc[20];
  #pragma unroll
  for (int k = 0; k < 20; k++) acc[k] = 0.f;
  for (int i = blockIdx.x * 256 + threadIdx.x; i < 16384; i += gridDim.x * 256) {
    int y = i >> 7, x = i & 127;
    float tt[5];
    tt[0] = P[i].x;
    tt[1] = P[(y << 7) | ((x - 1) & 127)].x;
    tt[2] = P[(y << 7) | ((x + 1) & 127)].x;
    tt[3] = P[(((y - 1) & 127) << 7) | x].x;
    tt[4] = P[(((y + 1) & 127) << 7) | x].x;
    float r[4] = { b0[i].x, b1[i].x, b2[i].x, b3[i].x };
    #pragma unroll
    for (int a = 0; a < 4; a++)
      #pragma unroll
      for (int c = 0; c < 5; c++) acc[a * 5 + c] += r[a] * tt[c];
  }
  blk_reduce<20>(acc, red);
  int tid = threadIdx.x;
  if (tid < 20) atomicAdd(&crxB[(tid / 5) * 8 + (tid % 5)], (double)red[tid]);
}
__global__ __launch_bounds__(256) void k_gram5(const float2* __restrict__ P, double* cr5) {
  __shared__ float red[100];
  float acc[25];
  #pragma unroll
  for (int k = 0; k < 25; k++) acc[k] = 0.f;
  for (int i = blockIdx.x * 256 + threadIdx.x; i < 16384; i += gridDim.x * 256) {
    int y = i >> 7, x = i & 127;
    float tt[5];
    tt[0] = P[i].x;
    tt[1] = P[(y << 7) | ((x - 1) & 127)].x;
    tt[2] = P[(y << 7) | ((x + 1) & 127)].x;
    tt[3] = P[(((y - 1) & 127) << 7) | x].x;
    tt[4] = P[(((y + 1) & 127) << 7) | x].x;
    #pragma unroll
    for (int a = 0; a < 5; a++)
      #pragma unroll
      for (int c = 0; c < 5; c++) acc[a * 5 + c] += tt[a] * tt[c];
  }
  blk_reduce<25>(acc, red);
  int tid = threadIdx.x;
  if (tid < 25) atomicAdd(&cr5[tid], (double)red[tid]);
}

// ================= finalize: write all 2456 outputs (raw-moment centering) =================
__global__ __launch_bounds__(256) void k_finalize(const double* __restrict__ stg, const unsigned* __restrict__ stgu,
                                                  float* __restrict__ out) {
  int t = blockIdx.x * 256 + threadIdx.x;
  if (t >= 2456) return;
  const double N = 1048576.0;
  if (t < 6) {
    double mu = stg[SG_PIX] / N;
    double vp = stg[SG_PIX + 1] / N;
    double r;
    if (t == 0) r = mu;
    else if (t == 1) r = vp * (N / (N - 1.0));
    else if (t == 2) r = (stg[SG_PIX + 2] / N) / (vp * sqrt(vp));
    else if (t == 3) r = (stg[SG_PIX + 3] / N) / (vp * vp);
    else if (t == 4) r = (double)funkey(stgu[1]);
    else r = (double)funkey(stgu[0]);
    out[t] = (float)r;
  } else if (t < 24) {
    int i = t - 6;
    double csz;
    if (i == 0) csz = 1048576.0;
    else if (i < 17) { int s = (i - 1) >> 2; double h = (double)(1024 >> s); csz = h * h; }
    else csz = 4096.0;
    out[t] = (float)(stg[SG_MAG + i] / csz);
  } else if (t < 1320) {
    int e = t - 24;
    int b = e & 3, s = (e >> 2) & 3, o = e >> 4;
    double h = (double)(1024 >> s); double csz = h * h;
    double m = stg[SG_MAG + 1 + 4 * s + b] / csz;
    out[t] = (float)(stg[SG_ACE + (s * 4 + b) * 81 + o] / csz - m * m);
  } else if (t < 1330) {
    int kurt = (t >= 1325);
    int s = t - (kurt ? 1325 : 1320);
    double h = (double)(1024 >> s); double csz = h * h;
    double vari = stg[SG_IMM + s * 3] / csz;
    double var0 = (stg[SG_PIX + 1] / N) * (N / (N - 1.0));
    double v = vari > 1e-12 ? vari : 1e-12;
    double r;
    if (vari / var0 > 1e-6)
      r = kurt ? (stg[SG_IMM + s * 3 + 2] / csz) / (v * v) : (stg[SG_IMM + s * 3 + 1] / csz) / (v * sqrt(v));
    else
      r = kurt ? 3.0 : 0.0;
    out[t] = (float)r;
  } else if (t < 1735) {
    int e = t - 1330;
    int s = e % 5, o = e / 5;
    double h = (double)(1024 >> s);
    out[t] = (float)(stg[SG_ACR + s * 81 + o] / (h * h));
  } else if (t < 1815) {
    int e = t - 1735;
    int s = e % 5, o = e / 5;
    if (s < 4) {
      double h = (double)(1024 >> s); double csz = h * h;
      int i = o >> 2, j = o & 3;
      double mi = stg[SG_MAG + 1 + 4 * s + i] / csz;
      double mj = stg[SG_MAG + 1 + 4 * s + j] / csz;
      out[t] = (float)(stg[SG_C0 + s * 16 + o] / csz - mi * mj);
    } else out[t] = 0.0f;
  } else if (t < 1879) {
    int e = t - 1815;
    int s = e & 3, o = e >> 2;
    if (s < 3) {
      double h = (double)(1024 >> s); double csz = h * h;
      int c = o >> 2, b = o & 3;
      double mc = stg[SG_MAG + 1 + 4 * s + c] / csz;
      double pm = stg[SG_PMAG + 4 * s + b] / csz;
      out[t] = (float)(stg[SG_CX + s * 16 + o] / csz - mc * pm);
    } else out[t] = 0.0f;
  } else if (t < 2199) {
    int e = t - 1879;
    int s = e % 5, o = e / 5;
    int i = o >> 3, j = o & 7;
    float r = 0.0f;
    if (s < 4) { if (i < 4 && j < 4) { double h = (double)(1024 >> s); r = (float)(stg[SG_CR + s * 16 + i * 4 + j] / (h * h)); } }
    else { if (i < 5 && j < 5) r = (float)(stg[SG_CR5 + i * 5 + j] / 4096.0); }
    out[t] = r;
  } else if (t < 2455) {
    int e = t - 2199;
    int s = e & 3, o = e >> 2;
    int i = o >> 3, j = o & 7;
    float r = 0.0f;
    if (i < 4) {
      if (s < 3) { double h = (double)(1024 >> s); r = (float)(stg[SG_CRX + s * 32 + i * 8 + j] / (h * h)); }
      else if (j < 5) r = (float)(stg[SG_CRX + 96 + i * 8 + j] / 16384.0);
    }
    out[t] = r;
  } else {
    out[t] = (float)(stg[SG_HISQ] / N);
  }
}

// ================= host orchestration =================
static inline int rb(int n) { int b = (n + 255) / 256; return b > 256 ? 256 : b; }

struct Bufs {
  const float* img;
  float2* L[5];
  float2* Wg;
  double* stg; unsigned* stgu;
  float* out;
  char* w1;   // 40 MiB, 5 x 8MiB slots (packed by plane size)
  char* w2;   // 32 MiB, 4 x 8MiB slots
  char* l0raw;
};

template<int N>
static void scale_phase(const Bufs& B, int s, hipStream_t st) {
  constexpr int RPB = FftConst<N>::RPB;
  constexpr size_t PB = (size_t)N * N * 8;
  const int np = (N == 128) ? 6 : 5;
  // --- passA: {im, B0..3 [, Plo]} ---
  { PAp a{}; a.twg = B.Wg;
    a.in[0] = B.L[s]; a.mode[0] = MA_IM; a.aux[0] = 0;
    for (int b = 0; b < 4; b++) { a.in[1 + b] = B.L[s]; a.mode[1 + b] = MA_BAND; a.aux[1 + b] = b; }
    if (np == 6) { a.in[5] = B.L[4]; a.mode[5] = MA_EMBED_LO; a.aux[5] = 0; }
    for (int p = 0; p < np; p++) a.out[p] = (float2*)(B.w1 + p * PB);
    k_passA<N, true><<<dim3(N / RPB, np), 256, 0, st>>>(a); }
  // --- transpose ---
  float2* D[6];
  { TPp t{};
    for (int p = 0; p < np; p++) {
      D[p] = (N <= 512 || p < 4) ? (float2*)(B.w2 + p * PB) : (float2*)B.l0raw;
      t.src[p] = (const float2*)(B.w1 + p * PB); t.dst[p] = D[p];
    }
    k_transpose<<<dim3(N / 32, N / 32, np), 256, 0, st>>>(t, N); }
  // --- passB: spatial + fused stats ---
  { PBp bb{}; bb.twg = B.Wg;
    for (int p = 0; p < np; p++) { bb.in[p] = D[p]; bb.out[p] = (float2*)(B.w1 + p * PB); }
    bb.wmode[0] = WB_WRITE_IM; bb.red[0] = B.stg + SG_IMM + s * 3;
    for (int b = 0; b < 4; b++) { bb.wmode[1 + b] = WB_WRITE_MAG; bb.red[1 + b] = B.stg + SG_MAG + 1 + 4 * s + b; }
    if (np == 6) bb.wmode[5] = WB_WRITE;
    k_passB<N, true><<<dim3(N / RPB, np), 256, 0, st>>>(bb); }
  // --- autocorr (im + 4 bands) ---
  { ACp c{};
    c.in[0] = (const float2*)(B.w1); c.g[0] = B.stg + SG_ACR + s * 81; c.mode[0] = 0;
    for (int b = 0; b < 4; b++) { c.in[1 + b] = (const float2*)(B.w1 + (1 + b) * PB); c.g[1 + b] = B.stg + SG_ACE + (s * 4 + b) * 81; c.mode[1 + b] = 1; }
    int nT = (N / 32) * (N / 32);
    k_autocorr<<<dim3(nT > 256 ? 256 : nT, 5), 256, 0, st>>>(c, N); }
  // --- raw gram ---
  k_gram4<<<rb(N * N), 256, 0, st>>>((const float2*)(B.w1 + PB), (const float2*)(B.w1 + 2 * PB),
                                     (const float2*)(B.w1 + 3 * PB), (const float2*)(B.w1 + 4 * PB),
                                     N * N, B.stg + SG_C0 + s * 16, B.stg + SG_CR + s * 16);
  if (s < 3) {
    // --- parents: 2 pairs, fused dots (no parent storage) ---
    for (int pr = 0; pr < 2; pr++) {
      { PAp a{}; a.twg = B.Wg;
        for (int k = 0; k < 2; k++) { int b = pr * 2 + k; a.in[k] = B.L[s + 1]; a.mode[k] = MA_EMBED_BAND; a.aux[k] = b; a.out[k] = (float2*)(B.w2 + k * PB); }
        k_passA<N, true><<<dim3(N / RPB, 2), 256, 0, st>>>(a); }
      { TPp t{};
        for (int k = 0; k < 2; k++) { t.src[k] = (const float2*)(B.w2 + k * PB); t.dst[k] = (float2*)(B.w2 + (2 + k) * PB); }
        k_transpose<<<dim3(N / 32, N / 32, 2), 256, 0, st>>>(t, N); }
      { PBp bb{}; bb.twg = B.Wg;
        for (int k = 0; k < 2; k++) { int b = pr * 2 + k; bb.in[k] = (const float2*)(B.w2 + (2 + k) * PB); bb.wmode[k] = WB_PDOTS; bb.aux[k] = b; bb.red[k] = B.stg + SG_PMAG + 4 * s + b; }
        for (int cc = 0; cc < 4; cc++) bb.Bp[cc] = (const float2*)(B.w1 + (1 + cc) * PB);
        bb.cx = B.stg + SG_CX + s * 16; bb.crx = B.stg + SG_CRX + s * 32;
        k_passB<N, true><<<dim3(N / RPB, 2), 256, 0, st>>>(bb); }
    }
  } else {
    k_dots_rpar5<<<64, 256, 0, st>>>((const float2*)(B.w1 + 5 * PB),
                                     (const float2*)(B.w1 + PB), (const float2*)(B.w1 + 2 * PB),
                                     (const float2*)(B.w1 + 3 * PB), (const float2*)(B.w1 + 4 * PB),
                                     B.stg + SG_CRX + 96);
    k_gram5<<<64, 256, 0, st>>>((const float2*)(B.w1 + 5 * PB), B.stg + SG_CR5);
  }
}

extern "C" void kernel_launch(void* const* d_in, const int* in_sizes, int n_in,
                              void* d_out, int out_size, void* d_ws, size_t ws_size,
                              hipStream_t stream) {
  (void)in_sizes; (void)n_in; (void)out_size;
  if (ws_size < 87031808ull) return;   // 83 MiB
  char* w = (char*)d_ws;
  Bufs B;
  B.img = (const float*)d_in[0];
  B.out = (float*)d_out;
  B.L[0] = (float2*)(w + 0ull);
  B.L[1] = (float2*)(w + 8388608ull);
  B.L[2] = (float2*)(w + 10485760ull);
  B.L[3] = (float2*)(w + 11010048ull);
  B.L[4] = (float2*)(w + 11141120ull);
  B.Wg   = (float2*)(w + 11173888ull);
  B.stg  = (double*)(w + 11177984ull);
  B.stgu = (unsigned*)(B.stg + NSTG);
  B.w1   = w + 11534336ull;            // 40 MiB
  B.w2   = w + 53477376ull;            // 32 MiB
  B.l0raw = w;                          // L0 region reused as 5th transpose slot at N=1024
  hipStream_t st = stream;
  double* stg = B.stg;
  constexpr size_t PB8 = 8388608ull;

  k_init<<<9, 256, 0, st>>>(stg, B.stgu, B.Wg);
  k_pix1<<<256, 256, 0, st>>>(B.img, 1048576, stg, B.stgu);
  k_pix2<<<256, 256, 0, st>>>(B.img, 1048576, stg);

  // forward fft2 (transposed-spectrum convention): img -> hi-spec (w1 slot1) + L0
  { PAp a{}; a.twg = B.Wg; a.in[0] = (const float2*)B.img; a.mode[0] = MA_REAL; a.aux[0] = 0;
    a.out[0] = (float2*)(B.w1);
    k_passA<1024, false><<<dim3(1024, 1), 256, 0, st>>>(a); }
  { TPp t{}; t.src[0] = (const float2*)(B.w1); t.dst[0] = (float2*)(B.w2);
    k_transpose<<<dim3(32, 32, 1), 256, 0, st>>>(t, 1024); }
  { PBp bb{}; bb.twg = B.Wg; bb.in[0] = (const float2*)(B.w2); bb.wmode[0] = WB_FWD_MASK;
    bb.out[0] = (float2*)(B.w1 + PB8); bb.out2 = B.L[0];
    k_passB<1024, false><<<dim3(1024, 1), 256, 0, st>>>(bb); }

  // hi residual: ifft2 of hi-spec, reduce-only (sum|re|, re^2)
  { PAp a{}; a.twg = B.Wg; a.in[0] = (const float2*)(B.w1 + PB8); a.mode[0] = MA_C2; a.aux[0] = 0;
    a.out[0] = (float2*)(B.w1);
    k_passA<1024, true><<<dim3(1024, 1), 256, 0, st>>>(a); }
  { TPp t{}; t.src[0] = (const float2*)(B.w1); t.dst[0] = (float2*)(B.w2);
    k_transpose<<<dim3(32, 32, 1), 256, 0, st>>>(t, 1024); }
  { PBp bb{}; bb.twg = B.Wg; bb.in[0] = (const float2*)(B.w2); bb.wmode[0] = WB_RED_HI;
    bb.red[0] = stg + SG_MAG; bb.red2 = stg + SG_HISQ;
    k_passB<1024, true><<<dim3(1024, 1), 256, 0, st>>>(bb); }

  // lowpass chain
  k_gen_Ldown<<<1024, 256, 0, st>>>(B.L[0], B.L[1], 512, 0);
  k_gen_Ldown<<<256, 256, 0, st>>>(B.L[1], B.L[2], 256, 0);
  k_gen_Ldown<<<64, 256, 0, st>>>(B.L[2], B.L[3], 128, 0);
  k_gen_Ldown<<<16, 256, 0, st>>>(B.L[3], B.L[4], 64, 1);

  // size-64 batch: {lo-resid (plain ifft of L4), imF4 = L4*lo0}
  {
    constexpr size_t PB = 64ull * 64ull * 8ull;
    constexpr int RPB = FftConst<64>::RPB;
    { PAp a{}; a.twg = B.Wg;
      a.in[0] = B.L[4]; a.mode[0] = MA_C2; a.aux[0] = 0; a.out[0] = (float2*)(B.w1);
      a.in[1] = B.L[4]; a.mode[1] = MA_IMF4; a.aux[1] = 0; a.out[1] = (float2*)(B.w1 + PB);
      k_passA<64, true><<<dim3(64 / RPB, 2), 256, 0, st>>>(a); }
    { TPp t{};
      t.src[0] = (const float2*)(B.w1); t.dst[0] = (float2*)(B.w2);
      t.src[1] = (const float2*)(B.w1 + PB); t.dst[1] = (float2*)(B.w2 + PB);
      k_transpose<<<dim3(2, 2, 2), 256, 0, st>>>(t, 64); }
    { PBp bb{}; bb.twg = B.Wg;
      bb.in[0] = (const float2*)(B.w2); bb.wmode[0] = WB_RED_ABSRE; bb.red[0] = stg + SG_MAG + 17;
      bb.in[1] = (const float2*)(B.w2 + PB); bb.wmode[1] = WB_WRITE_IM; bb.red[1] = stg + SG_IMM + 12;
      bb.out[1] = (float2*)(B.w1 + PB);
      k_passB<64, true><<<dim3(64 / RPB, 2), 256, 0, st>>>(bb); }
    { ACp c{}; c.in[0] = (const float2*)(B.w1 + PB); c.g[0] = stg + SG_ACR + 4 * 81; c.mode[0] = 0;
      k_autocorr<<<dim3(4, 1), 256, 0, st>>>(c, 64); }
  }

  // per-scale batches (each fully independent given L[s])
  scale_phase<128>(B, 3, st);
  scale_phase<256>(B, 2, st);
  scale_phase<512>(B, 1, st);
  scale_phase<1024>(B, 0, st);

  k_finalize<<<10, 256, 0, st>>>(stg, B.stgu, B.out);
}